// Round 7
// baseline (250.119 us; speedup 1.0000x reference)
//
#include <hip/hip_runtime.h>
#include <hip/hip_bf16.h>

typedef __bf16 bf16x8 __attribute__((ext_vector_type(8)));
typedef float f32x4 __attribute__((ext_vector_type(4)));
typedef unsigned int u32x4 __attribute__((ext_vector_type(4)));
typedef unsigned int u32x2 __attribute__((ext_vector_type(2)));
typedef int i32x2 __attribute__((ext_vector_type(2)));
typedef unsigned short u16;
typedef unsigned long long u64;

#define WAITVM(n) asm volatile("s_waitcnt vmcnt(" #n ")" ::: "memory")
#define WAITLG() asm volatile("s_waitcnt lgkmcnt(0)" ::: "memory")
#define SBAR() asm volatile("s_barrier" ::: "memory")

__device__ __forceinline__ u16 f2bf(float f) {
  unsigned u = __builtin_bit_cast(unsigned, f);
  u += 0x7FFFu + ((u >> 16) & 1u);   // RNE
  return (u16)(u >> 16);
}
// HW packed convert: 2 fp32 -> 2 bf16 (v_cvt_pk_bf16_f32, RNE)
__device__ __forceinline__ unsigned cvtpk(float a, float b) {
  float2 f; f.x = a; f.y = b;
  __hip_bfloat162 h = __float22bfloat162_rn(f);
  unsigned u;
  __builtin_memcpy(&u, &h, 4);
  return u;
}

// v_permlane32_swap_b32: after call, a = [a.lo ; b.lo], b = [a.hi ; b.hi]
__device__ __forceinline__ void plswap(unsigned &a, unsigned &b) {
  i32x2 r = __builtin_amdgcn_permlane32_swap((int)a, (int)b, false, false);
  a = (unsigned)r[0];
  b = (unsigned)r[1];
}

// async global->LDS direct copy, 16B per lane. LDS dest = wave-uniform base + lane*16.
__device__ __forceinline__ void gll16(const u16* g, u16* l) {
  __builtin_amdgcn_global_load_lds(
      (const __attribute__((address_space(1))) unsigned int*)g,
      (__attribute__((address_space(3))) unsigned int*)l, 16, 0, 0);
}

// ------------- transpose + cast: W[K][N] fp32 -> WT[N][K] bf16 -------------
__global__ void transpose_cast_kernel(const float* __restrict__ W, u16* __restrict__ WT, int K, int N) {
  __shared__ float tile[32][33];
  int c0 = blockIdx.x * 32, r0 = blockIdx.y * 32;
  int tx = threadIdx.x & 31, tg = threadIdx.x >> 5;
#pragma unroll
  for (int i = 0; i < 4; ++i) {
    int r = tg + i * 8;
    tile[r][tx] = W[(size_t)(r0 + r) * N + c0 + tx];
  }
  __syncthreads();
#pragma unroll
  for (int i = 0; i < 4; ++i) {
    int r = tg + i * 8;
    WT[(size_t)(c0 + r) * K + r0 + tx] = f2bf(tile[tx][r]);
  }
}

// ---------------- QKV GEMM: [8192x768] x [768x2304], fused fp32->bf16 A ----------------
// Minimum-2-phase pipeline (catalog T3): per BK=32 step, issue next-tile loads FIRST
// (A: fp32 global->reg; B: gll16), compute current buffer, convert+ds_write A, then
// ONE vmcnt(0)+lgkmcnt(0)+barrier. Half the barriers of the old scheme; loads get a
// full compute phase of cover. A is converted with cvtpk RNE == old cast_x (bit-exact).
// No XCD swizzle (R6 evidence: inputs L3-fit, swizzle cost 5%).
// Q pre-scaled by 0.125*log2(e). V written TRANSPOSED: Vt[bh][d][t].
__global__ __launch_bounds__(256, 4) void gemm_qkv_kernel(
    const float* __restrict__ X, const u16* __restrict__ BT, const float* __restrict__ bias,
    u16* __restrict__ Qb, u16* __restrict__ Kb, u16* __restrict__ Vt) {
  constexpr int K = 768;
  constexpr int NS = K / 32;  // 24 pipeline steps
  __shared__ u16 Asm[2][128 * 32];
  __shared__ u16 Bsm[2][128 * 32];
  const int tid = threadIdx.x;
  const int w = tid >> 6, lane = tid & 63;
  const int l15 = lane & 15, quad = lane >> 4;
  const int srow = tid >> 2, scol = (tid & 3) * 8;
  const int m0 = blockIdx.y * 128, n0 = blockIdx.x * 128;
  const float* Xg0 = X + (size_t)(m0 + srow) * K + scol;
  const float* Xg1 = X + (size_t)(m0 + 64 + srow) * K + scol;
  const u16* Bg = BT + (size_t)(n0 + srow) * K + scol;
  const int mw = (w >> 1) * 64, nw = (w & 1) * 64;
  f32x4 acc[4][4];
#pragma unroll
  for (int i = 0; i < 4; ++i)
#pragma unroll
    for (int j = 0; j < 4; ++j) acc[i][j] = {0.f, 0.f, 0.f, 0.f};

  f32x4 a0l, a0h, a1l, a1h;   // in-flight A (fp32), two 64-row halves
  auto LOADA = [&](int ks) {
    const float* p0 = Xg0 + ks * 32;
    const float* p1 = Xg1 + ks * 32;
    a0l = *(const f32x4*)p0; a0h = *(const f32x4*)(p0 + 4);
    a1l = *(const f32x4*)p1; a1h = *(const f32x4*)(p1 + 4);
  };
  auto WRITEA = [&](int buf) {
    u32x4 p0, p1;
    p0[0] = cvtpk(a0l[0], a0l[1]); p0[1] = cvtpk(a0l[2], a0l[3]);
    p0[2] = cvtpk(a0h[0], a0h[1]); p0[3] = cvtpk(a0h[2], a0h[3]);
    p1[0] = cvtpk(a1l[0], a1l[1]); p1[1] = cvtpk(a1l[2], a1l[3]);
    p1[2] = cvtpk(a1h[0], a1h[1]); p1[3] = cvtpk(a1h[2], a1h[3]);
    *(u32x4*)&Asm[buf][srow * 32 + scol] = p0;
    *(u32x4*)&Asm[buf][(64 + srow) * 32 + scol] = p1;
  };
  auto STAGEB = [&](int buf, int ks) {
    const u16* b = Bg + ks * 32;
    gll16(b, &Bsm[buf][(w * 16) * 32]);
    gll16(b + (size_t)64 * K, &Bsm[buf][(64 + w * 16) * 32]);
  };
  auto COMPUTE = [&](int buf) {
    bf16x8 af[4], bfj[4];
#pragma unroll
    for (int i = 0; i < 4; ++i) af[i] = *(const bf16x8*)&Asm[buf][(mw + i * 16 + l15) * 32 + quad * 8];
#pragma unroll
    for (int j = 0; j < 4; ++j) bfj[j] = *(const bf16x8*)&Bsm[buf][(nw + j * 16 + l15) * 32 + quad * 8];
#pragma unroll
    for (int i = 0; i < 4; ++i)
#pragma unroll
      for (int j = 0; j < 4; ++j)
        acc[i][j] = __builtin_amdgcn_mfma_f32_16x16x32_bf16(af[i], bfj[j], acc[i][j], 0, 0, 0);
  };

  // prologue: tile 0 -> buf0
  LOADA(0);
  STAGEB(0, 0);
  WRITEA(0);
  WAITVM(0); WAITLG(); SBAR();
  for (int s = 0; s < NS; ++s) {
    const int buf = s & 1;
    if (s + 1 < NS) { LOADA(s + 1); STAGEB(buf ^ 1, s + 1); }
    COMPUTE(buf);
    if (s + 1 < NS) WRITEA(buf ^ 1);
    WAITVM(0); WAITLG(); SBAR();
  }

  const int sec = blockIdx.x / 6;           // 0:Q 1:K 2:V (uniform per block; 768%128==0)
  const int nbase = n0 - sec * 768;
#pragma unroll
  for (int j = 0; j < 4; ++j) {
    const int nloc = nbase + nw + j * 16 + l15;
    const float bv = bias[sec * 768 + nloc];
    const int h = nloc >> 6, d = nloc & 63;
#pragma unroll
    for (int i = 0; i < 4; ++i) {
      const int m = m0 + mw + i * 16 + quad * 4;
      const int bb = m >> 11, trow = m & 2047;
      if (sec == 2) {
        u32x2 pk;
        pk[0] = cvtpk(acc[i][j][0] + bv, acc[i][j][1] + bv);
        pk[1] = cvtpk(acc[i][j][2] + bv, acc[i][j][3] + bv);
        *(u32x2*)(Vt + (size_t)((bb * 12 + h) * 64 + d) * 2048 + trow) = pk;
      } else {
        u16* dst = (sec == 0) ? Qb : Kb;
        const float scl = (sec == 0) ? 0.125f * 1.44269504f : 1.0f;
#pragma unroll
        for (int r = 0; r < 4; ++r)
          dst[(size_t)((bb * 12 + h) * 2048 + trow + r) * 64 + d] = f2bf((acc[i][j][r] + bv) * scl);
      }
    }
  }
}

// ---------------- proj GEMM: 64x128 tiles, minimum-2-phase BK=32, fp32 out + bias ----------------
// XCD-swizzled: grid 6x128 = 768 = 8*96. One barrier per step.
__global__ __launch_bounds__(256, 4) void gemm_proj_kernel(
    const u16* __restrict__ A, const u16* __restrict__ BT, const float* __restrict__ bias,
    float* __restrict__ out) {
  constexpr int K = 768;
  constexpr int NS = K / 32;
  __shared__ u16 Asm[2][64 * 32];
  __shared__ u16 Bsm[2][128 * 32];
  const int lin = blockIdx.y * 6 + blockIdx.x;
  const int swz = (lin & 7) * 96 + (lin >> 3);
  const int tid = threadIdx.x;
  const int w = tid >> 6, lane = tid & 63;
  const int l15 = lane & 15, quad = lane >> 4;
  const int srow = tid >> 2, scol = (tid & 3) * 8;
  const int m0 = (swz / 6) * 64, n0 = (swz % 6) * 128;
  const u16* Ag = A + (size_t)(m0 + srow) * K + scol;
  const u16* Bg = BT + (size_t)(n0 + srow) * K + scol;
  const int mw = (w >> 1) * 32, nw = (w & 1) * 64;
  f32x4 acc[2][4];
#pragma unroll
  for (int i = 0; i < 2; ++i)
#pragma unroll
    for (int j = 0; j < 4; ++j) acc[i][j] = {0.f, 0.f, 0.f, 0.f};

  auto STAGE = [&](int buf, int ks) {
    const u16* a = Ag + ks * 32;
    const u16* b = Bg + ks * 32;
    gll16(a, &Asm[buf][(w * 16) * 32]);
#pragma unroll
    for (int rb = 0; rb < 2; ++rb)
      gll16(b + (size_t)rb * 64 * K, &Bsm[buf][(rb * 64 + w * 16) * 32]);
  };
  auto COMPUTE = [&](int buf) {
    bf16x8 af[2], bfj[4];
#pragma unroll
    for (int i = 0; i < 2; ++i) af[i] = *(const bf16x8*)&Asm[buf][(mw + i * 16 + l15) * 32 + quad * 8];
#pragma unroll
    for (int j = 0; j < 4; ++j) bfj[j] = *(const bf16x8*)&Bsm[buf][(nw + j * 16 + l15) * 32 + quad * 8];
#pragma unroll
    for (int i = 0; i < 2; ++i)
#pragma unroll
      for (int j = 0; j < 4; ++j)
        acc[i][j] = __builtin_amdgcn_mfma_f32_16x16x32_bf16(af[i], bfj[j], acc[i][j], 0, 0, 0);
  };

  STAGE(0, 0);
  WAITVM(0); SBAR();
  for (int s = 0; s < NS; ++s) {
    const int buf = s & 1;
    if (s + 1 < NS) STAGE(buf ^ 1, s + 1);
    COMPUTE(buf);
    WAITVM(0); SBAR();
  }

#pragma unroll
  for (int j = 0; j < 4; ++j) {
    const int n = n0 + nw + j * 16 + l15;
    const float bv = bias[n];
#pragma unroll
    for (int i = 0; i < 2; ++i) {
      const int m = m0 + mw + i * 16 + quad * 4;
#pragma unroll
      for (int r = 0; r < 4; ++r) out[(size_t)(m + r) * 768 + n] = acc[i][j][r] + bv;
    }
  }
}

// ---------------- split-K causal flash attention, 8 waves / 128 q-rows per block ----------------
// Work unit: (bh, 128-q tile qt2 in 0..15, chunk c of <=8 k-tiles among nkt=2*qt2+2).
// 40 slots per bh. XCD-swizzled (T1): grid 40x48 = 1920 = 8*240; each XCD gets 6
// consecutive bh (3MB K/V, L2-resident); long-chunks-first preserved within each bh.
// 8 waves (512 thr); per-wave math identical to the 4-wave version (VGPR ~52).
// Waves 0-3 skip the block's final diagonal tile via wdiag guard (barriers uniform).
// P exchange in-register (T12); l-sum via ones-MFMA.
__global__ __launch_bounds__(512) void attn_split_kernel(
    const u16* __restrict__ Qg, const u16* __restrict__ Kg, const u16* __restrict__ Vtg,
    u16* __restrict__ Yb, float* __restrict__ Opart, float* __restrict__ lpart) {
  constexpr int T = 2048, D = 64;
  constexpr int LDP = 72;
  constexpr float MBOUND = 20.0f;
  __shared__ u16 Ks[2][64 * LDP];   // K tile  [k][d]
  __shared__ u16 VTs[2][64 * LDP];  // V^T tile [d][sigma(k)]
  const int lin = blockIdx.y * 40 + blockIdx.x;
  const int swzb = (lin & 7) * 240 + (lin >> 3);
  const int s = 39 - (swzb % 40);   // long chunks first (within each bh)
  const int bh = swzb / 40;
  int qt2, c;
  if (s < 4) { qt2 = s; c = 0; }
  else if (s < 12) { qt2 = 4 + ((s - 4) >> 1); c = (s - 4) & 1; }
  else if (s < 24) { int u = s - 12; int q3 = u / 3; qt2 = 8 + q3; c = u - 3 * q3; }
  else { int u = s - 24; qt2 = 12 + (u >> 2); c = u & 3; }
  const int nkt = 2 * qt2 + 2;
  const int niter = min(8, nkt - 8 * c);
  const int tid = threadIdx.x;
  const int w = tid >> 6, lane = tid & 63;
  const int l15 = lane & 15, quad = lane >> 4;
  // staging: 512 threads, one u32x4 (16B) each for K and V
  const int srow = tid >> 3;                // 0..63
  const int scol = (tid & 7) * 8;           // u16 units
  const int so0 = scol - 4 * (tid & 1);     // sigma dest for lo half
  const int so1 = scol + 8 - 4 * (tid & 1); // sigma dest for hi half
  const u16* Kp = Kg + (size_t)bh * T * D;
  const u16* VTp = Vtg + (size_t)bh * D * T;

  // per-wave role: rows qq; diagonal tile index for this wave
  const int wdiag = 2 * qt2 + (w >> 2);
  const int qq = qt2 * 128 + w * 16 + l15;
  const u16* qrow = Qg + ((size_t)bh * T + qq) * D;
  const bf16x8 qfa = *(const bf16x8*)(qrow + quad * 8);
  const bf16x8 qfb = *(const bf16x8*)(qrow + 32 + quad * 8);

  // all-ones bf16 A-operand for the l-sum MFMA
  u32x4 onesw; onesw[0] = 0x3F803F80u; onesw[1] = 0x3F803F80u; onesw[2] = 0x3F803F80u; onesw[3] = 0x3F803F80u;
  const bf16x8 ones = __builtin_bit_cast(bf16x8, onesw);

  f32x4 o[4] = {{0,0,0,0},{0,0,0,0},{0,0,0,0},{0,0,0,0}};  // O^T: row=d, col=q=l15
  f32x4 lacc = {0.f, 0.f, 0.f, 0.f};                       // l via ones-MFMA

  u32x4 kA, vA;
  auto LOADT = [&](int kt) {
    const int k1 = kt * 64;
    kA = *(const u32x4*)(Kp + (size_t)(k1 + srow) * D + scol);
    vA = *(const u32x4*)(VTp + (size_t)srow * T + k1 + scol);
  };
  auto STORET = [&](int buf) {
    *(u32x4*)&Ks[buf][srow * LDP + scol] = kA;
    u32x2 vlo; vlo[0] = vA[0]; vlo[1] = vA[1];
    u32x2 vhi; vhi[0] = vA[2]; vhi[1] = vA[3];
    *(u32x2*)&VTs[buf][srow * LDP + so0] = vlo;
    *(u32x2*)&VTs[buf][srow * LDP + so1] = vhi;
  };

  // prologue: tile 0 -> buf0; prefetch tile 1
  LOADT(c * 8);
  STORET(0);
  if (niter > 1) LOADT(c * 8 + 1);
  __syncthreads();

  for (int j = 0; j < niter; ++j) {
    const int buf = j & 1;
    const int ktg = c * 8 + j;
    if (ktg <= wdiag) {
      // S^T = K.Q^T : C-layout row = k_local = 16t+quad*4+r, col = q = l15
      f32x4 sA[4];
#pragma unroll
      for (int t = 0; t < 4; ++t) sA[t] = {-MBOUND, -MBOUND, -MBOUND, -MBOUND};
      __builtin_amdgcn_s_setprio(1);
#pragma unroll
      for (int t = 0; t < 4; ++t) {
        const bf16x8 kf0 = *(const bf16x8*)&Ks[buf][(t * 16 + l15) * LDP + quad * 8];
        const bf16x8 kf1 = *(const bf16x8*)&Ks[buf][(t * 16 + l15) * LDP + 32 + quad * 8];
        sA[t] = __builtin_amdgcn_mfma_f32_16x16x32_bf16(kf0, qfa, sA[t], 0, 0, 0);
        sA[t] = __builtin_amdgcn_mfma_f32_16x16x32_bf16(kf1, qfb, sA[t], 0, 0, 0);
      }
      __builtin_amdgcn_s_setprio(0);
      if (ktg == wdiag) {  // this wave's diagonal tile: causal mask
        const int k0 = ktg * 64;
#pragma unroll
        for (int t = 0; t < 4; ++t)
#pragma unroll
          for (int r = 0; r < 4; ++r)
            if (k0 + t * 16 + quad * 4 + r > qq) sA[t][r] = -1e30f;
      }
      // fixed-max softmax: p = 2^(s-M) (M folded into acc init), packed in-register
      unsigned W[4][2];
#pragma unroll
      for (int t = 0; t < 4; ++t) {
        float e0 = __builtin_amdgcn_exp2f(sA[t][0]);
        float e1 = __builtin_amdgcn_exp2f(sA[t][1]);
        float e2 = __builtin_amdgcn_exp2f(sA[t][2]);
        float e3 = __builtin_amdgcn_exp2f(sA[t][3]);
        W[t][0] = cvtpk(e0, e1);
        W[t][1] = cvtpk(e2, e3);
      }
      plswap(W[0][0], W[1][0]);
      plswap(W[0][1], W[1][1]);
      plswap(W[2][0], W[3][0]);
      plswap(W[2][1], W[3][1]);
      u32x4 paw; paw[0] = W[0][0]; paw[1] = W[0][1]; paw[2] = W[1][0]; paw[3] = W[1][1];
      u32x4 pbw; pbw[0] = W[2][0]; pbw[1] = W[2][1]; pbw[2] = W[3][0]; pbw[3] = W[3][1];
      const bf16x8 pa = __builtin_bit_cast(bf16x8, paw);
      const bf16x8 pb = __builtin_bit_cast(bf16x8, pbw);
      // O^T += V^T.P^T ; l += ones.P^T
      __builtin_amdgcn_s_setprio(1);
      lacc = __builtin_amdgcn_mfma_f32_16x16x32_bf16(ones, pa, lacc, 0, 0, 0);
      lacc = __builtin_amdgcn_mfma_f32_16x16x32_bf16(ones, pb, lacc, 0, 0, 0);
#pragma unroll
      for (int t = 0; t < 4; ++t) {
        const bf16x8 vf0 = *(const bf16x8*)&VTs[buf][(t * 16 + l15) * LDP + quad * 8];
        const bf16x8 vf1 = *(const bf16x8*)&VTs[buf][(t * 16 + l15) * LDP + 32 + quad * 8];
        o[t] = __builtin_amdgcn_mfma_f32_16x16x32_bf16(vf0, pa, o[t], 0, 0, 0);
        o[t] = __builtin_amdgcn_mfma_f32_16x16x32_bf16(vf1, pb, o[t], 0, 0, 0);
      }
      __builtin_amdgcn_s_setprio(0);
    }
    // stage tile j+1 into the other buffer; prefetch tile j+2
    if (j + 1 < niter) {
      STORET(buf ^ 1);
      if (j + 2 < niter) LOADT(c * 8 + j + 2);
    }
    __syncthreads();
  }

  const float lv = lacc[0];   // every lane holds the full 64-wide sum for its q
  if (qt2 <= 3) {
    // single chunk: normalize + write Yb directly
    const float inv = 1.f / lv;
    const int bidx = bh / 12, hidx = bh % 12;
    u16* y = Yb + ((size_t)bidx * T + qq) * 768 + hidx * 64;
#pragma unroll
    for (int t = 0; t < 4; ++t) {
      u32x2 pk;
      pk[0] = cvtpk(o[t][0] * inv, o[t][1] * inv);
      pk[1] = cvtpk(o[t][2] * inv, o[t][3] * inv);
      *(u32x2*)(y + t * 16 + quad * 4) = pk;
    }
  } else {
    // write unnormalized partials: Opart[pidx][q(128)][d(64)] fp32, lpart[pidx][q(128)]
    const size_t pidx = (size_t)bh * 40 + s;
    float* Op = Opart + pidx * 8192 + (size_t)(w * 16 + l15) * 64;
#pragma unroll
    for (int t = 0; t < 4; ++t) *(f32x4*)(Op + t * 16 + quad * 4) = o[t];
    if (quad == 0) lpart[pidx * 128 + w * 16 + l15] = lv;
  }
}

// ---------------- combine partials for qt2 >= 4 ----------------
__global__ __launch_bounds__(256) void attn_combine_kernel(
    const float* __restrict__ Opart, const float* __restrict__ lpart, u16* __restrict__ Yb) {
  constexpr int T = 2048;
  const int qt2 = 4 + blockIdx.x;   // 4..15
  const int bh = blockIdx.y;
  const int nch = (qt2 < 8) ? 2 : (qt2 < 12) ? 3 : 4;
  const int off = (qt2 < 8) ? 4 + (qt2 - 4) * 2 : (qt2 < 12) ? 12 + (qt2 - 8) * 3 : 24 + (qt2 - 12) * 4;
  const size_t base = (size_t)bh * 40 + off;
  const int tid = threadIdx.x;
  const int q = tid >> 1, db = (tid & 1) * 32;   // 128 q rows x 2 d-halves
  f32x4 o[8] = {{0,0,0,0},{0,0,0,0},{0,0,0,0},{0,0,0,0},{0,0,0,0},{0,0,0,0},{0,0,0,0},{0,0,0,0}};
  float l = 0.f;
  for (int cc = 0; cc < nch; ++cc) {
    const float* Op = Opart + (base + cc) * 8192 + (size_t)q * 64 + db;
#pragma unroll
    for (int v = 0; v < 8; ++v) o[v] += *(const f32x4*)(Op + v * 4);
    l += lpart[(base + cc) * 128 + q];
  }
  const float inv = 1.f / l;
  const int bidx = bh / 12, hidx = bh % 12;
  u16* y = Yb + ((size_t)bidx * T + qt2 * 128 + q) * 768 + hidx * 64 + db;
#pragma unroll
  for (int g = 0; g < 2; ++g) {
    u32x4 pk;
    pk[0] = cvtpk(o[g * 4 + 0][0] * inv, o[g * 4 + 0][1] * inv);
    pk[1] = cvtpk(o[g * 4 + 0][2] * inv, o[g * 4 + 0][3] * inv);
    pk[2] = cvtpk(o[g * 4 + 1][0] * inv, o[g * 4 + 1][1] * inv);
    pk[3] = cvtpk(o[g * 4 + 1][2] * inv, o[g * 4 + 1][3] * inv);
    *(u32x4*)(y + g * 16) = pk;
    pk[0] = cvtpk(o[g * 4 + 2][0] * inv, o[g * 4 + 2][1] * inv);
    pk[1] = cvtpk(o[g * 4 + 2][2] * inv, o[g * 4 + 2][3] * inv);
    pk[2] = cvtpk(o[g * 4 + 3][0] * inv, o[g * 4 + 3][1] * inv);
    pk[3] = cvtpk(o[g * 4 + 3][2] * inv, o[g * 4 + 3][3] * inv);
    *(u32x4*)(y + g * 16 + 8) = pk;
  }
}

// ---------------- fallback: round-7 attention (used if ws too small) ----------------
// NOTE: fallback needs bf16 Q/K/V which gemm_qkv still produces; it does not use xb.
__global__ __launch_bounds__(256) void attn_kernel(
    const u16* __restrict__ Qg, const u16* __restrict__ Kg, const u16* __restrict__ Vtg,
    u16* __restrict__ Yb) {
  constexpr int T = 2048, D = 64;
  constexpr int LDP = 72;
  constexpr float MBOUND = 20.0f;
  __shared__ u16 Ks[64 * LDP];
  __shared__ u16 VTs[64 * LDP];
  __shared__ u16 Ps[4 * 32 * LDP];
  const int qb = 15 - blockIdx.x;
  const int bh = blockIdx.y;
  const int Q0 = qb * 128;
  const int bidx = bh / 12, hidx = bh % 12;
  const int tid = threadIdx.x;
  const int w = tid >> 6, lane = tid & 63;
  const int l15 = lane & 15, quad = lane >> 4;
  const int srow = tid >> 2, scol = (tid & 3) * 16;
  const u16* Kp = Kg + (size_t)bh * T * D;
  const u16* VTp = Vtg + (size_t)bh * D * T;
  u16* pw0 = &Ps[(w * 32) * LDP];
  u16* pw1 = &Ps[(w * 32 + 16) * LDP];
  const u16* qrow0 = Qg + ((size_t)bh * T + Q0 + w * 16 + l15) * D;
  const bf16x8 qf0a = *(const bf16x8*)(qrow0 + quad * 8);
  const bf16x8 qf0b = *(const bf16x8*)(qrow0 + 32 + quad * 8);
  const bf16x8 qf1a = *(const bf16x8*)(qrow0 + (size_t)64 * D + quad * 8);
  const bf16x8 qf1b = *(const bf16x8*)(qrow0 + (size_t)64 * D + 32 + quad * 8);
  const int qq0 = Q0 + w * 16 + l15, qq1 = qq0 + 64;
  f32x4 o0[4] = {{0,0,0,0},{0,0,0,0},{0,0,0,0},{0,0,0,0}};
  f32x4 o1[4] = {{0,0,0,0},{0,0,0,0},{0,0,0,0},{0,0,0,0}};
  float l0v = 0.f, l1v = 0.f;
  const int nkt = 2 * qb + 2;
  u32x4 kA = *(const u32x4*)(Kp + (size_t)srow * D + scol);
  u32x4 kB = *(const u32x4*)(Kp + (size_t)srow * D + scol + 8);
  u32x4 vA = *(const u32x4*)(VTp + (size_t)srow * T + scol);
  u32x4 vB = *(const u32x4*)(VTp + (size_t)srow * T + scol + 8);
  for (int kt = 0; kt < nkt; ++kt) {
    __syncthreads();
    *(u32x4*)&Ks[srow * LDP + scol] = kA;
    *(u32x4*)&Ks[srow * LDP + scol + 8] = kB;
    *(u32x4*)&VTs[srow * LDP + scol] = vA;
    *(u32x4*)&VTs[srow * LDP + scol + 8] = vB;
    __syncthreads();
    if (kt + 1 < nkt) {
      const int k1 = (kt + 1) * 64;
      kA = *(const u32x4*)(Kp + (size_t)(k1 + srow) * D + scol);
      kB = *(const u32x4*)(Kp + (size_t)(k1 + srow) * D + scol + 8);
      vA = *(const u32x4*)(VTp + (size_t)srow * T + k1 + scol);
      vB = *(const u32x4*)(VTp + (size_t)srow * T + k1 + scol + 8);
    }
    const int k0 = kt * 64;
    const bool g0a = (kt <= 2 * qb);
    f32x4 s0[4] = {{0,0,0,0},{0,0,0,0},{0,0,0,0},{0,0,0,0}};
    f32x4 s1[4] = {{0,0,0,0},{0,0,0,0},{0,0,0,0},{0,0,0,0}};
#pragma unroll
    for (int t = 0; t < 4; ++t) {
      const bf16x8 kf0 = *(const bf16x8*)&Ks[(t * 16 + l15) * LDP + quad * 8];
      const bf16x8 kf1 = *(const bf16x8*)&Ks[(t * 16 + l15) * LDP + 32 + quad * 8];
      s0[t] = __builtin_amdgcn_mfma_f32_16x16x32_bf16(kf0, qf0a, s0[t], 0, 0, 0);
      s0[t] = __builtin_amdgcn_mfma_f32_16x16x32_bf16(kf1, qf0b, s0[t], 0, 0, 0);
      s1[t] = __builtin_amdgcn_mfma_f32_16x16x32_bf16(kf0, qf1a, s1[t], 0, 0, 0);
      s1[t] = __builtin_amdgcn_mfma_f32_16x16x32_bf16(kf1, qf1b, s1[t], 0, 0, 0);
    }
    if (g0a) {
      if (kt == 2 * qb) {
#pragma unroll
        for (int t = 0; t < 4; ++t)
#pragma unroll
          for (int r = 0; r < 4; ++r)
            if (k0 + t * 16 + quad * 4 + r > qq0) s0[t][r] = -1e30f;
      }
#pragma unroll
      for (int t = 0; t < 4; ++t) {
        float e0 = __builtin_amdgcn_exp2f(s0[t][0] - MBOUND);
        float e1 = __builtin_amdgcn_exp2f(s0[t][1] - MBOUND);
        float e2 = __builtin_amdgcn_exp2f(s0[t][2] - MBOUND);
        float e3 = __builtin_amdgcn_exp2f(s0[t][3] - MBOUND);
        l0v += (e0 + e1) + (e2 + e3);
        u32x2 pk;
        pk[0] = cvtpk(e0, e1);
        pk[1] = cvtpk(e2, e3);
        *(u32x2*)&pw0[l15 * LDP + t * 16 + quad * 4] = pk;
      }
    }
    {
      if (kt == 2 * qb + 1) {
#pragma unroll
        for (int t = 0; t < 4; ++t)
#pragma unroll
          for (int r = 0; r < 4; ++r)
            if (k0 + t * 16 + quad * 4 + r > qq1) s1[t][r] = -1e30f;
      }
#pragma unroll
      for (int t = 0; t < 4; ++t) {
        float e0 = __builtin_amdgcn_exp2f(s1[t][0] - MBOUND);
        float e1 = __builtin_amdgcn_exp2f(s1[t][1] - MBOUND);
        float e2 = __builtin_amdgcn_exp2f(s1[t][2] - MBOUND);
        float e3 = __builtin_amdgcn_exp2f(s1[t][3] - MBOUND);
        l1v += (e0 + e1) + (e2 + e3);
        u32x2 pk;
        pk[0] = cvtpk(e0, e1);
        pk[1] = cvtpk(e2, e3);
        *(u32x2*)&pw1[l15 * LDP + t * 16 + quad * 4] = pk;
      }
    }
    const bf16x8 p0a = *(const bf16x8*)&pw0[l15 * LDP + quad * 8];
    const bf16x8 p0b = *(const bf16x8*)&pw0[l15 * LDP + 32 + quad * 8];
    const bf16x8 p1a = *(const bf16x8*)&pw1[l15 * LDP + quad * 8];
    const bf16x8 p1b = *(const bf16x8*)&pw1[l15 * LDP + 32 + quad * 8];
#pragma unroll
    for (int t = 0; t < 4; ++t) {
      const bf16x8 vf0 = *(const bf16x8*)&VTs[(t * 16 + l15) * LDP + quad * 8];
      const bf16x8 vf1 = *(const bf16x8*)&VTs[(t * 16 + l15) * LDP + 32 + quad * 8];
      if (g0a) {
        o0[t] = __builtin_amdgcn_mfma_f32_16x16x32_bf16(vf0, p0a, o0[t], 0, 0, 0);
        o0[t] = __builtin_amdgcn_mfma_f32_16x16x32_bf16(vf1, p0b, o0[t], 0, 0, 0);
      }
      o1[t] = __builtin_amdgcn_mfma_f32_16x16x32_bf16(vf0, p1a, o1[t], 0, 0, 0);
      o1[t] = __builtin_amdgcn_mfma_f32_16x16x32_bf16(vf1, p1b, o1[t], 0, 0, 0);
    }
  }
  l0v += __shfl_xor(l0v, 16); l0v += __shfl_xor(l0v, 32);
  l1v += __shfl_xor(l1v, 16); l1v += __shfl_xor(l1v, 32);
  const float inv0 = 1.f / l0v, inv1 = 1.f / l1v;
  u16* y0 = Yb + ((size_t)bidx * T + qq0) * 768 + hidx * 64;
  u16* y1 = Yb + ((size_t)bidx * T + qq1) * 768 + hidx * 64;
#pragma unroll
  for (int t = 0; t < 4; ++t) {
    u32x2 pk0, pk1;
    pk0[0] = cvtpk(o0[t][0] * inv0, o0[t][1] * inv0);
    pk0[1] = cvtpk(o0[t][2] * inv0, o0[t][3] * inv0);
    pk1[0] = cvtpk(o1[t][0] * inv1, o1[t][1] * inv1);
    pk1[1] = cvtpk(o1[t][2] * inv1, o1[t][3] * inv1);
    *(u32x2*)(y0 + t * 16 + quad * 4) = pk0;
    *(u32x2*)(y1 + t * 16 + quad * 4) = pk1;
  }
}

extern "C" void kernel_launch(void* const* d_in, const int* in_sizes, int n_in,
                              void* d_out, int out_size, void* d_ws, size_t ws_size,
                              hipStream_t stream) {
  const float* x = (const float*)d_in[0];
  const float* W_qkv = (const float*)d_in[1];
  const float* b_qkv = (const float*)d_in[2];
  const float* W_proj = (const float*)d_in[3];
  const float* b_proj = (const float*)d_in[4];
  float* out = (float*)d_out;

  constexpr size_t MC = (size_t)8192 * 768;
  u16* xb = (u16*)d_ws;          // region kept for layout compat (unused now)
  u16* Qb = xb + MC;
  u16* Kb = Qb + MC;
  u16* Vt = Kb + MC;   // transposed V: [bh][d][t]
  u16* Yb = Vt + MC;
  u16* WqkvT = Yb + MC;
  u16* WprojT = WqkvT + (size_t)2304 * 768;
  // split-K partials (after the bf16 region); 1920*8192 == 3840*4096 (same bytes)
  constexpr size_t BASE_U16 = 5 * MC + (size_t)2304 * 768 + (size_t)768 * 768;  // 33,816,576
  float* Opart = (float*)((u16*)d_ws + BASE_U16);
  float* lpart = Opart + (size_t)1920 * 8192;
  constexpr size_t NEED = BASE_U16 * 2 + ((size_t)1920 * 8192 + (size_t)1920 * 128) * 4;
  const bool use_split = (ws_size >= NEED);

  transpose_cast_kernel<<<dim3(2304 / 32, 768 / 32), 256, 0, stream>>>(W_qkv, WqkvT, 768, 2304);
  transpose_cast_kernel<<<dim3(768 / 32, 768 / 32), 256, 0, stream>>>(W_proj, WprojT, 768, 768);
  gemm_qkv_kernel<<<dim3(18, 64), 256, 0, stream>>>(x, WqkvT, b_qkv, Qb, Kb, Vt);
  if (use_split) {
    attn_split_kernel<<<dim3(40, 48), 512, 0, stream>>>(Qb, Kb, Vt, Yb, Opart, lpart);
    attn_combine_kernel<<<dim3(12, 48), 256, 0, stream>>>(Opart, lpart, Yb);
  } else {
    attn_kernel<<<dim3(16, 48), 256, 0, stream>>>(Qb, Kb, Vt, Yb);
  }
  gemm_proj_kernel<<<dim3(6, 128), 256, 0, stream>>>(Yb, WprojT, b_proj, out);
}

// Round 8
// 239.854 us; speedup vs baseline: 1.0428x; 1.0428x over previous
//
#include <hip/hip_runtime.h>
#include <hip/hip_bf16.h>

typedef __bf16 bf16x8 __attribute__((ext_vector_type(8)));
typedef float f32x4 __attribute__((ext_vector_type(4)));
typedef unsigned int u32x4 __attribute__((ext_vector_type(4)));
typedef unsigned int u32x2 __attribute__((ext_vector_type(2)));
typedef int i32x2 __attribute__((ext_vector_type(2)));
typedef unsigned short u16;
typedef unsigned long long u64;

#define WAITVM(n) asm volatile("s_waitcnt vmcnt(" #n ")" ::: "memory")
#define SBAR() asm volatile("s_barrier" ::: "memory")

__device__ __forceinline__ u16 f2bf(float f) {
  unsigned u = __builtin_bit_cast(unsigned, f);
  u += 0x7FFFu + ((u >> 16) & 1u);   // RNE
  return (u16)(u >> 16);
}
// HW packed convert: 2 fp32 -> 2 bf16 (v_cvt_pk_bf16_f32, RNE)
__device__ __forceinline__ unsigned cvtpk(float a, float b) {
  float2 f; f.x = a; f.y = b;
  __hip_bfloat162 h = __float22bfloat162_rn(f);
  unsigned u;
  __builtin_memcpy(&u, &h, 4);
  return u;
}

// v_permlane32_swap_b32: after call, a = [a.lo ; b.lo], b = [a.hi ; b.hi]
__device__ __forceinline__ void plswap(unsigned &a, unsigned &b) {
  i32x2 r = __builtin_amdgcn_permlane32_swap((int)a, (int)b, false, false);
  a = (unsigned)r[0];
  b = (unsigned)r[1];
}

// async global->LDS direct copy, 16B per lane. LDS dest = wave-uniform base + lane*16.
__device__ __forceinline__ void gll16(const u16* g, u16* l) {
  __builtin_amdgcn_global_load_lds(
      (const __attribute__((address_space(1))) unsigned int*)g,
      (__attribute__((address_space(3))) unsigned int*)l, 16, 0, 0);
}

// ---------------- cast x (fp32 -> bf16), vectorized ----------------
__global__ void cast_x_kernel(const float* __restrict__ in, u16* __restrict__ out, int n4) {
  int i = blockIdx.x * blockDim.x + threadIdx.x;
  if (i >= n4) return;
  f32x4 v = *(const f32x4*)(in + (size_t)i * 4);
  u32x2 pk;
  pk[0] = cvtpk(v[0], v[1]);
  pk[1] = cvtpk(v[2], v[3]);
  *(u32x2*)(out + (size_t)i * 4) = pk;
}

// ------------- transpose + cast: W[K][N] fp32 -> WT[N][K] bf16 -------------
__global__ void transpose_cast_kernel(const float* __restrict__ W, u16* __restrict__ WT, int K, int N) {
  __shared__ float tile[32][33];
  int c0 = blockIdx.x * 32, r0 = blockIdx.y * 32;
  int tx = threadIdx.x & 31, tg = threadIdx.x >> 5;
#pragma unroll
  for (int i = 0; i < 4; ++i) {
    int r = tg + i * 8;
    tile[r][tx] = W[(size_t)(r0 + r) * N + c0 + tx];
  }
  __syncthreads();
#pragma unroll
  for (int i = 0; i < 4; ++i) {
    int r = tg + i * 8;
    WT[(size_t)(c0 + r) * K + r0 + tx] = f2bf(tile[tx][r]);
  }
}

// ---------------- QKV GEMM: [8192x768] x [768x2304], 256x128 tile, 8 waves ----------------
// Pipelined 2-phase, BK=32, 24 steps, counted s_waitcnt vmcnt(3) (3 gll16/thread/step).
// 256-row m-tile: one staging+barrier pair feeds 128 wave-MFMA (2x the 128-tile), B panel
// refetched by 32 m-blocks (was 64). Per-wave state unchanged (64x64 output, acc 64 VGPR).
// LDS 48KB -> 3 blocks x 8 waves = 24 waves/CU. No XCD swizzle (R6: L3-fit, swizzle hurt).
// Q pre-scaled by 0.125*log2(e). V written TRANSPOSED: Vt[bh][d][t].
__global__ __launch_bounds__(512) void gemm_qkv_kernel(
    const u16* __restrict__ A, const u16* __restrict__ BT, const float* __restrict__ bias,
    u16* __restrict__ Qb, u16* __restrict__ Kb, u16* __restrict__ Vt) {
  constexpr int K = 768;
  constexpr int NS = K / 32;  // 24 pipeline steps
  __shared__ u16 Asm[2][256 * 32];
  __shared__ u16 Bsm[2][128 * 32];
  const int tid = threadIdx.x;
  const int w = tid >> 6, lane = tid & 63;
  const int l15 = lane & 15, quad = lane >> 4;
  const int srow = tid >> 2, scol = (tid & 3) * 8;   // srow 0..127
  const int m0 = blockIdx.y * 256, n0 = blockIdx.x * 128;
  const u16* Ag = A + (size_t)(m0 + srow) * K + scol;
  const u16* Bg = BT + (size_t)(n0 + (srow & 127)) * K + scol;
  const int mw = (w >> 1) * 64, nw = (w & 1) * 64;   // wave grid 4(m) x 2(n)
  f32x4 acc[4][4];
#pragma unroll
  for (int i = 0; i < 4; ++i)
#pragma unroll
    for (int j = 0; j < 4; ++j) acc[i][j] = {0.f, 0.f, 0.f, 0.f};

  auto STAGE = [&](int buf, int ks) {
    const u16* a = Ag + ks * 32;
    // A: 256x32 via 2 calls (128 rows each); per-wave LDS base + lane*16
    gll16(a, &Asm[buf][(w * 16) * 32]);
    gll16(a + (size_t)128 * K, &Asm[buf][(128 + w * 16) * 32]);
    // B: 128x32 via 1 call across all 8 waves
    gll16(Bg + ks * 32, &Bsm[buf][(w * 16) * 32]);
  };
  auto COMPUTE = [&](int buf) {
    bf16x8 af[4], bfj[4];
#pragma unroll
    for (int i = 0; i < 4; ++i) af[i] = *(const bf16x8*)&Asm[buf][(mw + i * 16 + l15) * 32 + quad * 8];
#pragma unroll
    for (int j = 0; j < 4; ++j) bfj[j] = *(const bf16x8*)&Bsm[buf][(nw + j * 16 + l15) * 32 + quad * 8];
#pragma unroll
    for (int i = 0; i < 4; ++i)
#pragma unroll
      for (int j = 0; j < 4; ++j)
        acc[i][j] = __builtin_amdgcn_mfma_f32_16x16x32_bf16(af[i], bfj[j], acc[i][j], 0, 0, 0);
  };

  STAGE(0, 0);
  for (int s = 0; s + 2 < NS; s += 2) {
    STAGE(1, s + 1); WAITVM(3); SBAR(); COMPUTE(0); SBAR();
    STAGE(0, s + 2); WAITVM(3); SBAR(); COMPUTE(1); SBAR();
  }
  STAGE(1, NS - 1); WAITVM(3); SBAR(); COMPUTE(0);
  WAITVM(0); SBAR(); COMPUTE(1);

  const int sec = blockIdx.x / 6;           // 0:Q 1:K 2:V (uniform per block; 768%128==0)
  const int nbase = n0 - sec * 768;
#pragma unroll
  for (int j = 0; j < 4; ++j) {
    const int nloc = nbase + nw + j * 16 + l15;
    const float bv = bias[sec * 768 + nloc];
    const int h = nloc >> 6, d = nloc & 63;
#pragma unroll
    for (int i = 0; i < 4; ++i) {
      const int m = m0 + mw + i * 16 + quad * 4;
      const int bb = m >> 11, trow = m & 2047;
      if (sec == 2) {
        u32x2 pk;
        pk[0] = cvtpk(acc[i][j][0] + bv, acc[i][j][1] + bv);
        pk[1] = cvtpk(acc[i][j][2] + bv, acc[i][j][3] + bv);
        *(u32x2*)(Vt + (size_t)((bb * 12 + h) * 64 + d) * 2048 + trow) = pk;
      } else {
        u16* dst = (sec == 0) ? Qb : Kb;
        const float scl = (sec == 0) ? 0.125f * 1.44269504f : 1.0f;
#pragma unroll
        for (int r = 0; r < 4; ++r)
          dst[(size_t)((bb * 12 + h) * 2048 + trow + r) * 64 + d] = f2bf((acc[i][j][r] + bv) * scl);
      }
    }
  }
}

// ---------------- proj GEMM: 64x128 tiles, minimum-2-phase BK=32, fp32 out + bias ----------------
// XCD-swizzled: grid 6x128 = 768 = 8*96. One barrier per step.
__global__ __launch_bounds__(256, 4) void gemm_proj_kernel(
    const u16* __restrict__ A, const u16* __restrict__ BT, const float* __restrict__ bias,
    float* __restrict__ out) {
  constexpr int K = 768;
  constexpr int NS = K / 32;
  __shared__ u16 Asm[2][64 * 32];
  __shared__ u16 Bsm[2][128 * 32];
  const int lin = blockIdx.y * 6 + blockIdx.x;
  const int swz = (lin & 7) * 96 + (lin >> 3);
  const int tid = threadIdx.x;
  const int w = tid >> 6, lane = tid & 63;
  const int l15 = lane & 15, quad = lane >> 4;
  const int srow = tid >> 2, scol = (tid & 3) * 8;
  const int m0 = (swz / 6) * 64, n0 = (swz % 6) * 128;
  const u16* Ag = A + (size_t)(m0 + srow) * K + scol;
  const u16* Bg = BT + (size_t)(n0 + srow) * K + scol;
  const int mw = (w >> 1) * 32, nw = (w & 1) * 64;
  f32x4 acc[2][4];
#pragma unroll
  for (int i = 0; i < 2; ++i)
#pragma unroll
    for (int j = 0; j < 4; ++j) acc[i][j] = {0.f, 0.f, 0.f, 0.f};

  auto STAGE = [&](int buf, int ks) {
    const u16* a = Ag + ks * 32;
    const u16* b = Bg + ks * 32;
    gll16(a, &Asm[buf][(w * 16) * 32]);
#pragma unroll
    for (int rb = 0; rb < 2; ++rb)
      gll16(b + (size_t)rb * 64 * K, &Bsm[buf][(rb * 64 + w * 16) * 32]);
  };
  auto COMPUTE = [&](int buf) {
    bf16x8 af[2], bfj[4];
#pragma unroll
    for (int i = 0; i < 2; ++i) af[i] = *(const bf16x8*)&Asm[buf][(mw + i * 16 + l15) * 32 + quad * 8];
#pragma unroll
    for (int j = 0; j < 4; ++j) bfj[j] = *(const bf16x8*)&Bsm[buf][(nw + j * 16 + l15) * 32 + quad * 8];
#pragma unroll
    for (int i = 0; i < 2; ++i)
#pragma unroll
      for (int j = 0; j < 4; ++j)
        acc[i][j] = __builtin_amdgcn_mfma_f32_16x16x32_bf16(af[i], bfj[j], acc[i][j], 0, 0, 0);
  };

  STAGE(0, 0);
  WAITVM(0); SBAR();
  for (int s = 0; s < NS; ++s) {
    const int buf = s & 1;
    if (s + 1 < NS) STAGE(buf ^ 1, s + 1);
    COMPUTE(buf);
    WAITVM(0); SBAR();
  }

#pragma unroll
  for (int j = 0; j < 4; ++j) {
    const int n = n0 + nw + j * 16 + l15;
    const float bv = bias[n];
#pragma unroll
    for (int i = 0; i < 2; ++i) {
      const int m = m0 + mw + i * 16 + quad * 4;
#pragma unroll
      for (int r = 0; r < 4; ++r) out[(size_t)(m + r) * 768 + n] = acc[i][j][r] + bv;
    }
  }
}

// ---------------- split-K causal flash attention, 8 waves / 128 q-rows per block ----------------
// Work unit: (bh, 128-q tile qt2 in 0..15, chunk c of <=8 k-tiles among nkt=2*qt2+2).
// 40 slots per bh. XCD-swizzled (T1): grid 40x48 = 1920 = 8*240; each XCD gets 6
// consecutive bh (3MB K/V, L2-resident); long-chunks-first preserved within each bh.
// 8 waves (512 thr); per-wave math identical to the 4-wave version (VGPR ~52).
// Waves 0-3 skip the block's final diagonal tile via wdiag guard (barriers uniform).
// P exchange in-register (T12); l-sum via ones-MFMA.
__global__ __launch_bounds__(512) void attn_split_kernel(
    const u16* __restrict__ Qg, const u16* __restrict__ Kg, const u16* __restrict__ Vtg,
    u16* __restrict__ Yb, float* __restrict__ Opart, float* __restrict__ lpart) {
  constexpr int T = 2048, D = 64;
  constexpr int LDP = 72;
  constexpr float MBOUND = 20.0f;
  __shared__ u16 Ks[2][64 * LDP];   // K tile  [k][d]
  __shared__ u16 VTs[2][64 * LDP];  // V^T tile [d][sigma(k)]
  const int lin = blockIdx.y * 40 + blockIdx.x;
  const int swzb = (lin & 7) * 240 + (lin >> 3);
  const int s = 39 - (swzb % 40);   // long chunks first (within each bh)
  const int bh = swzb / 40;
  int qt2, c;
  if (s < 4) { qt2 = s; c = 0; }
  else if (s < 12) { qt2 = 4 + ((s - 4) >> 1); c = (s - 4) & 1; }
  else if (s < 24) { int u = s - 12; int q3 = u / 3; qt2 = 8 + q3; c = u - 3 * q3; }
  else { int u = s - 24; qt2 = 12 + (u >> 2); c = u & 3; }
  const int nkt = 2 * qt2 + 2;
  const int niter = min(8, nkt - 8 * c);
  const int tid = threadIdx.x;
  const int w = tid >> 6, lane = tid & 63;
  const int l15 = lane & 15, quad = lane >> 4;
  // staging: 512 threads, one u32x4 (16B) each for K and V
  const int srow = tid >> 3;                // 0..63
  const int scol = (tid & 7) * 8;           // u16 units
  const int so0 = scol - 4 * (tid & 1);     // sigma dest for lo half
  const int so1 = scol + 8 - 4 * (tid & 1); // sigma dest for hi half
  const u16* Kp = Kg + (size_t)bh * T * D;
  const u16* VTp = Vtg + (size_t)bh * D * T;

  // per-wave role: rows qq; diagonal tile index for this wave
  const int wdiag = 2 * qt2 + (w >> 2);
  const int qq = qt2 * 128 + w * 16 + l15;
  const u16* qrow = Qg + ((size_t)bh * T + qq) * D;
  const bf16x8 qfa = *(const bf16x8*)(qrow + quad * 8);
  const bf16x8 qfb = *(const bf16x8*)(qrow + 32 + quad * 8);

  // all-ones bf16 A-operand for the l-sum MFMA
  u32x4 onesw; onesw[0] = 0x3F803F80u; onesw[1] = 0x3F803F80u; onesw[2] = 0x3F803F80u; onesw[3] = 0x3F803F80u;
  const bf16x8 ones = __builtin_bit_cast(bf16x8, onesw);

  f32x4 o[4] = {{0,0,0,0},{0,0,0,0},{0,0,0,0},{0,0,0,0}};  // O^T: row=d, col=q=l15
  f32x4 lacc = {0.f, 0.f, 0.f, 0.f};                       // l via ones-MFMA

  u32x4 kA, vA;
  auto LOADT = [&](int kt) {
    const int k1 = kt * 64;
    kA = *(const u32x4*)(Kp + (size_t)(k1 + srow) * D + scol);
    vA = *(const u32x4*)(VTp + (size_t)srow * T + k1 + scol);
  };
  auto STORET = [&](int buf) {
    *(u32x4*)&Ks[buf][srow * LDP + scol] = kA;
    u32x2 vlo; vlo[0] = vA[0]; vlo[1] = vA[1];
    u32x2 vhi; vhi[0] = vA[2]; vhi[1] = vA[3];
    *(u32x2*)&VTs[buf][srow * LDP + so0] = vlo;
    *(u32x2*)&VTs[buf][srow * LDP + so1] = vhi;
  };

  // prologue: tile 0 -> buf0; prefetch tile 1
  LOADT(c * 8);
  STORET(0);
  if (niter > 1) LOADT(c * 8 + 1);
  __syncthreads();

  for (int j = 0; j < niter; ++j) {
    const int buf = j & 1;
    const int ktg = c * 8 + j;
    if (ktg <= wdiag) {
      // S^T = K.Q^T : C-layout row = k_local = 16t+quad*4+r, col = q = l15
      f32x4 sA[4];
#pragma unroll
      for (int t = 0; t < 4; ++t) sA[t] = {-MBOUND, -MBOUND, -MBOUND, -MBOUND};
      __builtin_amdgcn_s_setprio(1);
#pragma unroll
      for (int t = 0; t < 4; ++t) {
        const bf16x8 kf0 = *(const bf16x8*)&Ks[buf][(t * 16 + l15) * LDP + quad * 8];
        const bf16x8 kf1 = *(const bf16x8*)&Ks[buf][(t * 16 + l15) * LDP + 32 + quad * 8];
        sA[t] = __builtin_amdgcn_mfma_f32_16x16x32_bf16(kf0, qfa, sA[t], 0, 0, 0);
        sA[t] = __builtin_amdgcn_mfma_f32_16x16x32_bf16(kf1, qfb, sA[t], 0, 0, 0);
      }
      __builtin_amdgcn_s_setprio(0);
      if (ktg == wdiag) {  // this wave's diagonal tile: causal mask
        const int k0 = ktg * 64;
#pragma unroll
        for (int t = 0; t < 4; ++t)
#pragma unroll
          for (int r = 0; r < 4; ++r)
            if (k0 + t * 16 + quad * 4 + r > qq) sA[t][r] = -1e30f;
      }
      // fixed-max softmax: p = 2^(s-M) (M folded into acc init), packed in-register
      unsigned W[4][2];
#pragma unroll
      for (int t = 0; t < 4; ++t) {
        float e0 = __builtin_amdgcn_exp2f(sA[t][0]);
        float e1 = __builtin_amdgcn_exp2f(sA[t][1]);
        float e2 = __builtin_amdgcn_exp2f(sA[t][2]);
        float e3 = __builtin_amdgcn_exp2f(sA[t][3]);
        W[t][0] = cvtpk(e0, e1);
        W[t][1] = cvtpk(e2, e3);
      }
      plswap(W[0][0], W[1][0]);
      plswap(W[0][1], W[1][1]);
      plswap(W[2][0], W[3][0]);
      plswap(W[2][1], W[3][1]);
      u32x4 paw; paw[0] = W[0][0]; paw[1] = W[0][1]; paw[2] = W[1][0]; paw[3] = W[1][1];
      u32x4 pbw; pbw[0] = W[2][0]; pbw[1] = W[2][1]; pbw[2] = W[3][0]; pbw[3] = W[3][1];
      const bf16x8 pa = __builtin_bit_cast(bf16x8, paw);
      const bf16x8 pb = __builtin_bit_cast(bf16x8, pbw);
      // O^T += V^T.P^T ; l += ones.P^T
      __builtin_amdgcn_s_setprio(1);
      lacc = __builtin_amdgcn_mfma_f32_16x16x32_bf16(ones, pa, lacc, 0, 0, 0);
      lacc = __builtin_amdgcn_mfma_f32_16x16x32_bf16(ones, pb, lacc, 0, 0, 0);
#pragma unroll
      for (int t = 0; t < 4; ++t) {
        const bf16x8 vf0 = *(const bf16x8*)&VTs[buf][(t * 16 + l15) * LDP + quad * 8];
        const bf16x8 vf1 = *(const bf16x8*)&VTs[buf][(t * 16 + l15) * LDP + 32 + quad * 8];
        o[t] = __builtin_amdgcn_mfma_f32_16x16x32_bf16(vf0, pa, o[t], 0, 0, 0);
        o[t] = __builtin_amdgcn_mfma_f32_16x16x32_bf16(vf1, pb, o[t], 0, 0, 0);
      }
      __builtin_amdgcn_s_setprio(0);
    }
    // stage tile j+1 into the other buffer; prefetch tile j+2
    if (j + 1 < niter) {
      STORET(buf ^ 1);
      if (j + 2 < niter) LOADT(c * 8 + j + 2);
    }
    __syncthreads();
  }

  const float lv = lacc[0];   // every lane holds the full 64-wide sum for its q
  if (qt2 <= 3) {
    // single chunk: normalize + write Yb directly
    const float inv = 1.f / lv;
    const int bidx = bh / 12, hidx = bh % 12;
    u16* y = Yb + ((size_t)bidx * T + qq) * 768 + hidx * 64;
#pragma unroll
    for (int t = 0; t < 4; ++t) {
      u32x2 pk;
      pk[0] = cvtpk(o[t][0] * inv, o[t][1] * inv);
      pk[1] = cvtpk(o[t][2] * inv, o[t][3] * inv);
      *(u32x2*)(y + t * 16 + quad * 4) = pk;
    }
  } else {
    // write unnormalized partials: Opart[pidx][q(128)][d(64)] fp32, lpart[pidx][q(128)]
    const size_t pidx = (size_t)bh * 40 + s;
    float* Op = Opart + pidx * 8192 + (size_t)(w * 16 + l15) * 64;
#pragma unroll
    for (int t = 0; t < 4; ++t) *(f32x4*)(Op + t * 16 + quad * 4) = o[t];
    if (quad == 0) lpart[pidx * 128 + w * 16 + l15] = lv;
  }
}

// ---------------- combine partials for qt2 >= 4 ----------------
__global__ __launch_bounds__(256) void attn_combine_kernel(
    const float* __restrict__ Opart, const float* __restrict__ lpart, u16* __restrict__ Yb) {
  constexpr int T = 2048;
  const int qt2 = 4 + blockIdx.x;   // 4..15
  const int bh = blockIdx.y;
  const int nch = (qt2 < 8) ? 2 : (qt2 < 12) ? 3 : 4;
  const int off = (qt2 < 8) ? 4 + (qt2 - 4) * 2 : (qt2 < 12) ? 12 + (qt2 - 8) * 3 : 24 + (qt2 - 12) * 4;
  const size_t base = (size_t)bh * 40 + off;
  const int tid = threadIdx.x;
  const int q = tid >> 1, db = (tid & 1) * 32;   // 128 q rows x 2 d-halves
  f32x4 o[8] = {{0,0,0,0},{0,0,0,0},{0,0,0,0},{0,0,0,0},{0,0,0,0},{0,0,0,0},{0,0,0,0},{0,0,0,0}};
  float l = 0.f;
  for (int cc = 0; cc < nch; ++cc) {
    const float* Op = Opart + (base + cc) * 8192 + (size_t)q * 64 + db;
#pragma unroll
    for (int v = 0; v < 8; ++v) o[v] += *(const f32x4*)(Op + v * 4);
    l += lpart[(base + cc) * 128 + q];
  }
  const float inv = 1.f / l;
  const int bidx = bh / 12, hidx = bh % 12;
  u16* y = Yb + ((size_t)bidx * T + qt2 * 128 + q) * 768 + hidx * 64 + db;
#pragma unroll
  for (int g = 0; g < 2; ++g) {
    u32x4 pk;
    pk[0] = cvtpk(o[g * 4 + 0][0] * inv, o[g * 4 + 0][1] * inv);
    pk[1] = cvtpk(o[g * 4 + 0][2] * inv, o[g * 4 + 0][3] * inv);
    pk[2] = cvtpk(o[g * 4 + 1][0] * inv, o[g * 4 + 1][1] * inv);
    pk[3] = cvtpk(o[g * 4 + 1][2] * inv, o[g * 4 + 1][3] * inv);
    *(u32x4*)(y + g * 16) = pk;
    pk[0] = cvtpk(o[g * 4 + 2][0] * inv, o[g * 4 + 2][1] * inv);
    pk[1] = cvtpk(o[g * 4 + 2][2] * inv, o[g * 4 + 2][3] * inv);
    pk[2] = cvtpk(o[g * 4 + 3][0] * inv, o[g * 4 + 3][1] * inv);
    pk[3] = cvtpk(o[g * 4 + 3][2] * inv, o[g * 4 + 3][3] * inv);
    *(u32x4*)(y + g * 16 + 8) = pk;
  }
}

// ---------------- fallback attention (used if ws too small) ----------------
__global__ __launch_bounds__(256) void attn_kernel(
    const u16* __restrict__ Qg, const u16* __restrict__ Kg, const u16* __restrict__ Vtg,
    u16* __restrict__ Yb) {
  constexpr int T = 2048, D = 64;
  constexpr int LDP = 72;
  constexpr float MBOUND = 20.0f;
  __shared__ u16 Ks[64 * LDP];
  __shared__ u16 VTs[64 * LDP];
  __shared__ u16 Ps[4 * 32 * LDP];
  const int qb = 15 - blockIdx.x;
  const int bh = blockIdx.y;
  const int Q0 = qb * 128;
  const int bidx = bh / 12, hidx = bh % 12;
  const int tid = threadIdx.x;
  const int w = tid >> 6, lane = tid & 63;
  const int l15 = lane & 15, quad = lane >> 4;
  const int srow = tid >> 2, scol = (tid & 3) * 16;
  const u16* Kp = Kg + (size_t)bh * T * D;
  const u16* VTp = Vtg + (size_t)bh * D * T;
  u16* pw0 = &Ps[(w * 32) * LDP];
  u16* pw1 = &Ps[(w * 32 + 16) * LDP];
  const u16* qrow0 = Qg + ((size_t)bh * T + Q0 + w * 16 + l15) * D;
  const bf16x8 qf0a = *(const bf16x8*)(qrow0 + quad * 8);
  const bf16x8 qf0b = *(const bf16x8*)(qrow0 + 32 + quad * 8);
  const bf16x8 qf1a = *(const bf16x8*)(qrow0 + (size_t)64 * D + quad * 8);
  const bf16x8 qf1b = *(const bf16x8*)(qrow0 + (size_t)64 * D + 32 + quad * 8);
  const int qq0 = Q0 + w * 16 + l15, qq1 = qq0 + 64;
  f32x4 o0[4] = {{0,0,0,0},{0,0,0,0},{0,0,0,0},{0,0,0,0}};
  f32x4 o1[4] = {{0,0,0,0},{0,0,0,0},{0,0,0,0},{0,0,0,0}};
  float l0v = 0.f, l1v = 0.f;
  const int nkt = 2 * qb + 2;
  u32x4 kA = *(const u32x4*)(Kp + (size_t)srow * D + scol);
  u32x4 kB = *(const u32x4*)(Kp + (size_t)srow * D + scol + 8);
  u32x4 vA = *(const u32x4*)(VTp + (size_t)srow * T + scol);
  u32x4 vB = *(const u32x4*)(VTp + (size_t)srow * T + scol + 8);
  for (int kt = 0; kt < nkt; ++kt) {
    __syncthreads();
    *(u32x4*)&Ks[srow * LDP + scol] = kA;
    *(u32x4*)&Ks[srow * LDP + scol + 8] = kB;
    *(u32x4*)&VTs[srow * LDP + scol] = vA;
    *(u32x4*)&VTs[srow * LDP + scol + 8] = vB;
    __syncthreads();
    if (kt + 1 < nkt) {
      const int k1 = (kt + 1) * 64;
      kA = *(const u32x4*)(Kp + (size_t)(k1 + srow) * D + scol);
      kB = *(const u32x4*)(Kp + (size_t)(k1 + srow) * D + scol + 8);
      vA = *(const u32x4*)(VTp + (size_t)srow * T + k1 + scol);
      vB = *(const u32x4*)(VTp + (size_t)srow * T + k1 + scol + 8);
    }
    const int k0 = kt * 64;
    const bool g0a = (kt <= 2 * qb);
    f32x4 s0[4] = {{0,0,0,0},{0,0,0,0},{0,0,0,0},{0,0,0,0}};
    f32x4 s1[4] = {{0,0,0,0},{0,0,0,0},{0,0,0,0},{0,0,0,0}};
#pragma unroll
    for (int t = 0; t < 4; ++t) {
      const bf16x8 kf0 = *(const bf16x8*)&Ks[(t * 16 + l15) * LDP + quad * 8];
      const bf16x8 kf1 = *(const bf16x8*)&Ks[(t * 16 + l15) * LDP + 32 + quad * 8];
      s0[t] = __builtin_amdgcn_mfma_f32_16x16x32_bf16(kf0, qf0a, s0[t], 0, 0, 0);
      s0[t] = __builtin_amdgcn_mfma_f32_16x16x32_bf16(kf1, qf0b, s0[t], 0, 0, 0);
      s1[t] = __builtin_amdgcn_mfma_f32_16x16x32_bf16(kf0, qf1a, s1[t], 0, 0, 0);
      s1[t] = __builtin_amdgcn_mfma_f32_16x16x32_bf16(kf1, qf1b, s1[t], 0, 0, 0);
    }
    if (g0a) {
      if (kt == 2 * qb) {
#pragma unroll
        for (int t = 0; t < 4; ++t)
#pragma unroll
          for (int r = 0; r < 4; ++r)
            if (k0 + t * 16 + quad * 4 + r > qq0) s0[t][r] = -1e30f;
      }
#pragma unroll
      for (int t = 0; t < 4; ++t) {
        float e0 = __builtin_amdgcn_exp2f(s0[t][0] - MBOUND);
        float e1 = __builtin_amdgcn_exp2f(s0[t][1] - MBOUND);
        float e2 = __builtin_amdgcn_exp2f(s0[t][2] - MBOUND);
        float e3 = __builtin_amdgcn_exp2f(s0[t][3] - MBOUND);
        l0v += (e0 + e1) + (e2 + e3);
        u32x2 pk;
        pk[0] = cvtpk(e0, e1);
        pk[1] = cvtpk(e2, e3);
        *(u32x2*)&pw0[l15 * LDP + t * 16 + quad * 4] = pk;
      }
    }
    {
      if (kt == 2 * qb + 1) {
#pragma unroll
        for (int t = 0; t < 4; ++t)
#pragma unroll
          for (int r = 0; r < 4; ++r)
            if (k0 + t * 16 + quad * 4 + r > qq1) s1[t][r] = -1e30f;
      }
#pragma unroll
      for (int t = 0; t < 4; ++t) {
        float e0 = __builtin_amdgcn_exp2f(s1[t][0] - MBOUND);
        float e1 = __builtin_amdgcn_exp2f(s1[t][1] - MBOUND);
        float e2 = __builtin_amdgcn_exp2f(s1[t][2] - MBOUND);
        float e3 = __builtin_amdgcn_exp2f(s1[t][3] - MBOUND);
        l1v += (e0 + e1) + (e2 + e3);
        u32x2 pk;
        pk[0] = cvtpk(e0, e1);
        pk[1] = cvtpk(e2, e3);
        *(u32x2*)&pw1[l15 * LDP + t * 16 + quad * 4] = pk;
      }
    }
    const bf16x8 p0a = *(const bf16x8*)&pw0[l15 * LDP + quad * 8];
    const bf16x8 p0b = *(const bf16x8*)&pw0[l15 * LDP + 32 + quad * 8];
    const bf16x8 p1a = *(const bf16x8*)&pw1[l15 * LDP + quad * 8];
    const bf16x8 p1b = *(const bf16x8*)&pw1[l15 * LDP + 32 + quad * 8];
#pragma unroll
    for (int t = 0; t < 4; ++t) {
      const bf16x8 vf0 = *(const bf16x8*)&VTs[(t * 16 + l15) * LDP + quad * 8];
      const bf16x8 vf1 = *(const bf16x8*)&VTs[(t * 16 + l15) * LDP + 32 + quad * 8];
      if (g0a) {
        o0[t] = __builtin_amdgcn_mfma_f32_16x16x32_bf16(vf0, p0a, o0[t], 0, 0, 0);
        o0[t] = __builtin_amdgcn_mfma_f32_16x16x32_bf16(vf1, p0b, o0[t], 0, 0, 0);
      }
      o1[t] = __builtin_amdgcn_mfma_f32_16x16x32_bf16(vf0, p1a, o1[t], 0, 0, 0);
      o1[t] = __builtin_amdgcn_mfma_f32_16x16x32_bf16(vf1, p1b, o1[t], 0, 0, 0);
    }
  }
  l0v += __shfl_xor(l0v, 16); l0v += __shfl_xor(l0v, 32);
  l1v += __shfl_xor(l1v, 16); l1v += __shfl_xor(l1v, 32);
  const float inv0 = 1.f / l0v, inv1 = 1.f / l1v;
  u16* y0 = Yb + ((size_t)bidx * T + qq0) * 768 + hidx * 64;
  u16* y1 = Yb + ((size_t)bidx * T + qq1) * 768 + hidx * 64;
#pragma unroll
  for (int t = 0; t < 4; ++t) {
    u32x2 pk0, pk1;
    pk0[0] = cvtpk(o0[t][0] * inv0, o0[t][1] * inv0);
    pk0[1] = cvtpk(o0[t][2] * inv0, o0[t][3] * inv0);
    pk1[0] = cvtpk(o1[t][0] * inv1, o1[t][1] * inv1);
    pk1[1] = cvtpk(o1[t][2] * inv1, o1[t][3] * inv1);
    *(u32x2*)(y0 + t * 16 + quad * 4) = pk0;
    *(u32x2*)(y1 + t * 16 + quad * 4) = pk1;
  }
}

extern "C" void kernel_launch(void* const* d_in, const int* in_sizes, int n_in,
                              void* d_out, int out_size, void* d_ws, size_t ws_size,
                              hipStream_t stream) {
  const float* x = (const float*)d_in[0];
  const float* W_qkv = (const float*)d_in[1];
  const float* b_qkv = (const float*)d_in[2];
  const float* W_proj = (const float*)d_in[3];
  const float* b_proj = (const float*)d_in[4];
  float* out = (float*)d_out;

  constexpr size_t MC = (size_t)8192 * 768;
  u16* xb = (u16*)d_ws;
  u16* Qb = xb + MC;
  u16* Kb = Qb + MC;
  u16* Vt = Kb + MC;   // transposed V: [bh][d][t]
  u16* Yb = Vt + MC;
  u16* WqkvT = Yb + MC;
  u16* WprojT = WqkvT + (size_t)2304 * 768;
  // split-K partials (after the bf16 region); 1920*8192 == 3840*4096 (same bytes)
  constexpr size_t BASE_U16 = 5 * MC + (size_t)2304 * 768 + (size_t)768 * 768;  // 33,816,576
  float* Opart = (float*)((u16*)d_ws + BASE_U16);
  float* lpart = Opart + (size_t)1920 * 8192;
  constexpr size_t NEED = BASE_U16 * 2 + ((size_t)1920 * 8192 + (size_t)1920 * 128) * 4;
  const bool use_split = (ws_size >= NEED);

  cast_x_kernel<<<6291456 / (4 * 256), 256, 0, stream>>>(x, xb, 6291456 / 4);
  transpose_cast_kernel<<<dim3(2304 / 32, 768 / 32), 256, 0, stream>>>(W_qkv, WqkvT, 768, 2304);
  transpose_cast_kernel<<<dim3(768 / 32, 768 / 32), 256, 0, stream>>>(W_proj, WprojT, 768, 768);
  gemm_qkv_kernel<<<dim3(18, 32), 512, 0, stream>>>(xb, WqkvT, b_qkv, Qb, Kb, Vt);
  if (use_split) {
    attn_split_kernel<<<dim3(40, 48), 512, 0, stream>>>(Qb, Kb, Vt, Yb, Opart, lpart);
    attn_combine_kernel<<<dim3(12, 48), 256, 0, stream>>>(Opart, lpart, Yb);
  } else {
    attn_kernel<<<dim3(16, 48), 256, 0, stream>>>(Qb, Kb, Vt, Yb);
  }
  gemm_proj_kernel<<<dim3(6, 128), 256, 0, stream>>>(Yb, WprojT, b_proj, out);
}

// Round 9
// 227.116 us; speedup vs baseline: 1.1013x; 1.0561x over previous
//
#include <hip/hip_runtime.h>
#include <hip/hip_bf16.h>

typedef __bf16 bf16x8 __attribute__((ext_vector_type(8)));
typedef float f32x4 __attribute__((ext_vector_type(4)));
typedef unsigned int u32x4 __attribute__((ext_vector_type(4)));
typedef unsigned int u32x2 __attribute__((ext_vector_type(2)));
typedef int i32x2 __attribute__((ext_vector_type(2)));
typedef unsigned short u16;
typedef unsigned long long u64;

#define WAITVM(n) asm volatile("s_waitcnt vmcnt(" #n ")" ::: "memory")
#define SBAR() asm volatile("s_barrier" ::: "memory")

__device__ __forceinline__ u16 f2bf(float f) {
  unsigned u = __builtin_bit_cast(unsigned, f);
  u += 0x7FFFu + ((u >> 16) & 1u);   // RNE
  return (u16)(u >> 16);
}
// HW packed convert: 2 fp32 -> 2 bf16 (v_cvt_pk_bf16_f32, RNE)
__device__ __forceinline__ unsigned cvtpk(float a, float b) {
  float2 f; f.x = a; f.y = b;
  __hip_bfloat162 h = __float22bfloat162_rn(f);
  unsigned u;
  __builtin_memcpy(&u, &h, 4);
  return u;
}

// v_permlane32_swap_b32: after call, a = [a.lo ; b.lo], b = [a.hi ; b.hi]
__device__ __forceinline__ void plswap(unsigned &a, unsigned &b) {
  i32x2 r = __builtin_amdgcn_permlane32_swap((int)a, (int)b, false, false);
  a = (unsigned)r[0];
  b = (unsigned)r[1];
}

// async global->LDS direct copy, 16B per lane. LDS dest = wave-uniform base + lane*16.
__device__ __forceinline__ void gll16(const u16* g, u16* l) {
  __builtin_amdgcn_global_load_lds(
      (const __attribute__((address_space(1))) unsigned int*)g,
      (__attribute__((address_space(3))) unsigned int*)l, 16, 0, 0);
}

// ---------------- cast x (fp32 -> bf16), vectorized ----------------
__global__ void cast_x_kernel(const float* __restrict__ in, u16* __restrict__ out, int n4) {
  int i = blockIdx.x * blockDim.x + threadIdx.x;
  if (i >= n4) return;
  f32x4 v = *(const f32x4*)(in + (size_t)i * 4);
  u32x2 pk;
  pk[0] = cvtpk(v[0], v[1]);
  pk[1] = cvtpk(v[2], v[3]);
  *(u32x2*)(out + (size_t)i * 4) = pk;
}

// ------------- transpose + cast: W[K][N] fp32 -> WT[N][K] bf16 -------------
__global__ void transpose_cast_kernel(const float* __restrict__ W, u16* __restrict__ WT, int K, int N) {
  __shared__ float tile[32][33];
  int c0 = blockIdx.x * 32, r0 = blockIdx.y * 32;
  int tx = threadIdx.x & 31, tg = threadIdx.x >> 5;
#pragma unroll
  for (int i = 0; i < 4; ++i) {
    int r = tg + i * 8;
    tile[r][tx] = W[(size_t)(r0 + r) * N + c0 + tx];
  }
  __syncthreads();
#pragma unroll
  for (int i = 0; i < 4; ++i) {
    int r = tg + i * 8;
    WT[(size_t)(c0 + r) * K + r0 + tx] = f2bf(tile[tx][r]);
  }
}

// ---------------- QKV GEMM: [8192x768] x [768x2304] ----------------
// R5-best structure: 128x128 tile, 256 thr, pipelined 2-phase BK=32, counted vmcnt(4).
// No XCD swizzle (R6: inputs L3-fit, swizzle cost ~3us). 256-tile variant cost +9us (R8:
// occupancy collapse) - do not revisit.
// Q pre-scaled by 0.125*log2(e). V written TRANSPOSED: Vt[bh][d][t].
__global__ __launch_bounds__(256, 4) void gemm_qkv_kernel(
    const u16* __restrict__ A, const u16* __restrict__ BT, const float* __restrict__ bias,
    u16* __restrict__ Qb, u16* __restrict__ Kb, u16* __restrict__ Vt) {
  constexpr int K = 768;
  constexpr int NS = K / 32;  // 24 pipeline steps
  __shared__ u16 Asm[2][128 * 32];
  __shared__ u16 Bsm[2][128 * 32];
  const int tid = threadIdx.x;
  const int w = tid >> 6, lane = tid & 63;
  const int l15 = lane & 15, quad = lane >> 4;
  const int srow = tid >> 2, scol = (tid & 3) * 8;
  const int m0 = blockIdx.y * 128, n0 = blockIdx.x * 128;
  const u16* Ag = A + (size_t)(m0 + srow) * K + scol;
  const u16* Bg = BT + (size_t)(n0 + srow) * K + scol;
  const int mw = (w >> 1) * 64, nw = (w & 1) * 64;
  f32x4 acc[4][4];
#pragma unroll
  for (int i = 0; i < 4; ++i)
#pragma unroll
    for (int j = 0; j < 4; ++j) acc[i][j] = {0.f, 0.f, 0.f, 0.f};

  auto STAGE = [&](int buf, int ks) {
    const u16* a = Ag + ks * 32;
    const u16* b = Bg + ks * 32;
#pragma unroll
    for (int rb = 0; rb < 2; ++rb) {
      gll16(a + (size_t)rb * 64 * K, &Asm[buf][(rb * 64 + w * 16) * 32]);
      gll16(b + (size_t)rb * 64 * K, &Bsm[buf][(rb * 64 + w * 16) * 32]);
    }
  };
  auto COMPUTE = [&](int buf) {
    bf16x8 af[4], bfj[4];
#pragma unroll
    for (int i = 0; i < 4; ++i) af[i] = *(const bf16x8*)&Asm[buf][(mw + i * 16 + l15) * 32 + quad * 8];
#pragma unroll
    for (int j = 0; j < 4; ++j) bfj[j] = *(const bf16x8*)&Bsm[buf][(nw + j * 16 + l15) * 32 + quad * 8];
#pragma unroll
    for (int i = 0; i < 4; ++i)
#pragma unroll
      for (int j = 0; j < 4; ++j)
        acc[i][j] = __builtin_amdgcn_mfma_f32_16x16x32_bf16(af[i], bfj[j], acc[i][j], 0, 0, 0);
  };

  STAGE(0, 0);
  for (int s = 0; s + 2 < NS; s += 2) {
    STAGE(1, s + 1); WAITVM(4); SBAR(); COMPUTE(0); SBAR();
    STAGE(0, s + 2); WAITVM(4); SBAR(); COMPUTE(1); SBAR();
  }
  STAGE(1, NS - 1); WAITVM(4); SBAR(); COMPUTE(0);
  WAITVM(0); SBAR(); COMPUTE(1);

  const int sec = blockIdx.x / 6;           // 0:Q 1:K 2:V (uniform per block; 768%128==0)
  const int nbase = n0 - sec * 768;
#pragma unroll
  for (int j = 0; j < 4; ++j) {
    const int nloc = nbase + nw + j * 16 + l15;
    const float bv = bias[sec * 768 + nloc];
    const int h = nloc >> 6, d = nloc & 63;
#pragma unroll
    for (int i = 0; i < 4; ++i) {
      const int m = m0 + mw + i * 16 + quad * 4;
      const int bb = m >> 11, trow = m & 2047;
      if (sec == 2) {
        u32x2 pk;
        pk[0] = cvtpk(acc[i][j][0] + bv, acc[i][j][1] + bv);
        pk[1] = cvtpk(acc[i][j][2] + bv, acc[i][j][3] + bv);
        *(u32x2*)(Vt + (size_t)((bb * 12 + h) * 64 + d) * 2048 + trow) = pk;
      } else {
        u16* dst = (sec == 0) ? Qb : Kb;
        const float scl = (sec == 0) ? 0.125f * 1.44269504f : 1.0f;
#pragma unroll
        for (int r = 0; r < 4; ++r)
          dst[(size_t)((bb * 12 + h) * 2048 + trow + r) * 64 + d] = f2bf((acc[i][j][r] + bv) * scl);
      }
    }
  }
}

// ---------------- proj GEMM: 64x128 tiles, minimum-2-phase BK=32, fp32 out + bias ----------------
// XCD-swizzled: grid 6x128 = 768 = 8*96. One barrier per step.
__global__ __launch_bounds__(256, 4) void gemm_proj_kernel(
    const u16* __restrict__ A, const u16* __restrict__ BT, const float* __restrict__ bias,
    float* __restrict__ out) {
  constexpr int K = 768;
  constexpr int NS = K / 32;
  __shared__ u16 Asm[2][64 * 32];
  __shared__ u16 Bsm[2][128 * 32];
  const int lin = blockIdx.y * 6 + blockIdx.x;
  const int swz = (lin & 7) * 96 + (lin >> 3);
  const int tid = threadIdx.x;
  const int w = tid >> 6, lane = tid & 63;
  const int l15 = lane & 15, quad = lane >> 4;
  const int srow = tid >> 2, scol = (tid & 3) * 8;
  const int m0 = (swz / 6) * 64, n0 = (swz % 6) * 128;
  const u16* Ag = A + (size_t)(m0 + srow) * K + scol;
  const u16* Bg = BT + (size_t)(n0 + srow) * K + scol;
  const int mw = (w >> 1) * 32, nw = (w & 1) * 64;
  f32x4 acc[2][4];
#pragma unroll
  for (int i = 0; i < 2; ++i)
#pragma unroll
    for (int j = 0; j < 4; ++j) acc[i][j] = {0.f, 0.f, 0.f, 0.f};

  auto STAGE = [&](int buf, int ks) {
    const u16* a = Ag + ks * 32;
    const u16* b = Bg + ks * 32;
    gll16(a, &Asm[buf][(w * 16) * 32]);
#pragma unroll
    for (int rb = 0; rb < 2; ++rb)
      gll16(b + (size_t)rb * 64 * K, &Bsm[buf][(rb * 64 + w * 16) * 32]);
  };
  auto COMPUTE = [&](int buf) {
    bf16x8 af[2], bfj[4];
#pragma unroll
    for (int i = 0; i < 2; ++i) af[i] = *(const bf16x8*)&Asm[buf][(mw + i * 16 + l15) * 32 + quad * 8];
#pragma unroll
    for (int j = 0; j < 4; ++j) bfj[j] = *(const bf16x8*)&Bsm[buf][(nw + j * 16 + l15) * 32 + quad * 8];
#pragma unroll
    for (int i = 0; i < 2; ++i)
#pragma unroll
      for (int j = 0; j < 4; ++j)
        acc[i][j] = __builtin_amdgcn_mfma_f32_16x16x32_bf16(af[i], bfj[j], acc[i][j], 0, 0, 0);
  };

  STAGE(0, 0);
  WAITVM(0); SBAR();
  for (int s = 0; s < NS; ++s) {
    const int buf = s & 1;
    if (s + 1 < NS) STAGE(buf ^ 1, s + 1);
    COMPUTE(buf);
    WAITVM(0); SBAR();
  }

#pragma unroll
  for (int j = 0; j < 4; ++j) {
    const int n = n0 + nw + j * 16 + l15;
    const float bv = bias[n];
#pragma unroll
    for (int i = 0; i < 2; ++i) {
      const int m = m0 + mw + i * 16 + quad * 4;
#pragma unroll
      for (int r = 0; r < 4; ++r) out[(size_t)(m + r) * 768 + n] = acc[i][j][r] + bv;
    }
  }
}

// ---------------- split-K causal flash attention, 8 waves / 128 q-rows per block ----------------
// Work unit: (bh, 128-q tile qt2 in 0..15, chunk c of <=8 k-tiles among nkt=2*qt2+2).
// 40 slots per bh. XCD-swizzled (T1): grid 40x48 = 1920 = 8*240; each XCD gets 6
// consecutive bh (3MB K/V, L2-resident); long-chunks-first preserved within each bh.
// 8 waves (512 thr); per-wave math identical to the 4-wave version (VGPR ~52).
// Waves 0-3 skip the block's final diagonal tile via wdiag guard (barriers uniform).
// P exchange in-register (T12); l-sum via ones-MFMA.
__global__ __launch_bounds__(512) void attn_split_kernel(
    const u16* __restrict__ Qg, const u16* __restrict__ Kg, const u16* __restrict__ Vtg,
    u16* __restrict__ Yb, float* __restrict__ Opart, float* __restrict__ lpart) {
  constexpr int T = 2048, D = 64;
  constexpr int LDP = 72;
  constexpr float MBOUND = 20.0f;
  __shared__ u16 Ks[2][64 * LDP];   // K tile  [k][d]
  __shared__ u16 VTs[2][64 * LDP];  // V^T tile [d][sigma(k)]
  const int lin = blockIdx.y * 40 + blockIdx.x;
  const int swzb = (lin & 7) * 240 + (lin >> 3);
  const int s = 39 - (swzb % 40);   // long chunks first (within each bh)
  const int bh = swzb / 40;
  int qt2, c;
  if (s < 4) { qt2 = s; c = 0; }
  else if (s < 12) { qt2 = 4 + ((s - 4) >> 1); c = (s - 4) & 1; }
  else if (s < 24) { int u = s - 12; int q3 = u / 3; qt2 = 8 + q3; c = u - 3 * q3; }
  else { int u = s - 24; qt2 = 12 + (u >> 2); c = u & 3; }
  const int nkt = 2 * qt2 + 2;
  const int niter = min(8, nkt - 8 * c);
  const int tid = threadIdx.x;
  const int w = tid >> 6, lane = tid & 63;
  const int l15 = lane & 15, quad = lane >> 4;
  // staging: 512 threads, one u32x4 (16B) each for K and V
  const int srow = tid >> 3;                // 0..63
  const int scol = (tid & 7) * 8;           // u16 units
  const int so0 = scol - 4 * (tid & 1);     // sigma dest for lo half
  const int so1 = scol + 8 - 4 * (tid & 1); // sigma dest for hi half
  const u16* Kp = Kg + (size_t)bh * T * D;
  const u16* VTp = Vtg + (size_t)bh * D * T;

  // per-wave role: rows qq; diagonal tile index for this wave
  const int wdiag = 2 * qt2 + (w >> 2);
  const int qq = qt2 * 128 + w * 16 + l15;
  const u16* qrow = Qg + ((size_t)bh * T + qq) * D;
  const bf16x8 qfa = *(const bf16x8*)(qrow + quad * 8);
  const bf16x8 qfb = *(const bf16x8*)(qrow + 32 + quad * 8);

  // all-ones bf16 A-operand for the l-sum MFMA
  u32x4 onesw; onesw[0] = 0x3F803F80u; onesw[1] = 0x3F803F80u; onesw[2] = 0x3F803F80u; onesw[3] = 0x3F803F80u;
  const bf16x8 ones = __builtin_bit_cast(bf16x8, onesw);

  f32x4 o[4] = {{0,0,0,0},{0,0,0,0},{0,0,0,0},{0,0,0,0}};  // O^T: row=d, col=q=l15
  f32x4 lacc = {0.f, 0.f, 0.f, 0.f};                       // l via ones-MFMA

  u32x4 kA, vA;
  auto LOADT = [&](int kt) {
    const int k1 = kt * 64;
    kA = *(const u32x4*)(Kp + (size_t)(k1 + srow) * D + scol);
    vA = *(const u32x4*)(VTp + (size_t)srow * T + k1 + scol);
  };
  auto STORET = [&](int buf) {
    *(u32x4*)&Ks[buf][srow * LDP + scol] = kA;
    u32x2 vlo; vlo[0] = vA[0]; vlo[1] = vA[1];
    u32x2 vhi; vhi[0] = vA[2]; vhi[1] = vA[3];
    *(u32x2*)&VTs[buf][srow * LDP + so0] = vlo;
    *(u32x2*)&VTs[buf][srow * LDP + so1] = vhi;
  };

  // prologue: tile 0 -> buf0; prefetch tile 1
  LOADT(c * 8);
  STORET(0);
  if (niter > 1) LOADT(c * 8 + 1);
  __syncthreads();

  for (int j = 0; j < niter; ++j) {
    const int buf = j & 1;
    const int ktg = c * 8 + j;
    if (ktg <= wdiag) {
      // S^T = K.Q^T : C-layout row = k_local = 16t+quad*4+r, col = q = l15
      f32x4 sA[4];
#pragma unroll
      for (int t = 0; t < 4; ++t) sA[t] = {-MBOUND, -MBOUND, -MBOUND, -MBOUND};
      __builtin_amdgcn_s_setprio(1);
#pragma unroll
      for (int t = 0; t < 4; ++t) {
        const bf16x8 kf0 = *(const bf16x8*)&Ks[buf][(t * 16 + l15) * LDP + quad * 8];
        const bf16x8 kf1 = *(const bf16x8*)&Ks[buf][(t * 16 + l15) * LDP + 32 + quad * 8];
        sA[t] = __builtin_amdgcn_mfma_f32_16x16x32_bf16(kf0, qfa, sA[t], 0, 0, 0);
        sA[t] = __builtin_amdgcn_mfma_f32_16x16x32_bf16(kf1, qfb, sA[t], 0, 0, 0);
      }
      __builtin_amdgcn_s_setprio(0);
      if (ktg == wdiag) {  // this wave's diagonal tile: causal mask
        const int k0 = ktg * 64;
#pragma unroll
        for (int t = 0; t < 4; ++t)
#pragma unroll
          for (int r = 0; r < 4; ++r)
            if (k0 + t * 16 + quad * 4 + r > qq) sA[t][r] = -1e30f;
      }
      // fixed-max softmax: p = 2^(s-M) (M folded into acc init), packed in-register
      unsigned W[4][2];
#pragma unroll
      for (int t = 0; t < 4; ++t) {
        float e0 = __builtin_amdgcn_exp2f(sA[t][0]);
        float e1 = __builtin_amdgcn_exp2f(sA[t][1]);
        float e2 = __builtin_amdgcn_exp2f(sA[t][2]);
        float e3 = __builtin_amdgcn_exp2f(sA[t][3]);
        W[t][0] = cvtpk(e0, e1);
        W[t][1] = cvtpk(e2, e3);
      }
      plswap(W[0][0], W[1][0]);
      plswap(W[0][1], W[1][1]);
      plswap(W[2][0], W[3][0]);
      plswap(W[2][1], W[3][1]);
      u32x4 paw; paw[0] = W[0][0]; paw[1] = W[0][1]; paw[2] = W[1][0]; paw[3] = W[1][1];
      u32x4 pbw; pbw[0] = W[2][0]; pbw[1] = W[2][1]; pbw[2] = W[3][0]; pbw[3] = W[3][1];
      const bf16x8 pa = __builtin_bit_cast(bf16x8, paw);
      const bf16x8 pb = __builtin_bit_cast(bf16x8, pbw);
      // O^T += V^T.P^T ; l += ones.P^T
      __builtin_amdgcn_s_setprio(1);
      lacc = __builtin_amdgcn_mfma_f32_16x16x32_bf16(ones, pa, lacc, 0, 0, 0);
      lacc = __builtin_amdgcn_mfma_f32_16x16x32_bf16(ones, pb, lacc, 0, 0, 0);
#pragma unroll
      for (int t = 0; t < 4; ++t) {
        const bf16x8 vf0 = *(const bf16x8*)&VTs[buf][(t * 16 + l15) * LDP + quad * 8];
        const bf16x8 vf1 = *(const bf16x8*)&VTs[buf][(t * 16 + l15) * LDP + 32 + quad * 8];
        o[t] = __builtin_amdgcn_mfma_f32_16x16x32_bf16(vf0, pa, o[t], 0, 0, 0);
        o[t] = __builtin_amdgcn_mfma_f32_16x16x32_bf16(vf1, pb, o[t], 0, 0, 0);
      }
      __builtin_amdgcn_s_setprio(0);
    }
    // stage tile j+1 into the other buffer; prefetch tile j+2
    if (j + 1 < niter) {
      STORET(buf ^ 1);
      if (j + 2 < niter) LOADT(c * 8 + j + 2);
    }
    __syncthreads();
  }

  const float lv = lacc[0];   // every lane holds the full 64-wide sum for its q
  if (qt2 <= 3) {
    // single chunk: normalize + write Yb directly
    const float inv = 1.f / lv;
    const int bidx = bh / 12, hidx = bh % 12;
    u16* y = Yb + ((size_t)bidx * T + qq) * 768 + hidx * 64;
#pragma unroll
    for (int t = 0; t < 4; ++t) {
      u32x2 pk;
      pk[0] = cvtpk(o[t][0] * inv, o[t][1] * inv);
      pk[1] = cvtpk(o[t][2] * inv, o[t][3] * inv);
      *(u32x2*)(y + t * 16 + quad * 4) = pk;
    }
  } else {
    // write unnormalized partials: Opart[pidx][q(128)][d(64)] fp32, lpart[pidx][q(128)]
    const size_t pidx = (size_t)bh * 40 + s;
    float* Op = Opart + pidx * 8192 + (size_t)(w * 16 + l15) * 64;
#pragma unroll
    for (int t = 0; t < 4; ++t) *(f32x4*)(Op + t * 16 + quad * 4) = o[t];
    if (quad == 0) lpart[pidx * 128 + w * 16 + l15] = lv;
  }
}

// ---------------- combine partials for qt2 >= 4 ----------------
__global__ __launch_bounds__(256) void attn_combine_kernel(
    const float* __restrict__ Opart, const float* __restrict__ lpart, u16* __restrict__ Yb) {
  constexpr int T = 2048;
  const int qt2 = 4 + blockIdx.x;   // 4..15
  const int bh = blockIdx.y;
  const int nch = (qt2 < 8) ? 2 : (qt2 < 12) ? 3 : 4;
  const int off = (qt2 < 8) ? 4 + (qt2 - 4) * 2 : (qt2 < 12) ? 12 + (qt2 - 8) * 3 : 24 + (qt2 - 12) * 4;
  const size_t base = (size_t)bh * 40 + off;
  const int tid = threadIdx.x;
  const int q = tid >> 1, db = (tid & 1) * 32;   // 128 q rows x 2 d-halves
  f32x4 o[8] = {{0,0,0,0},{0,0,0,0},{0,0,0,0},{0,0,0,0},{0,0,0,0},{0,0,0,0},{0,0,0,0},{0,0,0,0}};
  float l = 0.f;
  for (int cc = 0; cc < nch; ++cc) {
    const float* Op = Opart + (base + cc) * 8192 + (size_t)q * 64 + db;
#pragma unroll
    for (int v = 0; v < 8; ++v) o[v] += *(const f32x4*)(Op + v * 4);
    l += lpart[(base + cc) * 128 + q];
  }
  const float inv = 1.f / l;
  const int bidx = bh / 12, hidx = bh % 12;
  u16* y = Yb + ((size_t)bidx * T + qt2 * 128 + q) * 768 + hidx * 64 + db;
#pragma unroll
  for (int g = 0; g < 2; ++g) {
    u32x4 pk;
    pk[0] = cvtpk(o[g * 4 + 0][0] * inv, o[g * 4 + 0][1] * inv);
    pk[1] = cvtpk(o[g * 4 + 0][2] * inv, o[g * 4 + 0][3] * inv);
    pk[2] = cvtpk(o[g * 4 + 1][0] * inv, o[g * 4 + 1][1] * inv);
    pk[3] = cvtpk(o[g * 4 + 1][2] * inv, o[g * 4 + 1][3] * inv);
    *(u32x4*)(y + g * 16) = pk;
    pk[0] = cvtpk(o[g * 4 + 2][0] * inv, o[g * 4 + 2][1] * inv);
    pk[1] = cvtpk(o[g * 4 + 2][2] * inv, o[g * 4 + 2][3] * inv);
    pk[2] = cvtpk(o[g * 4 + 3][0] * inv, o[g * 4 + 3][1] * inv);
    pk[3] = cvtpk(o[g * 4 + 3][2] * inv, o[g * 4 + 3][3] * inv);
    *(u32x4*)(y + g * 16 + 8) = pk;
  }
}

// ---------------- fallback attention (used if ws too small) ----------------
__global__ __launch_bounds__(256) void attn_kernel(
    const u16* __restrict__ Qg, const u16* __restrict__ Kg, const u16* __restrict__ Vtg,
    u16* __restrict__ Yb) {
  constexpr int T = 2048, D = 64;
  constexpr int LDP = 72;
  constexpr float MBOUND = 20.0f;
  __shared__ u16 Ks[64 * LDP];
  __shared__ u16 VTs[64 * LDP];
  __shared__ u16 Ps[4 * 32 * LDP];
  const int qb = 15 - blockIdx.x;
  const int bh = blockIdx.y;
  const int Q0 = qb * 128;
  const int bidx = bh / 12, hidx = bh % 12;
  const int tid = threadIdx.x;
  const int w = tid >> 6, lane = tid & 63;
  const int l15 = lane & 15, quad = lane >> 4;
  const int srow = tid >> 2, scol = (tid & 3) * 16;
  const u16* Kp = Kg + (size_t)bh * T * D;
  const u16* VTp = Vtg + (size_t)bh * D * T;
  u16* pw0 = &Ps[(w * 32) * LDP];
  u16* pw1 = &Ps[(w * 32 + 16) * LDP];
  const u16* qrow0 = Qg + ((size_t)bh * T + Q0 + w * 16 + l15) * D;
  const bf16x8 qf0a = *(const bf16x8*)(qrow0 + quad * 8);
  const bf16x8 qf0b = *(const bf16x8*)(qrow0 + 32 + quad * 8);
  const bf16x8 qf1a = *(const bf16x8*)(qrow0 + (size_t)64 * D + quad * 8);
  const bf16x8 qf1b = *(const bf16x8*)(qrow0 + (size_t)64 * D + 32 + quad * 8);
  const int qq0 = Q0 + w * 16 + l15, qq1 = qq0 + 64;
  f32x4 o0[4] = {{0,0,0,0},{0,0,0,0},{0,0,0,0},{0,0,0,0}};
  f32x4 o1[4] = {{0,0,0,0},{0,0,0,0},{0,0,0,0},{0,0,0,0}};
  float l0v = 0.f, l1v = 0.f;
  const int nkt = 2 * qb + 2;
  u32x4 kA = *(const u32x4*)(Kp + (size_t)srow * D + scol);
  u32x4 kB = *(const u32x4*)(Kp + (size_t)srow * D + scol + 8);
  u32x4 vA = *(const u32x4*)(VTp + (size_t)srow * T + scol);
  u32x4 vB = *(const u32x4*)(VTp + (size_t)srow * T + scol + 8);
  for (int kt = 0; kt < nkt; ++kt) {
    __syncthreads();
    *(u32x4*)&Ks[srow * LDP + scol] = kA;
    *(u32x4*)&Ks[srow * LDP + scol + 8] = kB;
    *(u32x4*)&VTs[srow * LDP + scol] = vA;
    *(u32x4*)&VTs[srow * LDP + scol + 8] = vB;
    __syncthreads();
    if (kt + 1 < nkt) {
      const int k1 = (kt + 1) * 64;
      kA = *(const u32x4*)(Kp + (size_t)(k1 + srow) * D + scol);
      kB = *(const u32x4*)(Kp + (size_t)(k1 + srow) * D + scol + 8);
      vA = *(const u32x4*)(VTp + (size_t)srow * T + k1 + scol);
      vB = *(const u32x4*)(VTp + (size_t)srow * T + k1 + scol + 8);
    }
    const int k0 = kt * 64;
    const bool g0a = (kt <= 2 * qb);
    f32x4 s0[4] = {{0,0,0,0},{0,0,0,0},{0,0,0,0},{0,0,0,0}};
    f32x4 s1[4] = {{0,0,0,0},{0,0,0,0},{0,0,0,0},{0,0,0,0}};
#pragma unroll
    for (int t = 0; t < 4; ++t) {
      const bf16x8 kf0 = *(const bf16x8*)&Ks[(t * 16 + l15) * LDP + quad * 8];
      const bf16x8 kf1 = *(const bf16x8*)&Ks[(t * 16 + l15) * LDP + 32 + quad * 8];
      s0[t] = __builtin_amdgcn_mfma_f32_16x16x32_bf16(kf0, qf0a, s0[t], 0, 0, 0);
      s0[t] = __builtin_amdgcn_mfma_f32_16x16x32_bf16(kf1, qf0b, s0[t], 0, 0, 0);
      s1[t] = __builtin_amdgcn_mfma_f32_16x16x32_bf16(kf0, qf1a, s1[t], 0, 0, 0);
      s1[t] = __builtin_amdgcn_mfma_f32_16x16x32_bf16(kf1, qf1b, s1[t], 0, 0, 0);
    }
    if (g0a) {
      if (kt == 2 * qb) {
#pragma unroll
        for (int t = 0; t < 4; ++t)
#pragma unroll
          for (int r = 0; r < 4; ++r)
            if (k0 + t * 16 + quad * 4 + r > qq0) s0[t][r] = -1e30f;
      }
#pragma unroll
      for (int t = 0; t < 4; ++t) {
        float e0 = __builtin_amdgcn_exp2f(s0[t][0] - MBOUND);
        float e1 = __builtin_amdgcn_exp2f(s0[t][1] - MBOUND);
        float e2 = __builtin_amdgcn_exp2f(s0[t][2] - MBOUND);
        float e3 = __builtin_amdgcn_exp2f(s0[t][3] - MBOUND);
        l0v += (e0 + e1) + (e2 + e3);
        u32x2 pk;
        pk[0] = cvtpk(e0, e1);
        pk[1] = cvtpk(e2, e3);
        *(u32x2*)&pw0[l15 * LDP + t * 16 + quad * 4] = pk;
      }
    }
    {
      if (kt == 2 * qb + 1) {
#pragma unroll
        for (int t = 0; t < 4; ++t)
#pragma unroll
          for (int r = 0; r < 4; ++r)
            if (k0 + t * 16 + quad * 4 + r > qq1) s1[t][r] = -1e30f;
      }
#pragma unroll
      for (int t = 0; t < 4; ++t) {
        float e0 = __builtin_amdgcn_exp2f(s1[t][0] - MBOUND);
        float e1 = __builtin_amdgcn_exp2f(s1[t][1] - MBOUND);
        float e2 = __builtin_amdgcn_exp2f(s1[t][2] - MBOUND);
        float e3 = __builtin_amdgcn_exp2f(s1[t][3] - MBOUND);
        l1v += (e0 + e1) + (e2 + e3);
        u32x2 pk;
        pk[0] = cvtpk(e0, e1);
        pk[1] = cvtpk(e2, e3);
        *(u32x2*)&pw1[l15 * LDP + t * 16 + quad * 4] = pk;
      }
    }
    const bf16x8 p0a = *(const bf16x8*)&pw0[l15 * LDP + quad * 8];
    const bf16x8 p0b = *(const bf16x8*)&pw0[l15 * LDP + 32 + quad * 8];
    const bf16x8 p1a = *(const bf16x8*)&pw1[l15 * LDP + quad * 8];
    const bf16x8 p1b = *(const bf16x8*)&pw1[l15 * LDP + 32 + quad * 8];
#pragma unroll
    for (int t = 0; t < 4; ++t) {
      const bf16x8 vf0 = *(const bf16x8*)&VTs[(t * 16 + l15) * LDP + quad * 8];
      const bf16x8 vf1 = *(const bf16x8*)&VTs[(t * 16 + l15) * LDP + 32 + quad * 8];
      if (g0a) {
        o0[t] = __builtin_amdgcn_mfma_f32_16x16x32_bf16(vf0, p0a, o0[t], 0, 0, 0);
        o0[t] = __builtin_amdgcn_mfma_f32_16x16x32_bf16(vf1, p0b, o0[t], 0, 0, 0);
      }
      o1[t] = __builtin_amdgcn_mfma_f32_16x16x32_bf16(vf0, p1a, o1[t], 0, 0, 0);
      o1[t] = __builtin_amdgcn_mfma_f32_16x16x32_bf16(vf1, p1b, o1[t], 0, 0, 0);
    }
  }
  l0v += __shfl_xor(l0v, 16); l0v += __shfl_xor(l0v, 32);
  l1v += __shfl_xor(l1v, 16); l1v += __shfl_xor(l1v, 32);
  const float inv0 = 1.f / l0v, inv1 = 1.f / l1v;
  u16* y0 = Yb + ((size_t)bidx * T + qq0) * 768 + hidx * 64;
  u16* y1 = Yb + ((size_t)bidx * T + qq1) * 768 + hidx * 64;
#pragma unroll
  for (int t = 0; t < 4; ++t) {
    u32x2 pk0, pk1;
    pk0[0] = cvtpk(o0[t][0] * inv0, o0[t][1] * inv0);
    pk0[1] = cvtpk(o0[t][2] * inv0, o0[t][3] * inv0);
    pk1[0] = cvtpk(o1[t][0] * inv1, o1[t][1] * inv1);
    pk1[1] = cvtpk(o1[t][2] * inv1, o1[t][3] * inv1);
    *(u32x2*)(y0 + t * 16 + quad * 4) = pk0;
    *(u32x2*)(y1 + t * 16 + quad * 4) = pk1;
  }
}

extern "C" void kernel_launch(void* const* d_in, const int* in_sizes, int n_in,
                              void* d_out, int out_size, void* d_ws, size_t ws_size,
                              hipStream_t stream) {
  const float* x = (const float*)d_in[0];
  const float* W_qkv = (const float*)d_in[1];
  const float* b_qkv = (const float*)d_in[2];
  const float* W_proj = (const float*)d_in[3];
  const float* b_proj = (const float*)d_in[4];
  float* out = (float*)d_out;

  constexpr size_t MC = (size_t)8192 * 768;
  u16* xb = (u16*)d_ws;
  u16* Qb = xb + MC;
  u16* Kb = Qb + MC;
  u16* Vt = Kb + MC;   // transposed V: [bh][d][t]
  u16* Yb = Vt + MC;
  u16* WqkvT = Yb + MC;
  u16* WprojT = WqkvT + (size_t)2304 * 768;
  // split-K partials (after the bf16 region); 1920*8192 == 3840*4096 (same bytes)
  constexpr size_t BASE_U16 = 5 * MC + (size_t)2304 * 768 + (size_t)768 * 768;  // 33,816,576
  float* Opart = (float*)((u16*)d_ws + BASE_U16);
  float* lpart = Opart + (size_t)1920 * 8192;
  constexpr size_t NEED = BASE_U16 * 2 + ((size_t)1920 * 8192 + (size_t)1920 * 128) * 4;
  const bool use_split = (ws_size >= NEED);

  cast_x_kernel<<<6291456 / (4 * 256), 256, 0, stream>>>(x, xb, 6291456 / 4);
  transpose_cast_kernel<<<dim3(2304 / 32, 768 / 32), 256, 0, stream>>>(W_qkv, WqkvT, 768, 2304);
  transpose_cast_kernel<<<dim3(768 / 32, 768 / 32), 256, 0, stream>>>(W_proj, WprojT, 768, 768);
  gemm_qkv_kernel<<<dim3(18, 64), 256, 0, stream>>>(xb, WqkvT, b_qkv, Qb, Kb, Vt);
  if (use_split) {
    attn_split_kernel<<<dim3(40, 48), 512, 0, stream>>>(Qb, Kb, Vt, Yb, Opart, lpart);
    attn_combine_kernel<<<dim3(12, 48), 256, 0, stream>>>(Opart, lpart, Yb);
  } else {
    attn_kernel<<<dim3(16, 48), 256, 0, stream>>>(Qb, Kb, Vt, Yb);
  }
  gemm_proj_kernel<<<dim3(6, 128), 256, 0, stream>>>(Yb, WprojT, b_proj, out);
}

// Round 10
// 223.055 us; speedup vs baseline: 1.1213x; 1.0182x over previous
//
#include <hip/hip_runtime.h>
#include <hip/hip_bf16.h>

typedef __bf16 bf16x8 __attribute__((ext_vector_type(8)));
typedef float f32x4 __attribute__((ext_vector_type(4)));
typedef unsigned int u32x4 __attribute__((ext_vector_type(4)));
typedef unsigned int u32x2 __attribute__((ext_vector_type(2)));
typedef int i32x2 __attribute__((ext_vector_type(2)));
typedef unsigned short u16;
typedef unsigned long long u64;

#define WAITVM(n) asm volatile("s_waitcnt vmcnt(" #n ")" ::: "memory")
#define SBAR() asm volatile("s_barrier" ::: "memory")

__device__ __forceinline__ u16 f2bf(float f) {
  unsigned u = __builtin_bit_cast(unsigned, f);
  u += 0x7FFFu + ((u >> 16) & 1u);   // RNE
  return (u16)(u >> 16);
}
// HW packed convert: 2 fp32 -> 2 bf16 (v_cvt_pk_bf16_f32, RNE)
__device__ __forceinline__ unsigned cvtpk(float a, float b) {
  float2 f; f.x = a; f.y = b;
  __hip_bfloat162 h = __float22bfloat162_rn(f);
  unsigned u;
  __builtin_memcpy(&u, &h, 4);
  return u;
}

// v_permlane32_swap_b32: after call, a = [a.lo ; b.lo], b = [a.hi ; b.hi]
__device__ __forceinline__ void plswap(unsigned &a, unsigned &b) {
  i32x2 r = __builtin_amdgcn_permlane32_swap((int)a, (int)b, false, false);
  a = (unsigned)r[0];
  b = (unsigned)r[1];
}

// async global->LDS direct copy, 16B per lane. LDS dest = wave-uniform base + lane*16.
__device__ __forceinline__ void gll16(const u16* g, u16* l) {
  __builtin_amdgcn_global_load_lds(
      (const __attribute__((address_space(1))) unsigned int*)g,
      (__attribute__((address_space(3))) unsigned int*)l, 16, 0, 0);
}

// ---------------- cast x (fp32 -> bf16), vectorized ----------------
__global__ void cast_x_kernel(const float* __restrict__ in, u16* __restrict__ out, int n4) {
  int i = blockIdx.x * blockDim.x + threadIdx.x;
  if (i >= n4) return;
  f32x4 v = *(const f32x4*)(in + (size_t)i * 4);
  u32x2 pk;
  pk[0] = cvtpk(v[0], v[1]);
  pk[1] = cvtpk(v[2], v[3]);
  *(u32x2*)(out + (size_t)i * 4) = pk;
}

// ------------- transpose + cast: W[K][N] fp32 -> WT[N][K] bf16 -------------
__global__ void transpose_cast_kernel(const float* __restrict__ W, u16* __restrict__ WT, int K, int N) {
  __shared__ float tile[32][33];
  int c0 = blockIdx.x * 32, r0 = blockIdx.y * 32;
  int tx = threadIdx.x & 31, tg = threadIdx.x >> 5;
#pragma unroll
  for (int i = 0; i < 4; ++i) {
    int r = tg + i * 8;
    tile[r][tx] = W[(size_t)(r0 + r) * N + c0 + tx];
  }
  __syncthreads();
#pragma unroll
  for (int i = 0; i < 4; ++i) {
    int r = tg + i * 8;
    WT[(size_t)(c0 + r) * K + r0 + tx] = f2bf(tile[tx][r]);
  }
}

// ---------------- QKV GEMM: [8192x768] x [768x2304] ----------------
// 128x128 tile, 256 thr, BK=32, 24 steps — R5 structure but with a 3-STAGE LDS
// pipeline (depth 2): tile s's loads are issued two compute phases before use, so
// counted WAITVM(8) gives each tile ~400-500cy of cover (L2 ~200cy, HBM ~900cy)
// instead of depth-1's ~100cy. Only the depth changed vs R5/R9 (tile/waves/epilogue
// identical). LDS 48KB -> 3 blocks/CU cap (measured effective occupancy was ~2.4).
// Q pre-scaled by 0.125*log2(e). V written TRANSPOSED: Vt[bh][d][t].
__global__ __launch_bounds__(256, 3) void gemm_qkv_kernel(
    const u16* __restrict__ A, const u16* __restrict__ BT, const float* __restrict__ bias,
    u16* __restrict__ Qb, u16* __restrict__ Kb, u16* __restrict__ Vt) {
  constexpr int K = 768;
  constexpr int NS = K / 32;  // 24 pipeline steps (multiple of 3)
  __shared__ u16 Asm[3][128 * 32];
  __shared__ u16 Bsm[3][128 * 32];
  const int tid = threadIdx.x;
  const int w = tid >> 6, lane = tid & 63;
  const int l15 = lane & 15, quad = lane >> 4;
  const int srow = tid >> 2, scol = (tid & 3) * 8;
  const int m0 = blockIdx.y * 128, n0 = blockIdx.x * 128;
  const u16* Ag = A + (size_t)(m0 + srow) * K + scol;
  const u16* Bg = BT + (size_t)(n0 + srow) * K + scol;
  const int mw = (w >> 1) * 64, nw = (w & 1) * 64;
  f32x4 acc[4][4];
#pragma unroll
  for (int i = 0; i < 4; ++i)
#pragma unroll
    for (int j = 0; j < 4; ++j) acc[i][j] = {0.f, 0.f, 0.f, 0.f};

  auto STAGE = [&](int buf, int ks) {
    const u16* a = Ag + ks * 32;
    const u16* b = Bg + ks * 32;
#pragma unroll
    for (int rb = 0; rb < 2; ++rb) {
      gll16(a + (size_t)rb * 64 * K, &Asm[buf][(rb * 64 + w * 16) * 32]);
      gll16(b + (size_t)rb * 64 * K, &Bsm[buf][(rb * 64 + w * 16) * 32]);
    }
  };
  auto COMPUTE = [&](int buf) {
    bf16x8 af[4], bfj[4];
#pragma unroll
    for (int i = 0; i < 4; ++i) af[i] = *(const bf16x8*)&Asm[buf][(mw + i * 16 + l15) * 32 + quad * 8];
#pragma unroll
    for (int j = 0; j < 4; ++j) bfj[j] = *(const bf16x8*)&Bsm[buf][(nw + j * 16 + l15) * 32 + quad * 8];
#pragma unroll
    for (int i = 0; i < 4; ++i)
#pragma unroll
      for (int j = 0; j < 4; ++j)
        acc[i][j] = __builtin_amdgcn_mfma_f32_16x16x32_bf16(af[i], bfj[j], acc[i][j], 0, 0, 0);
  };

  // prologue: tiles 0,1 in flight (depth 2)
  STAGE(0, 0);
  STAGE(1, 1);
  // steady state: at step s (buf s%3), issue tile s+2 into buf (s+2)%3, then wait
  // until only tiles s+1,s+2 outstanding (vmcnt(8)) -> tile s landed. Barrier pair
  // protects LDS (post-compute barrier guards the buffer re-staged 2 steps later).
  // NS=24: steps 0..21 stage; step 22 waits vmcnt(4); step 23 waits vmcnt(0).
  for (int s = 0; s < NS - 3; s += 3) {
    STAGE((s + 2) % 3, s + 2); WAITVM(8); SBAR(); COMPUTE(s % 3); SBAR();
    STAGE((s + 3) % 3, s + 3); WAITVM(8); SBAR(); COMPUTE((s + 1) % 3); SBAR();
    STAGE((s + 4) % 3, s + 4); WAITVM(8); SBAR(); COMPUTE((s + 2) % 3); SBAR();
  }
  // s = NS-3, NS-2, NS-1 (21,22,23): one more stage (tile 23), then drain
  STAGE((NS - 1) % 3, NS - 1); WAITVM(8); SBAR(); COMPUTE((NS - 3) % 3); SBAR();
  WAITVM(4); SBAR(); COMPUTE((NS - 2) % 3); SBAR();
  WAITVM(0); SBAR(); COMPUTE((NS - 1) % 3);

  const int sec = blockIdx.x / 6;           // 0:Q 1:K 2:V (uniform per block; 768%128==0)
  const int nbase = n0 - sec * 768;
#pragma unroll
  for (int j = 0; j < 4; ++j) {
    const int nloc = nbase + nw + j * 16 + l15;
    const float bv = bias[sec * 768 + nloc];
    const int h = nloc >> 6, d = nloc & 63;
#pragma unroll
    for (int i = 0; i < 4; ++i) {
      const int m = m0 + mw + i * 16 + quad * 4;
      const int bb = m >> 11, trow = m & 2047;
      if (sec == 2) {
        u32x2 pk;
        pk[0] = cvtpk(acc[i][j][0] + bv, acc[i][j][1] + bv);
        pk[1] = cvtpk(acc[i][j][2] + bv, acc[i][j][3] + bv);
        *(u32x2*)(Vt + (size_t)((bb * 12 + h) * 64 + d) * 2048 + trow) = pk;
      } else {
        u16* dst = (sec == 0) ? Qb : Kb;
        const float scl = (sec == 0) ? 0.125f * 1.44269504f : 1.0f;
#pragma unroll
        for (int r = 0; r < 4; ++r)
          dst[(size_t)((bb * 12 + h) * 2048 + trow + r) * 64 + d] = f2bf((acc[i][j][r] + bv) * scl);
      }
    }
  }
}

// ---------------- proj GEMM: 64x128 tiles, minimum-2-phase BK=32, fp32 out + bias ----------------
// XCD-swizzled: grid 6x128 = 768 = 8*96. One barrier per step.
__global__ __launch_bounds__(256, 4) void gemm_proj_kernel(
    const u16* __restrict__ A, const u16* __restrict__ BT, const float* __restrict__ bias,
    float* __restrict__ out) {
  constexpr int K = 768;
  constexpr int NS = K / 32;
  __shared__ u16 Asm[2][64 * 32];
  __shared__ u16 Bsm[2][128 * 32];
  const int lin = blockIdx.y * 6 + blockIdx.x;
  const int swz = (lin & 7) * 96 + (lin >> 3);
  const int tid = threadIdx.x;
  const int w = tid >> 6, lane = tid & 63;
  const int l15 = lane & 15, quad = lane >> 4;
  const int srow = tid >> 2, scol = (tid & 3) * 8;
  const int m0 = (swz / 6) * 64, n0 = (swz % 6) * 128;
  const u16* Ag = A + (size_t)(m0 + srow) * K + scol;
  const u16* Bg = BT + (size_t)(n0 + srow) * K + scol;
  const int mw = (w >> 1) * 32, nw = (w & 1) * 64;
  f32x4 acc[2][4];
#pragma unroll
  for (int i = 0; i < 2; ++i)
#pragma unroll
    for (int j = 0; j < 4; ++j) acc[i][j] = {0.f, 0.f, 0.f, 0.f};

  auto STAGE = [&](int buf, int ks) {
    const u16* a = Ag + ks * 32;
    const u16* b = Bg + ks * 32;
    gll16(a, &Asm[buf][(w * 16) * 32]);
#pragma unroll
    for (int rb = 0; rb < 2; ++rb)
      gll16(b + (size_t)rb * 64 * K, &Bsm[buf][(rb * 64 + w * 16) * 32]);
  };
  auto COMPUTE = [&](int buf) {
    bf16x8 af[2], bfj[4];
#pragma unroll
    for (int i = 0; i < 2; ++i) af[i] = *(const bf16x8*)&Asm[buf][(mw + i * 16 + l15) * 32 + quad * 8];
#pragma unroll
    for (int j = 0; j < 4; ++j) bfj[j] = *(const bf16x8*)&Bsm[buf][(nw + j * 16 + l15) * 32 + quad * 8];
#pragma unroll
    for (int i = 0; i < 2; ++i)
#pragma unroll
      for (int j = 0; j < 4; ++j)
        acc[i][j] = __builtin_amdgcn_mfma_f32_16x16x32_bf16(af[i], bfj[j], acc[i][j], 0, 0, 0);
  };

  STAGE(0, 0);
  WAITVM(0); SBAR();
  for (int s = 0; s < NS; ++s) {
    const int buf = s & 1;
    if (s + 1 < NS) STAGE(buf ^ 1, s + 1);
    COMPUTE(buf);
    WAITVM(0); SBAR();
  }

#pragma unroll
  for (int j = 0; j < 4; ++j) {
    const int n = n0 + nw + j * 16 + l15;
    const float bv = bias[n];
#pragma unroll
    for (int i = 0; i < 2; ++i) {
      const int m = m0 + mw + i * 16 + quad * 4;
#pragma unroll
      for (int r = 0; r < 4; ++r) out[(size_t)(m + r) * 768 + n] = acc[i][j][r] + bv;
    }
  }
}

// ---------------- split-K causal flash attention, 8 waves / 128 q-rows per block ----------------
// Work unit: (bh, 128-q tile qt2 in 0..15, chunk c of <=8 k-tiles among nkt=2*qt2+2).
// 40 slots per bh. XCD-swizzled (T1): grid 40x48 = 1920 = 8*240; each XCD gets 6
// consecutive bh (3MB K/V, L2-resident); long-chunks-first preserved within each bh.
// 8 waves (512 thr); per-wave math identical to the 4-wave version (VGPR ~52).
// Waves 0-3 skip the block's final diagonal tile via wdiag guard (barriers uniform).
// P exchange in-register (T12); l-sum via ones-MFMA.
__global__ __launch_bounds__(512) void attn_split_kernel(
    const u16* __restrict__ Qg, const u16* __restrict__ Kg, const u16* __restrict__ Vtg,
    u16* __restrict__ Yb, float* __restrict__ Opart, float* __restrict__ lpart) {
  constexpr int T = 2048, D = 64;
  constexpr int LDP = 72;
  constexpr float MBOUND = 20.0f;
  __shared__ u16 Ks[2][64 * LDP];   // K tile  [k][d]
  __shared__ u16 VTs[2][64 * LDP];  // V^T tile [d][sigma(k)]
  const int lin = blockIdx.y * 40 + blockIdx.x;
  const int swzb = (lin & 7) * 240 + (lin >> 3);
  const int s = 39 - (swzb % 40);   // long chunks first (within each bh)
  const int bh = swzb / 40;
  int qt2, c;
  if (s < 4) { qt2 = s; c = 0; }
  else if (s < 12) { qt2 = 4 + ((s - 4) >> 1); c = (s - 4) & 1; }
  else if (s < 24) { int u = s - 12; int q3 = u / 3; qt2 = 8 + q3; c = u - 3 * q3; }
  else { int u = s - 24; qt2 = 12 + (u >> 2); c = u & 3; }
  const int nkt = 2 * qt2 + 2;
  const int niter = min(8, nkt - 8 * c);
  const int tid = threadIdx.x;
  const int w = tid >> 6, lane = tid & 63;
  const int l15 = lane & 15, quad = lane >> 4;
  // staging: 512 threads, one u32x4 (16B) each for K and V
  const int srow = tid >> 3;                // 0..63
  const int scol = (tid & 7) * 8;           // u16 units
  const int so0 = scol - 4 * (tid & 1);     // sigma dest for lo half
  const int so1 = scol + 8 - 4 * (tid & 1); // sigma dest for hi half
  const u16* Kp = Kg + (size_t)bh * T * D;
  const u16* VTp = Vtg + (size_t)bh * D * T;

  // per-wave role: rows qq; diagonal tile index for this wave
  const int wdiag = 2 * qt2 + (w >> 2);
  const int qq = qt2 * 128 + w * 16 + l15;
  const u16* qrow = Qg + ((size_t)bh * T + qq) * D;
  const bf16x8 qfa = *(const bf16x8*)(qrow + quad * 8);
  const bf16x8 qfb = *(const bf16x8*)(qrow + 32 + quad * 8);

  // all-ones bf16 A-operand for the l-sum MFMA
  u32x4 onesw; onesw[0] = 0x3F803F80u; onesw[1] = 0x3F803F80u; onesw[2] = 0x3F803F80u; onesw[3] = 0x3F803F80u;
  const bf16x8 ones = __builtin_bit_cast(bf16x8, onesw);

  f32x4 o[4] = {{0,0,0,0},{0,0,0,0},{0,0,0,0},{0,0,0,0}};  // O^T: row=d, col=q=l15
  f32x4 lacc = {0.f, 0.f, 0.f, 0.f};                       // l via ones-MFMA

  u32x4 kA, vA;
  auto LOADT = [&](int kt) {
    const int k1 = kt * 64;
    kA = *(const u32x4*)(Kp + (size_t)(k1 + srow) * D + scol);
    vA = *(const u32x4*)(VTp + (size_t)srow * T + k1 + scol);
  };
  auto STORET = [&](int buf) {
    *(u32x4*)&Ks[buf][srow * LDP + scol] = kA;
    u32x2 vlo; vlo[0] = vA[0]; vlo[1] = vA[1];
    u32x2 vhi; vhi[0] = vA[2]; vhi[1] = vA[3];
    *(u32x2*)&VTs[buf][srow * LDP + so0] = vlo;
    *(u32x2*)&VTs[buf][srow * LDP + so1] = vhi;
  };

  // prologue: tile 0 -> buf0; prefetch tile 1
  LOADT(c * 8);
  STORET(0);
  if (niter > 1) LOADT(c * 8 + 1);
  __syncthreads();

  for (int j = 0; j < niter; ++j) {
    const int buf = j & 1;
    const int ktg = c * 8 + j;
    if (ktg <= wdiag) {
      // S^T = K.Q^T : C-layout row = k_local = 16t+quad*4+r, col = q = l15
      f32x4 sA[4];
#pragma unroll
      for (int t = 0; t < 4; ++t) sA[t] = {-MBOUND, -MBOUND, -MBOUND, -MBOUND};
      __builtin_amdgcn_s_setprio(1);
#pragma unroll
      for (int t = 0; t < 4; ++t) {
        const bf16x8 kf0 = *(const bf16x8*)&Ks[buf][(t * 16 + l15) * LDP + quad * 8];
        const bf16x8 kf1 = *(const bf16x8*)&Ks[buf][(t * 16 + l15) * LDP + 32 + quad * 8];
        sA[t] = __builtin_amdgcn_mfma_f32_16x16x32_bf16(kf0, qfa, sA[t], 0, 0, 0);
        sA[t] = __builtin_amdgcn_mfma_f32_16x16x32_bf16(kf1, qfb, sA[t], 0, 0, 0);
      }
      __builtin_amdgcn_s_setprio(0);
      if (ktg == wdiag) {  // this wave's diagonal tile: causal mask
        const int k0 = ktg * 64;
#pragma unroll
        for (int t = 0; t < 4; ++t)
#pragma unroll
          for (int r = 0; r < 4; ++r)
            if (k0 + t * 16 + quad * 4 + r > qq) sA[t][r] = -1e30f;
      }
      // fixed-max softmax: p = 2^(s-M) (M folded into acc init), packed in-register
      unsigned W[4][2];
#pragma unroll
      for (int t = 0; t < 4; ++t) {
        float e0 = __builtin_amdgcn_exp2f(sA[t][0]);
        float e1 = __builtin_amdgcn_exp2f(sA[t][1]);
        float e2 = __builtin_amdgcn_exp2f(sA[t][2]);
        float e3 = __builtin_amdgcn_exp2f(sA[t][3]);
        W[t][0] = cvtpk(e0, e1);
        W[t][1] = cvtpk(e2, e3);
      }
      plswap(W[0][0], W[1][0]);
      plswap(W[0][1], W[1][1]);
      plswap(W[2][0], W[3][0]);
      plswap(W[2][1], W[3][1]);
      u32x4 paw; paw[0] = W[0][0]; paw[1] = W[0][1]; paw[2] = W[1][0]; paw[3] = W[1][1];
      u32x4 pbw; pbw[0] = W[2][0]; pbw[1] = W[2][1]; pbw[2] = W[3][0]; pbw[3] = W[3][1];
      const bf16x8 pa = __builtin_bit_cast(bf16x8, paw);
      const bf16x8 pb = __builtin_bit_cast(bf16x8, pbw);
      // O^T += V^T.P^T ; l += ones.P^T
      __builtin_amdgcn_s_setprio(1);
      lacc = __builtin_amdgcn_mfma_f32_16x16x32_bf16(ones, pa, lacc, 0, 0, 0);
      lacc = __builtin_amdgcn_mfma_f32_16x16x32_bf16(ones, pb, lacc, 0, 0, 0);
#pragma unroll
      for (int t = 0; t < 4; ++t) {
        const bf16x8 vf0 = *(const bf16x8*)&VTs[buf][(t * 16 + l15) * LDP + quad * 8];
        const bf16x8 vf1 = *(const bf16x8*)&VTs[buf][(t * 16 + l15) * LDP + 32 + quad * 8];
        o[t] = __builtin_amdgcn_mfma_f32_16x16x32_bf16(vf0, pa, o[t], 0, 0, 0);
        o[t] = __builtin_amdgcn_mfma_f32_16x16x32_bf16(vf1, pb, o[t], 0, 0, 0);
      }
      __builtin_amdgcn_s_setprio(0);
    }
    // stage tile j+1 into the other buffer; prefetch tile j+2
    if (j + 1 < niter) {
      STORET(buf ^ 1);
      if (j + 2 < niter) LOADT(c * 8 + j + 2);
    }
    __syncthreads();
  }

  const float lv = lacc[0];   // every lane holds the full 64-wide sum for its q
  if (qt2 <= 3) {
    // single chunk: normalize + write Yb directly
    const float inv = 1.f / lv;
    const int bidx = bh / 12, hidx = bh % 12;
    u16* y = Yb + ((size_t)bidx * T + qq) * 768 + hidx * 64;
#pragma unroll
    for (int t = 0; t < 4; ++t) {
      u32x2 pk;
      pk[0] = cvtpk(o[t][0] * inv, o[t][1] * inv);
      pk[1] = cvtpk(o[t][2] * inv, o[t][3] * inv);
      *(u32x2*)(y + t * 16 + quad * 4) = pk;
    }
  } else {
    // write unnormalized partials: Opart[pidx][q(128)][d(64)] fp32, lpart[pidx][q(128)]
    const size_t pidx = (size_t)bh * 40 + s;
    float* Op = Opart + pidx * 8192 + (size_t)(w * 16 + l15) * 64;
#pragma unroll
    for (int t = 0; t < 4; ++t) *(f32x4*)(Op + t * 16 + quad * 4) = o[t];
    if (quad == 0) lpart[pidx * 128 + w * 16 + l15] = lv;
  }
}

// ---------------- combine partials for qt2 >= 4 ----------------
__global__ __launch_bounds__(256) void attn_combine_kernel(
    const float* __restrict__ Opart, const float* __restrict__ lpart, u16* __restrict__ Yb) {
  constexpr int T = 2048;
  const int qt2 = 4 + blockIdx.x;   // 4..15
  const int bh = blockIdx.y;
  const int nch = (qt2 < 8) ? 2 : (qt2 < 12) ? 3 : 4;
  const int off = (qt2 < 8) ? 4 + (qt2 - 4) * 2 : (qt2 < 12) ? 12 + (qt2 - 8) * 3 : 24 + (qt2 - 12) * 4;
  const size_t base = (size_t)bh * 40 + off;
  const int tid = threadIdx.x;
  const int q = tid >> 1, db = (tid & 1) * 32;   // 128 q rows x 2 d-halves
  f32x4 o[8] = {{0,0,0,0},{0,0,0,0},{0,0,0,0},{0,0,0,0},{0,0,0,0},{0,0,0,0},{0,0,0,0},{0,0,0,0}};
  float l = 0.f;
  for (int cc = 0; cc < nch; ++cc) {
    const float* Op = Opart + (base + cc) * 8192 + (size_t)q * 64 + db;
#pragma unroll
    for (int v = 0; v < 8; ++v) o[v] += *(const f32x4*)(Op + v * 4);
    l += lpart[(base + cc) * 128 + q];
  }
  const float inv = 1.f / l;
  const int bidx = bh / 12, hidx = bh % 12;
  u16* y = Yb + ((size_t)bidx * T + qt2 * 128 + q) * 768 + hidx * 64 + db;
#pragma unroll
  for (int g = 0; g < 2; ++g) {
    u32x4 pk;
    pk[0] = cvtpk(o[g * 4 + 0][0] * inv, o[g * 4 + 0][1] * inv);
    pk[1] = cvtpk(o[g * 4 + 0][2] * inv, o[g * 4 + 0][3] * inv);
    pk[2] = cvtpk(o[g * 4 + 1][0] * inv, o[g * 4 + 1][1] * inv);
    pk[3] = cvtpk(o[g * 4 + 1][2] * inv, o[g * 4 + 1][3] * inv);
    *(u32x4*)(y + g * 16) = pk;
    pk[0] = cvtpk(o[g * 4 + 2][0] * inv, o[g * 4 + 2][1] * inv);
    pk[1] = cvtpk(o[g * 4 + 2][2] * inv, o[g * 4 + 2][3] * inv);
    pk[2] = cvtpk(o[g * 4 + 3][0] * inv, o[g * 4 + 3][1] * inv);
    pk[3] = cvtpk(o[g * 4 + 3][2] * inv, o[g * 4 + 3][3] * inv);
    *(u32x4*)(y + g * 16 + 8) = pk;
  }
}

// ---------------- fallback attention (used if ws too small) ----------------
__global__ __launch_bounds__(256) void attn_kernel(
    const u16* __restrict__ Qg, const u16* __restrict__ Kg, const u16* __restrict__ Vtg,
    u16* __restrict__ Yb) {
  constexpr int T = 2048, D = 64;
  constexpr int LDP = 72;
  constexpr float MBOUND = 20.0f;
  __shared__ u16 Ks[64 * LDP];
  __shared__ u16 VTs[64 * LDP];
  __shared__ u16 Ps[4 * 32 * LDP];
  const int qb = 15 - blockIdx.x;
  const int bh = blockIdx.y;
  const int Q0 = qb * 128;
  const int bidx = bh / 12, hidx = bh % 12;
  const int tid = threadIdx.x;
  const int w = tid >> 6, lane = tid & 63;
  const int l15 = lane & 15, quad = lane >> 4;
  const int srow = tid >> 2, scol = (tid & 3) * 16;
  const u16* Kp = Kg + (size_t)bh * T * D;
  const u16* VTp = Vtg + (size_t)bh * D * T;
  u16* pw0 = &Ps[(w * 32) * LDP];
  u16* pw1 = &Ps[(w * 32 + 16) * LDP];
  const u16* qrow0 = Qg + ((size_t)bh * T + Q0 + w * 16 + l15) * D;
  const bf16x8 qf0a = *(const bf16x8*)(qrow0 + quad * 8);
  const bf16x8 qf0b = *(const bf16x8*)(qrow0 + 32 + quad * 8);
  const bf16x8 qf1a = *(const bf16x8*)(qrow0 + (size_t)64 * D + quad * 8);
  const bf16x8 qf1b = *(const bf16x8*)(qrow0 + (size_t)64 * D + 32 + quad * 8);
  const int qq0 = Q0 + w * 16 + l15, qq1 = qq0 + 64;
  f32x4 o0[4] = {{0,0,0,0},{0,0,0,0},{0,0,0,0},{0,0,0,0}};
  f32x4 o1[4] = {{0,0,0,0},{0,0,0,0},{0,0,0,0},{0,0,0,0}};
  float l0v = 0.f, l1v = 0.f;
  const int nkt = 2 * qb + 2;
  u32x4 kA = *(const u32x4*)(Kp + (size_t)srow * D + scol);
  u32x4 kB = *(const u32x4*)(Kp + (size_t)srow * D + scol + 8);
  u32x4 vA = *(const u32x4*)(VTp + (size_t)srow * T + scol);
  u32x4 vB = *(const u32x4*)(VTp + (size_t)srow * T + scol + 8);
  for (int kt = 0; kt < nkt; ++kt) {
    __syncthreads();
    *(u32x4*)&Ks[srow * LDP + scol] = kA;
    *(u32x4*)&Ks[srow * LDP + scol + 8] = kB;
    *(u32x4*)&VTs[srow * LDP + scol] = vA;
    *(u32x4*)&VTs[srow * LDP + scol + 8] = vB;
    __syncthreads();
    if (kt + 1 < nkt) {
      const int k1 = (kt + 1) * 64;
      kA = *(const u32x4*)(Kp + (size_t)(k1 + srow) * D + scol);
      kB = *(const u32x4*)(Kp + (size_t)(k1 + srow) * D + scol + 8);
      vA = *(const u32x4*)(VTp + (size_t)srow * T + k1 + scol);
      vB = *(const u32x4*)(VTp + (size_t)srow * T + k1 + scol + 8);
    }
    const int k0 = kt * 64;
    const bool g0a = (kt <= 2 * qb);
    f32x4 s0[4] = {{0,0,0,0},{0,0,0,0},{0,0,0,0},{0,0,0,0}};
    f32x4 s1[4] = {{0,0,0,0},{0,0,0,0},{0,0,0,0},{0,0,0,0}};
#pragma unroll
    for (int t = 0; t < 4; ++t) {
      const bf16x8 kf0 = *(const bf16x8*)&Ks[(t * 16 + l15) * LDP + quad * 8];
      const bf16x8 kf1 = *(const bf16x8*)&Ks[(t * 16 + l15) * LDP + 32 + quad * 8];
      s0[t] = __builtin_amdgcn_mfma_f32_16x16x32_bf16(kf0, qf0a, s0[t], 0, 0, 0);
      s0[t] = __builtin_amdgcn_mfma_f32_16x16x32_bf16(kf1, qf0b, s0[t], 0, 0, 0);
      s1[t] = __builtin_amdgcn_mfma_f32_16x16x32_bf16(kf0, qf1a, s1[t], 0, 0, 0);
      s1[t] = __builtin_amdgcn_mfma_f32_16x16x32_bf16(kf1, qf1b, s1[t], 0, 0, 0);
    }
    if (g0a) {
      if (kt == 2 * qb) {
#pragma unroll
        for (int t = 0; t < 4; ++t)
#pragma unroll
          for (int r = 0; r < 4; ++r)
            if (k0 + t * 16 + quad * 4 + r > qq0) s0[t][r] = -1e30f;
      }
#pragma unroll
      for (int t = 0; t < 4; ++t) {
        float e0 = __builtin_amdgcn_exp2f(s0[t][0] - MBOUND);
        float e1 = __builtin_amdgcn_exp2f(s0[t][1] - MBOUND);
        float e2 = __builtin_amdgcn_exp2f(s0[t][2] - MBOUND);
        float e3 = __builtin_amdgcn_exp2f(s0[t][3] - MBOUND);
        l0v += (e0 + e1) + (e2 + e3);
        u32x2 pk;
        pk[0] = cvtpk(e0, e1);
        pk[1] = cvtpk(e2, e3);
        *(u32x2*)&pw0[l15 * LDP + t * 16 + quad * 4] = pk;
      }
    }
    {
      if (kt == 2 * qb + 1) {
#pragma unroll
        for (int t = 0; t < 4; ++t)
#pragma unroll
          for (int r = 0; r < 4; ++r)
            if (k0 + t * 16 + quad * 4 + r > qq1) s1[t][r] = -1e30f;
      }
#pragma unroll
      for (int t = 0; t < 4; ++t) {
        float e0 = __builtin_amdgcn_exp2f(s1[t][0] - MBOUND);
        float e1 = __builtin_amdgcn_exp2f(s1[t][1] - MBOUND);
        float e2 = __builtin_amdgcn_exp2f(s1[t][2] - MBOUND);
        float e3 = __builtin_amdgcn_exp2f(s1[t][3] - MBOUND);
        l1v += (e0 + e1) + (e2 + e3);
        u32x2 pk;
        pk[0] = cvtpk(e0, e1);
        pk[1] = cvtpk(e2, e3);
        *(u32x2*)&pw1[l15 * LDP + t * 16 + quad * 4] = pk;
      }
    }
    const bf16x8 p0a = *(const bf16x8*)&pw0[l15 * LDP + quad * 8];
    const bf16x8 p0b = *(const bf16x8*)&pw0[l15 * LDP + 32 + quad * 8];
    const bf16x8 p1a = *(const bf16x8*)&pw1[l15 * LDP + quad * 8];
    const bf16x8 p1b = *(const bf16x8*)&pw1[l15 * LDP + 32 + quad * 8];
#pragma unroll
    for (int t = 0; t < 4; ++t) {
      const bf16x8 vf0 = *(const bf16x8*)&VTs[(t * 16 + l15) * LDP + quad * 8];
      const bf16x8 vf1 = *(const bf16x8*)&VTs[(t * 16 + l15) * LDP + 32 + quad * 8];
      if (g0a) {
        o0[t] = __builtin_amdgcn_mfma_f32_16x16x32_bf16(vf0, p0a, o0[t], 0, 0, 0);
        o0[t] = __builtin_amdgcn_mfma_f32_16x16x32_bf16(vf1, p0b, o0[t], 0, 0, 0);
      }
      o1[t] = __builtin_amdgcn_mfma_f32_16x16x32_bf16(vf0, p1a, o1[t], 0, 0, 0);
      o1[t] = __builtin_amdgcn_mfma_f32_16x16x32_bf16(vf1, p1b, o1[t], 0, 0, 0);
    }
  }
  l0v += __shfl_xor(l0v, 16); l0v += __shfl_xor(l0v, 32);
  l1v += __shfl_xor(l1v, 16); l1v += __shfl_xor(l1v, 32);
  const float inv0 = 1.f / l0v, inv1 = 1.f / l1v;
  u16* y0 = Yb + ((size_t)bidx * T + qq0) * 768 + hidx * 64;
  u16* y1 = Yb + ((size_t)bidx * T + qq1) * 768 + hidx * 64;
#pragma unroll
  for (int t = 0; t < 4; ++t) {
    u32x2 pk0, pk1;
    pk0[0] = cvtpk(o0[t][0] * inv0, o0[t][1] * inv0);
    pk0[1] = cvtpk(o0[t][2] * inv0, o0[t][3] * inv0);
    pk1[0] = cvtpk(o1[t][0] * inv1, o1[t][1] * inv1);
    pk1[1] = cvtpk(o1[t][2] * inv1, o1[t][3] * inv1);
    *(u32x2*)(y0 + t * 16 + quad * 4) = pk0;
    *(u32x2*)(y1 + t * 16 + quad * 4) = pk1;
  }
}

extern "C" void kernel_launch(void* const* d_in, const int* in_sizes, int n_in,
                              void* d_out, int out_size, void* d_ws, size_t ws_size,
                              hipStream_t stream) {
  const float* x = (const float*)d_in[0];
  const float* W_qkv = (const float*)d_in[1];
  const float* b_qkv = (const float*)d_in[2];
  const float* W_proj = (const float*)d_in[3];
  const float* b_proj = (const float*)d_in[4];
  float* out = (float*)d_out;

  constexpr size_t MC = (size_t)8192 * 768;
  u16* xb = (u16*)d_ws;
  u16* Qb = xb + MC;
  u16* Kb = Qb + MC;
  u16* Vt = Kb + MC;   // transposed V: [bh][d][t]
  u16* Yb = Vt + MC;
  u16* WqkvT = Yb + MC;
  u16* WprojT = WqkvT + (size_t)2304 * 768;
  // split-K partials (after the bf16 region); 1920*8192 == 3840*4096 (same bytes)
  constexpr size_t BASE_U16 = 5 * MC + (size_t)2304 * 768 + (size_t)768 * 768;  // 33,816,576
  float* Opart = (float*)((u16*)d_ws + BASE_U16);
  float* lpart = Opart + (size_t)1920 * 8192;
  constexpr size_t NEED = BASE_U16 * 2 + ((size_t)1920 * 8192 + (size_t)1920 * 128) * 4;
  const bool use_split = (ws_size >= NEED);

  cast_x_kernel<<<6291456 / (4 * 256), 256, 0, stream>>>(x, xb, 6291456 / 4);
  transpose_cast_kernel<<<dim3(2304 / 32, 768 / 32), 256, 0, stream>>>(W_qkv, WqkvT, 768, 2304);
  transpose_cast_kernel<<<dim3(768 / 32, 768 / 32), 256, 0, stream>>>(W_proj, WprojT, 768, 768);
  gemm_qkv_kernel<<<dim3(18, 64), 256, 0, stream>>>(xb, WqkvT, b_qkv, Qb, Kb, Vt);
  if (use_split) {
    attn_split_kernel<<<dim3(40, 48), 512, 0, stream>>>(Qb, Kb, Vt, Yb, Opart, lpart);
    attn_combine_kernel<<<dim3(12, 48), 256, 0, stream>>>(Opart, lpart, Yb);
  } else {
    attn_kernel<<<dim3(16, 48), 256, 0, stream>>>(Qb, Kb, Vt, Yb);
  }
  gemm_proj_kernel<<<dim3(6, 128), 256, 0, stream>>>(Yb, WprojT, b_proj, out);
}

// Round 11
// 217.268 us; speedup vs baseline: 1.1512x; 1.0266x over previous
//
#include <hip/hip_runtime.h>
#include <hip/hip_bf16.h>

typedef __bf16 bf16x8 __attribute__((ext_vector_type(8)));
typedef float f32x4 __attribute__((ext_vector_type(4)));
typedef unsigned int u32x4 __attribute__((ext_vector_type(4)));
typedef unsigned int u32x2 __attribute__((ext_vector_type(2)));
typedef int i32x2 __attribute__((ext_vector_type(2)));
typedef unsigned short u16;
typedef unsigned long long u64;

#define WAITVM(n) asm volatile("s_waitcnt vmcnt(" #n ")" ::: "memory")
#define SBAR() asm volatile("s_barrier" ::: "memory")

__device__ __forceinline__ u16 f2bf(float f) {
  unsigned u = __builtin_bit_cast(unsigned, f);
  u += 0x7FFFu + ((u >> 16) & 1u);   // RNE
  return (u16)(u >> 16);
}
// HW packed convert: 2 fp32 -> 2 bf16 (v_cvt_pk_bf16_f32, RNE)
__device__ __forceinline__ unsigned cvtpk(float a, float b) {
  float2 f; f.x = a; f.y = b;
  __hip_bfloat162 h = __float22bfloat162_rn(f);
  unsigned u;
  __builtin_memcpy(&u, &h, 4);
  return u;
}

// v_permlane32_swap_b32: after call, a = [a.lo ; b.lo], b = [a.hi ; b.hi]
__device__ __forceinline__ void plswap(unsigned &a, unsigned &b) {
  i32x2 r = __builtin_amdgcn_permlane32_swap((int)a, (int)b, false, false);
  a = (unsigned)r[0];
  b = (unsigned)r[1];
}

// async global->LDS direct copy, 16B per lane. LDS dest = wave-uniform base + lane*16.
__device__ __forceinline__ void gll16(const u16* g, u16* l) {
  __builtin_amdgcn_global_load_lds(
      (const __attribute__((address_space(1))) unsigned int*)g,
      (__attribute__((address_space(3))) unsigned int*)l, 16, 0, 0);
}

// ---------------- cast x (fp32 -> bf16), vectorized ----------------
__global__ void cast_x_kernel(const float* __restrict__ in, u16* __restrict__ out, int n4) {
  int i = blockIdx.x * blockDim.x + threadIdx.x;
  if (i >= n4) return;
  f32x4 v = *(const f32x4*)(in + (size_t)i * 4);
  u32x2 pk;
  pk[0] = cvtpk(v[0], v[1]);
  pk[1] = cvtpk(v[2], v[3]);
  *(u32x2*)(out + (size_t)i * 4) = pk;
}

// ------------- transpose + cast: W[K][N] fp32 -> WT[N][K] bf16 -------------
__global__ void transpose_cast_kernel(const float* __restrict__ W, u16* __restrict__ WT, int K, int N) {
  __shared__ float tile[32][33];
  int c0 = blockIdx.x * 32, r0 = blockIdx.y * 32;
  int tx = threadIdx.x & 31, tg = threadIdx.x >> 5;
#pragma unroll
  for (int i = 0; i < 4; ++i) {
    int r = tg + i * 8;
    tile[r][tx] = W[(size_t)(r0 + r) * N + c0 + tx];
  }
  __syncthreads();
#pragma unroll
  for (int i = 0; i < 4; ++i) {
    int r = tg + i * 8;
    WT[(size_t)(c0 + r) * K + r0 + tx] = f2bf(tile[tx][r]);
  }
}

// ---------------- QKV GEMM: [8192x768] x [768x2304] ----------------
// 128x128 tile, 256 thr, BK=32, 24 steps, 3-STAGE LDS pipeline (depth 2): tile s's
// loads issued two compute phases before use; counted WAITVM(8) gives ~400-500cy cover.
// (R10 verified: this beat the depth-1 R5 loop.) No XCD swizzle (R6: L3-fit).
// Q pre-scaled by 0.125*log2(e). V written TRANSPOSED: Vt[bh][d][t].
__global__ __launch_bounds__(256, 3) void gemm_qkv_kernel(
    const u16* __restrict__ A, const u16* __restrict__ BT, const float* __restrict__ bias,
    u16* __restrict__ Qb, u16* __restrict__ Kb, u16* __restrict__ Vt) {
  constexpr int K = 768;
  constexpr int NS = K / 32;  // 24 pipeline steps (multiple of 3)
  __shared__ u16 Asm[3][128 * 32];
  __shared__ u16 Bsm[3][128 * 32];
  const int tid = threadIdx.x;
  const int w = tid >> 6, lane = tid & 63;
  const int l15 = lane & 15, quad = lane >> 4;
  const int srow = tid >> 2, scol = (tid & 3) * 8;
  const int m0 = blockIdx.y * 128, n0 = blockIdx.x * 128;
  const u16* Ag = A + (size_t)(m0 + srow) * K + scol;
  const u16* Bg = BT + (size_t)(n0 + srow) * K + scol;
  const int mw = (w >> 1) * 64, nw = (w & 1) * 64;
  f32x4 acc[4][4];
#pragma unroll
  for (int i = 0; i < 4; ++i)
#pragma unroll
    for (int j = 0; j < 4; ++j) acc[i][j] = {0.f, 0.f, 0.f, 0.f};

  auto STAGE = [&](int buf, int ks) {
    const u16* a = Ag + ks * 32;
    const u16* b = Bg + ks * 32;
#pragma unroll
    for (int rb = 0; rb < 2; ++rb) {
      gll16(a + (size_t)rb * 64 * K, &Asm[buf][(rb * 64 + w * 16) * 32]);
      gll16(b + (size_t)rb * 64 * K, &Bsm[buf][(rb * 64 + w * 16) * 32]);
    }
  };
  auto COMPUTE = [&](int buf) {
    bf16x8 af[4], bfj[4];
#pragma unroll
    for (int i = 0; i < 4; ++i) af[i] = *(const bf16x8*)&Asm[buf][(mw + i * 16 + l15) * 32 + quad * 8];
#pragma unroll
    for (int j = 0; j < 4; ++j) bfj[j] = *(const bf16x8*)&Bsm[buf][(nw + j * 16 + l15) * 32 + quad * 8];
#pragma unroll
    for (int i = 0; i < 4; ++i)
#pragma unroll
      for (int j = 0; j < 4; ++j)
        acc[i][j] = __builtin_amdgcn_mfma_f32_16x16x32_bf16(af[i], bfj[j], acc[i][j], 0, 0, 0);
  };

  STAGE(0, 0);
  STAGE(1, 1);
  for (int s = 0; s < NS - 3; s += 3) {
    STAGE((s + 2) % 3, s + 2); WAITVM(8); SBAR(); COMPUTE(s % 3); SBAR();
    STAGE((s + 3) % 3, s + 3); WAITVM(8); SBAR(); COMPUTE((s + 1) % 3); SBAR();
    STAGE((s + 4) % 3, s + 4); WAITVM(8); SBAR(); COMPUTE((s + 2) % 3); SBAR();
  }
  STAGE((NS - 1) % 3, NS - 1); WAITVM(8); SBAR(); COMPUTE((NS - 3) % 3); SBAR();
  WAITVM(4); SBAR(); COMPUTE((NS - 2) % 3); SBAR();
  WAITVM(0); SBAR(); COMPUTE((NS - 1) % 3);

  const int sec = blockIdx.x / 6;           // 0:Q 1:K 2:V (uniform per block; 768%128==0)
  const int nbase = n0 - sec * 768;
#pragma unroll
  for (int j = 0; j < 4; ++j) {
    const int nloc = nbase + nw + j * 16 + l15;
    const float bv = bias[sec * 768 + nloc];
    const int h = nloc >> 6, d = nloc & 63;
#pragma unroll
    for (int i = 0; i < 4; ++i) {
      const int m = m0 + mw + i * 16 + quad * 4;
      const int bb = m >> 11, trow = m & 2047;
      if (sec == 2) {
        u32x2 pk;
        pk[0] = cvtpk(acc[i][j][0] + bv, acc[i][j][1] + bv);
        pk[1] = cvtpk(acc[i][j][2] + bv, acc[i][j][3] + bv);
        *(u32x2*)(Vt + (size_t)((bb * 12 + h) * 64 + d) * 2048 + trow) = pk;
      } else {
        u16* dst = (sec == 0) ? Qb : Kb;
        const float scl = (sec == 0) ? 0.125f * 1.44269504f : 1.0f;
#pragma unroll
        for (int r = 0; r < 4; ++r)
          dst[(size_t)((bb * 12 + h) * 2048 + trow + r) * 64 + d] = f2bf((acc[i][j][r] + bv) * scl);
      }
    }
  }
}

// ---------------- proj GEMM: 64x128 tiles, 3-stage depth-2 pipeline, fp32 out + bias ----------------
// Same counted-vmcnt schedule as qkv (R10-verified): 3 loads/stage -> WAITVM(6) steady,
// WAITVM(3)/WAITVM(0) drain. LDS 36KB -> 4 blocks/CU. XCD-swizzled (grid 768 = 8*96).
__global__ __launch_bounds__(256, 4) void gemm_proj_kernel(
    const u16* __restrict__ A, const u16* __restrict__ BT, const float* __restrict__ bias,
    float* __restrict__ out) {
  constexpr int K = 768;
  constexpr int NS = K / 32;
  __shared__ u16 Asm[3][64 * 32];
  __shared__ u16 Bsm[3][128 * 32];
  const int lin = blockIdx.y * 6 + blockIdx.x;
  const int swz = (lin & 7) * 96 + (lin >> 3);
  const int tid = threadIdx.x;
  const int w = tid >> 6, lane = tid & 63;
  const int l15 = lane & 15, quad = lane >> 4;
  const int srow = tid >> 2, scol = (tid & 3) * 8;
  const int m0 = (swz / 6) * 64, n0 = (swz % 6) * 128;
  const u16* Ag = A + (size_t)(m0 + srow) * K + scol;
  const u16* Bg = BT + (size_t)(n0 + srow) * K + scol;
  const int mw = (w >> 1) * 32, nw = (w & 1) * 64;
  f32x4 acc[2][4];
#pragma unroll
  for (int i = 0; i < 2; ++i)
#pragma unroll
    for (int j = 0; j < 4; ++j) acc[i][j] = {0.f, 0.f, 0.f, 0.f};

  auto STAGE = [&](int buf, int ks) {
    const u16* a = Ag + ks * 32;
    const u16* b = Bg + ks * 32;
    gll16(a, &Asm[buf][(w * 16) * 32]);
#pragma unroll
    for (int rb = 0; rb < 2; ++rb)
      gll16(b + (size_t)rb * 64 * K, &Bsm[buf][(rb * 64 + w * 16) * 32]);
  };
  auto COMPUTE = [&](int buf) {
    bf16x8 af[2], bfj[4];
#pragma unroll
    for (int i = 0; i < 2; ++i) af[i] = *(const bf16x8*)&Asm[buf][(mw + i * 16 + l15) * 32 + quad * 8];
#pragma unroll
    for (int j = 0; j < 4; ++j) bfj[j] = *(const bf16x8*)&Bsm[buf][(nw + j * 16 + l15) * 32 + quad * 8];
#pragma unroll
    for (int i = 0; i < 2; ++i)
#pragma unroll
      for (int j = 0; j < 4; ++j)
        acc[i][j] = __builtin_amdgcn_mfma_f32_16x16x32_bf16(af[i], bfj[j], acc[i][j], 0, 0, 0);
  };

  STAGE(0, 0);
  STAGE(1, 1);
  for (int s = 0; s < NS - 3; s += 3) {
    STAGE((s + 2) % 3, s + 2); WAITVM(6); SBAR(); COMPUTE(s % 3); SBAR();
    STAGE((s + 3) % 3, s + 3); WAITVM(6); SBAR(); COMPUTE((s + 1) % 3); SBAR();
    STAGE((s + 4) % 3, s + 4); WAITVM(6); SBAR(); COMPUTE((s + 2) % 3); SBAR();
  }
  STAGE((NS - 1) % 3, NS - 1); WAITVM(6); SBAR(); COMPUTE((NS - 3) % 3); SBAR();
  WAITVM(3); SBAR(); COMPUTE((NS - 2) % 3); SBAR();
  WAITVM(0); SBAR(); COMPUTE((NS - 1) % 3);

#pragma unroll
  for (int j = 0; j < 4; ++j) {
    const int n = n0 + nw + j * 16 + l15;
    const float bv = bias[n];
#pragma unroll
    for (int i = 0; i < 2; ++i) {
      const int m = m0 + mw + i * 16 + quad * 4;
#pragma unroll
      for (int r = 0; r < 4; ++r) out[(size_t)(m + r) * 768 + n] = acc[i][j][r] + bv;
    }
  }
}

// ---------------- split-K causal flash attention, 8 waves / 128 q-rows per block ----------------
// REDUCED SPLIT (R11): 24 slots per bh. qt2 0..7 -> single chunk (niter = nkt <= 16,
// write Yb directly). qt2 8..15 -> TWO equal chunks of nkt/2 (9..16 tiles) -> partials.
// Halves Opart traffic (56.6 -> 25.2 MB each way) and combine work vs the 40-slot scheme.
// XCD-swizzled: grid 24x48 = 1152 = 8*144. 8 waves (512 thr); per-wave math unchanged.
// P exchange in-register (T12); l-sum via ones-MFMA; wdiag guard for diagonal tiles.
__global__ __launch_bounds__(512) void attn_split_kernel(
    const u16* __restrict__ Qg, const u16* __restrict__ Kg, const u16* __restrict__ Vtg,
    u16* __restrict__ Yb, float* __restrict__ Opart, float* __restrict__ lpart) {
  constexpr int T = 2048, D = 64;
  constexpr int LDP = 72;
  constexpr float MBOUND = 20.0f;
  __shared__ u16 Ks[2][64 * LDP];   // K tile  [k][d]
  __shared__ u16 VTs[2][64 * LDP];  // V^T tile [d][sigma(k)]
  const int lin = blockIdx.y * 24 + blockIdx.x;
  const int swzb = (lin & 7) * 144 + (lin >> 3);
  const int s = 23 - (swzb % 24);   // long chunks first (within each bh)
  const int bh = swzb / 24;
  int qt2, c;
  if (s < 8) { qt2 = s; c = 0; }
  else { qt2 = 8 + ((s - 8) >> 1); c = (s - 8) & 1; }
  const int nkt = 2 * qt2 + 2;
  const int half = nkt >> 1;                     // nkt even
  const int start = c ? half : 0;
  const int niter = (qt2 < 8) ? nkt : half;      // equal chunks for qt2 >= 8
  const int tid = threadIdx.x;
  const int w = tid >> 6, lane = tid & 63;
  const int l15 = lane & 15, quad = lane >> 4;
  // staging: 512 threads, one u32x4 (16B) each for K and V
  const int srow = tid >> 3;                // 0..63
  const int scol = (tid & 7) * 8;           // u16 units
  const int so0 = scol - 4 * (tid & 1);     // sigma dest for lo half
  const int so1 = scol + 8 - 4 * (tid & 1); // sigma dest for hi half
  const u16* Kp = Kg + (size_t)bh * T * D;
  const u16* VTp = Vtg + (size_t)bh * D * T;

  // per-wave role: rows qq; diagonal tile index for this wave
  const int wdiag = 2 * qt2 + (w >> 2);
  const int qq = qt2 * 128 + w * 16 + l15;
  const u16* qrow = Qg + ((size_t)bh * T + qq) * D;
  const bf16x8 qfa = *(const bf16x8*)(qrow + quad * 8);
  const bf16x8 qfb = *(const bf16x8*)(qrow + 32 + quad * 8);

  // all-ones bf16 A-operand for the l-sum MFMA
  u32x4 onesw; onesw[0] = 0x3F803F80u; onesw[1] = 0x3F803F80u; onesw[2] = 0x3F803F80u; onesw[3] = 0x3F803F80u;
  const bf16x8 ones = __builtin_bit_cast(bf16x8, onesw);

  f32x4 o[4] = {{0,0,0,0},{0,0,0,0},{0,0,0,0},{0,0,0,0}};  // O^T: row=d, col=q=l15
  f32x4 lacc = {0.f, 0.f, 0.f, 0.f};                       // l via ones-MFMA

  u32x4 kA, vA;
  auto LOADT = [&](int kt) {
    const int k1 = kt * 64;
    kA = *(const u32x4*)(Kp + (size_t)(k1 + srow) * D + scol);
    vA = *(const u32x4*)(VTp + (size_t)srow * T + k1 + scol);
  };
  auto STORET = [&](int buf) {
    *(u32x4*)&Ks[buf][srow * LDP + scol] = kA;
    u32x2 vlo; vlo[0] = vA[0]; vlo[1] = vA[1];
    u32x2 vhi; vhi[0] = vA[2]; vhi[1] = vA[3];
    *(u32x2*)&VTs[buf][srow * LDP + so0] = vlo;
    *(u32x2*)&VTs[buf][srow * LDP + so1] = vhi;
  };

  // prologue: first tile -> buf0; prefetch next
  LOADT(start);
  STORET(0);
  if (niter > 1) LOADT(start + 1);
  __syncthreads();

  for (int j = 0; j < niter; ++j) {
    const int buf = j & 1;
    const int ktg = start + j;
    if (ktg <= wdiag) {
      // S^T = K.Q^T : C-layout row = k_local = 16t+quad*4+r, col = q = l15
      f32x4 sA[4];
#pragma unroll
      for (int t = 0; t < 4; ++t) sA[t] = {-MBOUND, -MBOUND, -MBOUND, -MBOUND};
      __builtin_amdgcn_s_setprio(1);
#pragma unroll
      for (int t = 0; t < 4; ++t) {
        const bf16x8 kf0 = *(const bf16x8*)&Ks[buf][(t * 16 + l15) * LDP + quad * 8];
        const bf16x8 kf1 = *(const bf16x8*)&Ks[buf][(t * 16 + l15) * LDP + 32 + quad * 8];
        sA[t] = __builtin_amdgcn_mfma_f32_16x16x32_bf16(kf0, qfa, sA[t], 0, 0, 0);
        sA[t] = __builtin_amdgcn_mfma_f32_16x16x32_bf16(kf1, qfb, sA[t], 0, 0, 0);
      }
      __builtin_amdgcn_s_setprio(0);
      if (ktg == wdiag) {  // this wave's diagonal tile: causal mask
        const int k0 = ktg * 64;
#pragma unroll
        for (int t = 0; t < 4; ++t)
#pragma unroll
          for (int r = 0; r < 4; ++r)
            if (k0 + t * 16 + quad * 4 + r > qq) sA[t][r] = -1e30f;
      }
      // fixed-max softmax: p = 2^(s-M) (M folded into acc init), packed in-register
      unsigned W[4][2];
#pragma unroll
      for (int t = 0; t < 4; ++t) {
        float e0 = __builtin_amdgcn_exp2f(sA[t][0]);
        float e1 = __builtin_amdgcn_exp2f(sA[t][1]);
        float e2 = __builtin_amdgcn_exp2f(sA[t][2]);
        float e3 = __builtin_amdgcn_exp2f(sA[t][3]);
        W[t][0] = cvtpk(e0, e1);
        W[t][1] = cvtpk(e2, e3);
      }
      plswap(W[0][0], W[1][0]);
      plswap(W[0][1], W[1][1]);
      plswap(W[2][0], W[3][0]);
      plswap(W[2][1], W[3][1]);
      u32x4 paw; paw[0] = W[0][0]; paw[1] = W[0][1]; paw[2] = W[1][0]; paw[3] = W[1][1];
      u32x4 pbw; pbw[0] = W[2][0]; pbw[1] = W[2][1]; pbw[2] = W[3][0]; pbw[3] = W[3][1];
      const bf16x8 pa = __builtin_bit_cast(bf16x8, paw);
      const bf16x8 pb = __builtin_bit_cast(bf16x8, pbw);
      // O^T += V^T.P^T ; l += ones.P^T
      __builtin_amdgcn_s_setprio(1);
      lacc = __builtin_amdgcn_mfma_f32_16x16x32_bf16(ones, pa, lacc, 0, 0, 0);
      lacc = __builtin_amdgcn_mfma_f32_16x16x32_bf16(ones, pb, lacc, 0, 0, 0);
#pragma unroll
      for (int t = 0; t < 4; ++t) {
        const bf16x8 vf0 = *(const bf16x8*)&VTs[buf][(t * 16 + l15) * LDP + quad * 8];
        const bf16x8 vf1 = *(const bf16x8*)&VTs[buf][(t * 16 + l15) * LDP + 32 + quad * 8];
        o[t] = __builtin_amdgcn_mfma_f32_16x16x32_bf16(vf0, pa, o[t], 0, 0, 0);
        o[t] = __builtin_amdgcn_mfma_f32_16x16x32_bf16(vf1, pb, o[t], 0, 0, 0);
      }
      __builtin_amdgcn_s_setprio(0);
    }
    // stage tile j+1 into the other buffer; prefetch tile j+2
    if (j + 1 < niter) {
      STORET(buf ^ 1);
      if (j + 2 < niter) LOADT(start + j + 2);
    }
    __syncthreads();
  }

  const float lv = lacc[0];   // every lane holds the full 64-wide sum for its q
  if (qt2 <= 7) {
    // single chunk: normalize + write Yb directly
    const float inv = 1.f / lv;
    const int bidx = bh / 12, hidx = bh % 12;
    u16* y = Yb + ((size_t)bidx * T + qq) * 768 + hidx * 64;
#pragma unroll
    for (int t = 0; t < 4; ++t) {
      u32x2 pk;
      pk[0] = cvtpk(o[t][0] * inv, o[t][1] * inv);
      pk[1] = cvtpk(o[t][2] * inv, o[t][3] * inv);
      *(u32x2*)(y + t * 16 + quad * 4) = pk;
    }
  } else {
    // write unnormalized partials: Opart[pidx][q(128)][d(64)] fp32, lpart[pidx][q(128)]
    const size_t pidx = (size_t)bh * 24 + s;
    float* Op = Opart + pidx * 8192 + (size_t)(w * 16 + l15) * 64;
#pragma unroll
    for (int t = 0; t < 4; ++t) *(f32x4*)(Op + t * 16 + quad * 4) = o[t];
    if (quad == 0) lpart[pidx * 128 + w * 16 + l15] = lv;
  }
}

// ---------------- combine partials for qt2 >= 8 (nch = 2) ----------------
__global__ __launch_bounds__(256) void attn_combine_kernel(
    const float* __restrict__ Opart, const float* __restrict__ lpart, u16* __restrict__ Yb) {
  constexpr int T = 2048;
  const int qt2 = 8 + blockIdx.x;   // 8..15
  const int bh = blockIdx.y;
  const size_t base = (size_t)bh * 24 + 8 + (qt2 - 8) * 2;
  const int tid = threadIdx.x;
  const int q = tid >> 1, db = (tid & 1) * 32;   // 128 q rows x 2 d-halves
  f32x4 o[8] = {{0,0,0,0},{0,0,0,0},{0,0,0,0},{0,0,0,0},{0,0,0,0},{0,0,0,0},{0,0,0,0},{0,0,0,0}};
  float l = 0.f;
  for (int cc = 0; cc < 2; ++cc) {
    const float* Op = Opart + (base + cc) * 8192 + (size_t)q * 64 + db;
#pragma unroll
    for (int v = 0; v < 8; ++v) o[v] += *(const f32x4*)(Op + v * 4);
    l += lpart[(base + cc) * 128 + q];
  }
  const float inv = 1.f / l;
  const int bidx = bh / 12, hidx = bh % 12;
  u16* y = Yb + ((size_t)bidx * T + qt2 * 128 + q) * 768 + hidx * 64 + db;
#pragma unroll
  for (int g = 0; g < 2; ++g) {
    u32x4 pk;
    pk[0] = cvtpk(o[g * 4 + 0][0] * inv, o[g * 4 + 0][1] * inv);
    pk[1] = cvtpk(o[g * 4 + 0][2] * inv, o[g * 4 + 0][3] * inv);
    pk[2] = cvtpk(o[g * 4 + 1][0] * inv, o[g * 4 + 1][1] * inv);
    pk[3] = cvtpk(o[g * 4 + 1][2] * inv, o[g * 4 + 1][3] * inv);
    *(u32x4*)(y + g * 16) = pk;
    pk[0] = cvtpk(o[g * 4 + 2][0] * inv, o[g * 4 + 2][1] * inv);
    pk[1] = cvtpk(o[g * 4 + 2][2] * inv, o[g * 4 + 2][3] * inv);
    pk[2] = cvtpk(o[g * 4 + 3][0] * inv, o[g * 4 + 3][1] * inv);
    pk[3] = cvtpk(o[g * 4 + 3][2] * inv, o[g * 4 + 3][3] * inv);
    *(u32x4*)(y + g * 16 + 8) = pk;
  }
}

// ---------------- fallback attention (used if ws too small) ----------------
__global__ __launch_bounds__(256) void attn_kernel(
    const u16* __restrict__ Qg, const u16* __restrict__ Kg, const u16* __restrict__ Vtg,
    u16* __restrict__ Yb) {
  constexpr int T = 2048, D = 64;
  constexpr int LDP = 72;
  constexpr float MBOUND = 20.0f;
  __shared__ u16 Ks[64 * LDP];
  __shared__ u16 VTs[64 * LDP];
  __shared__ u16 Ps[4 * 32 * LDP];
  const int qb = 15 - blockIdx.x;
  const int bh = blockIdx.y;
  const int Q0 = qb * 128;
  const int bidx = bh / 12, hidx = bh % 12;
  const int tid = threadIdx.x;
  const int w = tid >> 6, lane = tid & 63;
  const int l15 = lane & 15, quad = lane >> 4;
  const int srow = tid >> 2, scol = (tid & 3) * 16;
  const u16* Kp = Kg + (size_t)bh * T * D;
  const u16* VTp = Vtg + (size_t)bh * D * T;
  u16* pw0 = &Ps[(w * 32) * LDP];
  u16* pw1 = &Ps[(w * 32 + 16) * LDP];
  const u16* qrow0 = Qg + ((size_t)bh * T + Q0 + w * 16 + l15) * D;
  const bf16x8 qf0a = *(const bf16x8*)(qrow0 + quad * 8);
  const bf16x8 qf0b = *(const bf16x8*)(qrow0 + 32 + quad * 8);
  const bf16x8 qf1a = *(const bf16x8*)(qrow0 + (size_t)64 * D + quad * 8);
  const bf16x8 qf1b = *(const bf16x8*)(qrow0 + (size_t)64 * D + 32 + quad * 8);
  const int qq0 = Q0 + w * 16 + l15, qq1 = qq0 + 64;
  f32x4 o0[4] = {{0,0,0,0},{0,0,0,0},{0,0,0,0},{0,0,0,0}};
  f32x4 o1[4] = {{0,0,0,0},{0,0,0,0},{0,0,0,0},{0,0,0,0}};
  float l0v = 0.f, l1v = 0.f;
  const int nkt = 2 * qb + 2;
  u32x4 kA = *(const u32x4*)(Kp + (size_t)srow * D + scol);
  u32x4 kB = *(const u32x4*)(Kp + (size_t)srow * D + scol + 8);
  u32x4 vA = *(const u32x4*)(VTp + (size_t)srow * T + scol);
  u32x4 vB = *(const u32x4*)(VTp + (size_t)srow * T + scol + 8);
  for (int kt = 0; kt < nkt; ++kt) {
    __syncthreads();
    *(u32x4*)&Ks[srow * LDP + scol] = kA;
    *(u32x4*)&Ks[srow * LDP + scol + 8] = kB;
    *(u32x4*)&VTs[srow * LDP + scol] = vA;
    *(u32x4*)&VTs[srow * LDP + scol + 8] = vB;
    __syncthreads();
    if (kt + 1 < nkt) {
      const int k1 = (kt + 1) * 64;
      kA = *(const u32x4*)(Kp + (size_t)(k1 + srow) * D + scol);
      kB = *(const u32x4*)(Kp + (size_t)(k1 + srow) * D + scol + 8);
      vA = *(const u32x4*)(VTp + (size_t)srow * T + k1 + scol);
      vB = *(const u32x4*)(VTp + (size_t)srow * T + k1 + scol + 8);
    }
    const int k0 = kt * 64;
    const bool g0a = (kt <= 2 * qb);
    f32x4 s0[4] = {{0,0,0,0},{0,0,0,0},{0,0,0,0},{0,0,0,0}};
    f32x4 s1[4] = {{0,0,0,0},{0,0,0,0},{0,0,0,0},{0,0,0,0}};
#pragma unroll
    for (int t = 0; t < 4; ++t) {
      const bf16x8 kf0 = *(const bf16x8*)&Ks[(t * 16 + l15) * LDP + quad * 8];
      const bf16x8 kf1 = *(const bf16x8*)&Ks[(t * 16 + l15) * LDP + 32 + quad * 8];
      s0[t] = __builtin_amdgcn_mfma_f32_16x16x32_bf16(kf0, qf0a, s0[t], 0, 0, 0);
      s0[t] = __builtin_amdgcn_mfma_f32_16x16x32_bf16(kf1, qf0b, s0[t], 0, 0, 0);
      s1[t] = __builtin_amdgcn_mfma_f32_16x16x32_bf16(kf0, qf1a, s1[t], 0, 0, 0);
      s1[t] = __builtin_amdgcn_mfma_f32_16x16x32_bf16(kf1, qf1b, s1[t], 0, 0, 0);
    }
    if (g0a) {
      if (kt == 2 * qb) {
#pragma unroll
        for (int t = 0; t < 4; ++t)
#pragma unroll
          for (int r = 0; r < 4; ++r)
            if (k0 + t * 16 + quad * 4 + r > qq0) s0[t][r] = -1e30f;
      }
#pragma unroll
      for (int t = 0; t < 4; ++t) {
        float e0 = __builtin_amdgcn_exp2f(s0[t][0] - MBOUND);
        float e1 = __builtin_amdgcn_exp2f(s0[t][1] - MBOUND);
        float e2 = __builtin_amdgcn_exp2f(s0[t][2] - MBOUND);
        float e3 = __builtin_amdgcn_exp2f(s0[t][3] - MBOUND);
        l0v += (e0 + e1) + (e2 + e3);
        u32x2 pk;
        pk[0] = cvtpk(e0, e1);
        pk[1] = cvtpk(e2, e3);
        *(u32x2*)&pw0[l15 * LDP + t * 16 + quad * 4] = pk;
      }
    }
    {
      if (kt == 2 * qb + 1) {
#pragma unroll
        for (int t = 0; t < 4; ++t)
#pragma unroll
          for (int r = 0; r < 4; ++r)
            if (k0 + t * 16 + quad * 4 + r > qq1) s1[t][r] = -1e30f;
      }
#pragma unroll
      for (int t = 0; t < 4; ++t) {
        float e0 = __builtin_amdgcn_exp2f(s1[t][0] - MBOUND);
        float e1 = __builtin_amdgcn_exp2f(s1[t][1] - MBOUND);
        float e2 = __builtin_amdgcn_exp2f(s1[t][2] - MBOUND);
        float e3 = __builtin_amdgcn_exp2f(s1[t][3] - MBOUND);
        l1v += (e0 + e1) + (e2 + e3);
        u32x2 pk;
        pk[0] = cvtpk(e0, e1);
        pk[1] = cvtpk(e2, e3);
        *(u32x2*)&pw1[l15 * LDP + t * 16 + quad * 4] = pk;
      }
    }
    const bf16x8 p0a = *(const bf16x8*)&pw0[l15 * LDP + quad * 8];
    const bf16x8 p0b = *(const bf16x8*)&pw0[l15 * LDP + 32 + quad * 8];
    const bf16x8 p1a = *(const bf16x8*)&pw1[l15 * LDP + quad * 8];
    const bf16x8 p1b = *(const bf16x8*)&pw1[l15 * LDP + 32 + quad * 8];
#pragma unroll
    for (int t = 0; t < 4; ++t) {
      const bf16x8 vf0 = *(const bf16x8*)&VTs[(t * 16 + l15) * LDP + quad * 8];
      const bf16x8 vf1 = *(const bf16x8*)&VTs[(t * 16 + l15) * LDP + 32 + quad * 8];
      if (g0a) {
        o0[t] = __builtin_amdgcn_mfma_f32_16x16x32_bf16(vf0, p0a, o0[t], 0, 0, 0);
        o0[t] = __builtin_amdgcn_mfma_f32_16x16x32_bf16(vf1, p0b, o0[t], 0, 0, 0);
      }
      o1[t] = __builtin_amdgcn_mfma_f32_16x16x32_bf16(vf0, p1a, o1[t], 0, 0, 0);
      o1[t] = __builtin_amdgcn_mfma_f32_16x16x32_bf16(vf1, p1b, o1[t], 0, 0, 0);
    }
  }
  l0v += __shfl_xor(l0v, 16); l0v += __shfl_xor(l0v, 32);
  l1v += __shfl_xor(l1v, 16); l1v += __shfl_xor(l1v, 32);
  const float inv0 = 1.f / l0v, inv1 = 1.f / l1v;
  u16* y0 = Yb + ((size_t)bidx * T + qq0) * 768 + hidx * 64;
  u16* y1 = Yb + ((size_t)bidx * T + qq1) * 768 + hidx * 64;
#pragma unroll
  for (int t = 0; t < 4; ++t) {
    u32x2 pk0, pk1;
    pk0[0] = cvtpk(o0[t][0] * inv0, o0[t][1] * inv0);
    pk0[1] = cvtpk(o0[t][2] * inv0, o0[t][3] * inv0);
    pk1[0] = cvtpk(o1[t][0] * inv1, o1[t][1] * inv1);
    pk1[1] = cvtpk(o1[t][2] * inv1, o1[t][3] * inv1);
    *(u32x2*)(y0 + t * 16 + quad * 4) = pk0;
    *(u32x2*)(y1 + t * 16 + quad * 4) = pk1;
  }
}

extern "C" void kernel_launch(void* const* d_in, const int* in_sizes, int n_in,
                              void* d_out, int out_size, void* d_ws, size_t ws_size,
                              hipStream_t stream) {
  const float* x = (const float*)d_in[0];
  const float* W_qkv = (const float*)d_in[1];
  const float* b_qkv = (const float*)d_in[2];
  const float* W_proj = (const float*)d_in[3];
  const float* b_proj = (const float*)d_in[4];
  float* out = (float*)d_out;

  constexpr size_t MC = (size_t)8192 * 768;
  u16* xb = (u16*)d_ws;
  u16* Qb = xb + MC;
  u16* Kb = Qb + MC;
  u16* Vt = Kb + MC;   // transposed V: [bh][d][t]
  u16* Yb = Vt + MC;
  u16* WqkvT = Yb + MC;
  u16* WprojT = WqkvT + (size_t)2304 * 768;
  // split-K partials (after the bf16 region). Region sized for the old 1920-slot
  // layout (NEED unchanged); the 24-slot scheme uses 1152 slots = a subset.
  constexpr size_t BASE_U16 = 5 * MC + (size_t)2304 * 768 + (size_t)768 * 768;  // 33,816,576
  float* Opart = (float*)((u16*)d_ws + BASE_U16);
  float* lpart = Opart + (size_t)1920 * 8192;
  constexpr size_t NEED = BASE_U16 * 2 + ((size_t)1920 * 8192 + (size_t)1920 * 128) * 4;
  const bool use_split = (ws_size >= NEED);

  cast_x_kernel<<<6291456 / (4 * 256), 256, 0, stream>>>(x, xb, 6291456 / 4);
  transpose_cast_kernel<<<dim3(2304 / 32, 768 / 32), 256, 0, stream>>>(W_qkv, WqkvT, 768, 2304);
  transpose_cast_kernel<<<dim3(768 / 32, 768 / 32), 256, 0, stream>>>(W_proj, WprojT, 768, 768);
  gemm_qkv_kernel<<<dim3(18, 64), 256, 0, stream>>>(xb, WqkvT, b_qkv, Qb, Kb, Vt);
  if (use_split) {
    attn_split_kernel<<<dim3(24, 48), 512, 0, stream>>>(Qb, Kb, Vt, Yb, Opart, lpart);
    attn_combine_kernel<<<dim3(8, 48), 256, 0, stream>>>(Opart, lpart, Yb);
  } else {
    attn_kernel<<<dim3(16, 48), 256, 0, stream>>>(Qb, Kb, Vt, Yb);
  }
  gemm_proj_kernel<<<dim3(6, 128), 256, 0, stream>>>(Yb, WprojT, b_proj, out);
}

// Round 13
// 214.777 us; speedup vs baseline: 1.1646x; 1.0116x over previous
//
#include <hip/hip_runtime.h>
#include <hip/hip_bf16.h>

typedef __bf16 bf16x8 __attribute__((ext_vector_type(8)));
typedef float f32x4 __attribute__((ext_vector_type(4)));
typedef unsigned int u32x4 __attribute__((ext_vector_type(4)));
typedef unsigned int u32x2 __attribute__((ext_vector_type(2)));
typedef int i32x2 __attribute__((ext_vector_type(2)));
typedef unsigned short u16;
typedef unsigned long long u64;

#define WAITVM(n) asm volatile("s_waitcnt vmcnt(" #n ")" ::: "memory")
#define SBAR() asm volatile("s_barrier" ::: "memory")

__device__ __forceinline__ u16 f2bf(float f) {
  unsigned u = __builtin_bit_cast(unsigned, f);
  u += 0x7FFFu + ((u >> 16) & 1u);   // RNE
  return (u16)(u >> 16);
}
// HW packed convert: 2 fp32 -> 2 bf16 (v_cvt_pk_bf16_f32, RNE)
__device__ __forceinline__ unsigned cvtpk(float a, float b) {
  float2 f; f.x = a; f.y = b;
  __hip_bfloat162 h = __float22bfloat162_rn(f);
  unsigned u;
  __builtin_memcpy(&u, &h, 4);
  return u;
}

// v_permlane32_swap_b32: after call, a = [a.lo ; b.lo], b = [a.hi ; b.hi]
__device__ __forceinline__ void plswap(unsigned &a, unsigned &b) {
  i32x2 r = __builtin_amdgcn_permlane32_swap((int)a, (int)b, false, false);
  a = (unsigned)r[0];
  b = (unsigned)r[1];
}

// async global->LDS direct copy, 16B per lane. LDS dest = wave-uniform base + lane*16.
__device__ __forceinline__ void gll16(const u16* g, u16* l) {
  __builtin_amdgcn_global_load_lds(
      (const __attribute__((address_space(1))) unsigned int*)g,
      (__attribute__((address_space(3))) unsigned int*)l, 16, 0, 0);
}

// ---------------- cast x (fp32 -> bf16), vectorized ----------------
__global__ void cast_x_kernel(const float* __restrict__ in, u16* __restrict__ out, int n4) {
  int i = blockIdx.x * blockDim.x + threadIdx.x;
  if (i >= n4) return;
  f32x4 v = *(const f32x4*)(in + (size_t)i * 4);
  u32x2 pk;
  pk[0] = cvtpk(v[0], v[1]);
  pk[1] = cvtpk(v[2], v[3]);
  *(u32x2*)(out + (size_t)i * 4) = pk;
}

// ------- fused transpose + cast for BOTH weights: W[K][N] fp32 -> WT[N][K] bf16 -------
// blockIdx.x < 72: W_qkv (768x2304); else W_proj (768x768). Saves one launch.
__global__ void transpose_cast2_kernel(const float* __restrict__ W1, u16* __restrict__ WT1,
                                       const float* __restrict__ W2, u16* __restrict__ WT2) {
  __shared__ float tile[32][33];
  constexpr int K = 768;
  int bx = blockIdx.x;
  const float* W; u16* WT; int N;
  if (bx < 72) { W = W1; WT = WT1; N = 2304; }
  else { W = W2; WT = WT2; N = 768; bx -= 72; }
  int c0 = bx * 32, r0 = blockIdx.y * 32;
  int tx = threadIdx.x & 31, tg = threadIdx.x >> 5;
#pragma unroll
  for (int i = 0; i < 4; ++i) {
    int r = tg + i * 8;
    tile[r][tx] = W[(size_t)(r0 + r) * N + c0 + tx];
  }
  __syncthreads();
#pragma unroll
  for (int i = 0; i < 4; ++i) {
    int r = tg + i * 8;
    WT[(size_t)(c0 + r) * K + r0 + tx] = f2bf(tile[tx][r]);
  }
}

// ---------------- QKV GEMM: [8192x768] x [768x2304] ----------------
// 128x128 tile, 256 thr, BK=32, 24 steps, 3-STAGE LDS pipeline (depth 2): tile s's
// loads issued two compute phases before use; counted WAITVM(8) gives ~400-500cy cover.
// (R10 verified.) No XCD swizzle (R6: L3-fit).
// Q pre-scaled by 0.125*log2(e). V written TRANSPOSED: Vt[bh][d][t].
__global__ __launch_bounds__(256, 3) void gemm_qkv_kernel(
    const u16* __restrict__ A, const u16* __restrict__ BT, const float* __restrict__ bias,
    u16* __restrict__ Qb, u16* __restrict__ Kb, u16* __restrict__ Vt) {
  constexpr int K = 768;
  constexpr int NS = K / 32;  // 24 pipeline steps (multiple of 3)
  __shared__ u16 Asm[3][128 * 32];
  __shared__ u16 Bsm[3][128 * 32];
  const int tid = threadIdx.x;
  const int w = tid >> 6, lane = tid & 63;
  const int l15 = lane & 15, quad = lane >> 4;
  const int srow = tid >> 2, scol = (tid & 3) * 8;
  const int m0 = blockIdx.y * 128, n0 = blockIdx.x * 128;
  const u16* Ag = A + (size_t)(m0 + srow) * K + scol;
  const u16* Bg = BT + (size_t)(n0 + srow) * K + scol;
  const int mw = (w >> 1) * 64, nw = (w & 1) * 64;
  f32x4 acc[4][4];
#pragma unroll
  for (int i = 0; i < 4; ++i)
#pragma unroll
    for (int j = 0; j < 4; ++j) acc[i][j] = {0.f, 0.f, 0.f, 0.f};

  auto STAGE = [&](int buf, int ks) {
    const u16* a = Ag + ks * 32;
    const u16* b = Bg + ks * 32;
#pragma unroll
    for (int rb = 0; rb < 2; ++rb) {
      gll16(a + (size_t)rb * 64 * K, &Asm[buf][(rb * 64 + w * 16) * 32]);
      gll16(b + (size_t)rb * 64 * K, &Bsm[buf][(rb * 64 + w * 16) * 32]);
    }
  };
  auto COMPUTE = [&](int buf) {
    bf16x8 af[4], bfj[4];
#pragma unroll
    for (int i = 0; i < 4; ++i) af[i] = *(const bf16x8*)&Asm[buf][(mw + i * 16 + l15) * 32 + quad * 8];
#pragma unroll
    for (int j = 0; j < 4; ++j) bfj[j] = *(const bf16x8*)&Bsm[buf][(nw + j * 16 + l15) * 32 + quad * 8];
#pragma unroll
    for (int i = 0; i < 4; ++i)
#pragma unroll
      for (int j = 0; j < 4; ++j)
        acc[i][j] = __builtin_amdgcn_mfma_f32_16x16x32_bf16(af[i], bfj[j], acc[i][j], 0, 0, 0);
  };

  STAGE(0, 0);
  STAGE(1, 1);
  for (int s = 0; s < NS - 3; s += 3) {
    STAGE((s + 2) % 3, s + 2); WAITVM(8); SBAR(); COMPUTE(s % 3); SBAR();
    STAGE((s + 3) % 3, s + 3); WAITVM(8); SBAR(); COMPUTE((s + 1) % 3); SBAR();
    STAGE((s + 4) % 3, s + 4); WAITVM(8); SBAR(); COMPUTE((s + 2) % 3); SBAR();
  }
  STAGE((NS - 1) % 3, NS - 1); WAITVM(8); SBAR(); COMPUTE((NS - 3) % 3); SBAR();
  WAITVM(4); SBAR(); COMPUTE((NS - 2) % 3); SBAR();
  WAITVM(0); SBAR(); COMPUTE((NS - 1) % 3);

  const int sec = blockIdx.x / 6;           // 0:Q 1:K 2:V (uniform per block; 768%128==0)
  const int nbase = n0 - sec * 768;
#pragma unroll
  for (int j = 0; j < 4; ++j) {
    const int nloc = nbase + nw + j * 16 + l15;
    const float bv = bias[sec * 768 + nloc];
    const int h = nloc >> 6, d = nloc & 63;
#pragma unroll
    for (int i = 0; i < 4; ++i) {
      const int m = m0 + mw + i * 16 + quad * 4;
      const int bb = m >> 11, trow = m & 2047;
      if (sec == 2) {
        u32x2 pk;
        pk[0] = cvtpk(acc[i][j][0] + bv, acc[i][j][1] + bv);
        pk[1] = cvtpk(acc[i][j][2] + bv, acc[i][j][3] + bv);
        *(u32x2*)(Vt + (size_t)((bb * 12 + h) * 64 + d) * 2048 + trow) = pk;
      } else {
        u16* dst = (sec == 0) ? Qb : Kb;
        const float scl = (sec == 0) ? 0.125f * 1.44269504f : 1.0f;
#pragma unroll
        for (int r = 0; r < 4; ++r)
          dst[(size_t)((bb * 12 + h) * 2048 + trow + r) * 64 + d] = f2bf((acc[i][j][r] + bv) * scl);
      }
    }
  }
}

// ---------------- proj GEMM: 64x128 tiles, 3-stage depth-2 pipeline, fp32 out + bias ----------------
// R11-verified counted-vmcnt schedule: WAITVM(6)/(3)/(0). XCD-swizzled (grid 768 = 8*96).
__global__ __launch_bounds__(256, 4) void gemm_proj_kernel(
    const u16* __restrict__ A, const u16* __restrict__ BT, const float* __restrict__ bias,
    float* __restrict__ out) {
  constexpr int K = 768;
  constexpr int NS = K / 32;
  __shared__ u16 Asm[3][64 * 32];
  __shared__ u16 Bsm[3][128 * 32];
  const int lin = blockIdx.y * 6 + blockIdx.x;
  const int swz = (lin & 7) * 96 + (lin >> 3);
  const int tid = threadIdx.x;
  const int w = tid >> 6, lane = tid & 63;
  const int l15 = lane & 15, quad = lane >> 4;
  const int srow = tid >> 2, scol = (tid & 3) * 8;
  const int m0 = (swz / 6) * 64, n0 = (swz % 6) * 128;
  const u16* Ag = A + (size_t)(m0 + srow) * K + scol;
  const u16* Bg = BT + (size_t)(n0 + srow) * K + scol;
  const int mw = (w >> 1) * 32, nw = (w & 1) * 64;
  f32x4 acc[2][4];
#pragma unroll
  for (int i = 0; i < 2; ++i)
#pragma unroll
    for (int j = 0; j < 4; ++j) acc[i][j] = {0.f, 0.f, 0.f, 0.f};

  auto STAGE = [&](int buf, int ks) {
    const u16* a = Ag + ks * 32;
    const u16* b = Bg + ks * 32;
    gll16(a, &Asm[buf][(w * 16) * 32]);
#pragma unroll
    for (int rb = 0; rb < 2; ++rb)
      gll16(b + (size_t)rb * 64 * K, &Bsm[buf][(rb * 64 + w * 16) * 32]);
  };
  auto COMPUTE = [&](int buf) {
    bf16x8 af[2], bfj[4];
#pragma unroll
    for (int i = 0; i < 2; ++i) af[i] = *(const bf16x8*)&Asm[buf][(mw + i * 16 + l15) * 32 + quad * 8];
#pragma unroll
    for (int j = 0; j < 4; ++j) bfj[j] = *(const bf16x8*)&Bsm[buf][(nw + j * 16 + l15) * 32 + quad * 8];
#pragma unroll
    for (int i = 0; i < 2; ++i)
#pragma unroll
      for (int j = 0; j < 4; ++j)
        acc[i][j] = __builtin_amdgcn_mfma_f32_16x16x32_bf16(af[i], bfj[j], acc[i][j], 0, 0, 0);
  };

  STAGE(0, 0);
  STAGE(1, 1);
  for (int s = 0; s < NS - 3; s += 3) {
    STAGE((s + 2) % 3, s + 2); WAITVM(6); SBAR(); COMPUTE(s % 3); SBAR();
    STAGE((s + 3) % 3, s + 3); WAITVM(6); SBAR(); COMPUTE((s + 1) % 3); SBAR();
    STAGE((s + 4) % 3, s + 4); WAITVM(6); SBAR(); COMPUTE((s + 2) % 3); SBAR();
  }
  STAGE((NS - 1) % 3, NS - 1); WAITVM(6); SBAR(); COMPUTE((NS - 3) % 3); SBAR();
  WAITVM(3); SBAR(); COMPUTE((NS - 2) % 3); SBAR();
  WAITVM(0); SBAR(); COMPUTE((NS - 1) % 3);

#pragma unroll
  for (int j = 0; j < 4; ++j) {
    const int n = n0 + nw + j * 16 + l15;
    const float bv = bias[n];
#pragma unroll
    for (int i = 0; i < 2; ++i) {
      const int m = m0 + mw + i * 16 + quad * 4;
#pragma unroll
      for (int r = 0; r < 4; ++r) out[(size_t)(m + r) * 768 + n] = acc[i][j][r] + bv;
    }
  }
}

// ---------------- split-K causal flash attention, 8 waves / 128 q-rows per block ----------------
// 30-slot decode: qt2 0..5 single chunk (<=12 iters); qt2 6..11 two halves (7..12);
// qt2 12..15 three thirds (8..11). Max chunk 12 iters (was 16) -> shorter tail; partial
// slots 24/bh (writes ~37.7MB). Grid 30x48 = 1440 = 8*180, XCD-swizzled, long-first.
// 8 waves (512 thr); per-wave math unchanged (T12 in-reg P, ones-MFMA l-sum, wdiag).
__global__ __launch_bounds__(512) void attn_split_kernel(
    const u16* __restrict__ Qg, const u16* __restrict__ Kg, const u16* __restrict__ Vtg,
    u16* __restrict__ Yb, float* __restrict__ Opart, float* __restrict__ lpart) {
  constexpr int T = 2048, D = 64;
  constexpr int LDP = 72;
  constexpr float MBOUND = 20.0f;
  __shared__ u16 Ks[2][64 * LDP];   // K tile  [k][d]
  __shared__ u16 VTs[2][64 * LDP];  // V^T tile [d][sigma(k)]
  const int lin = blockIdx.y * 30 + blockIdx.x;
  const int swzb = (lin & 7) * 180 + (lin >> 3);
  const int s = 29 - (swzb % 30);   // long chunks first (within each bh)
  const int bh = swzb / 30;
  int qt2, c, mode;                 // mode: 1/2/3 chunks
  if (s < 6) { qt2 = s; c = 0; mode = 1; }
  else if (s < 18) { int u = s - 6; qt2 = 6 + (u >> 1); c = u & 1; mode = 2; }
  else { int u = s - 18; qt2 = 12 + u / 3; c = u % 3; mode = 3; }
  const int nkt = 2 * qt2 + 2;
  int start, niter;
  if (mode == 1) { start = 0; niter = nkt; }
  else if (mode == 2) { const int half = nkt >> 1; start = c * half; niter = half; }
  else {
    const int b = nkt / 3, r = nkt - 3 * b;
    const int e0 = b + (r > 0), e1 = b + (r > 1);
    start = (c == 0) ? 0 : (c == 1) ? e0 : e0 + e1;
    niter = (c == 0) ? e0 : (c == 1) ? e1 : b;
  }
  const int tid = threadIdx.x;
  const int w = tid >> 6, lane = tid & 63;
  const int l15 = lane & 15, quad = lane >> 4;
  // staging: 512 threads, one u32x4 (16B) each for K and V
  const int srow = tid >> 3;                // 0..63
  const int scol = (tid & 7) * 8;           // u16 units
  const int so0 = scol - 4 * (tid & 1);     // sigma dest for lo half
  const int so1 = scol + 8 - 4 * (tid & 1); // sigma dest for hi half
  const u16* Kp = Kg + (size_t)bh * T * D;
  const u16* VTp = Vtg + (size_t)bh * D * T;

  // per-wave role: rows qq; diagonal tile index for this wave
  const int wdiag = 2 * qt2 + (w >> 2);
  const int qq = qt2 * 128 + w * 16 + l15;
  const u16* qrow = Qg + ((size_t)bh * T + qq) * D;
  const bf16x8 qfa = *(const bf16x8*)(qrow + quad * 8);
  const bf16x8 qfb = *(const bf16x8*)(qrow + 32 + quad * 8);

  // all-ones bf16 A-operand for the l-sum MFMA
  u32x4 onesw; onesw[0] = 0x3F803F80u; onesw[1] = 0x3F803F80u; onesw[2] = 0x3F803F80u; onesw[3] = 0x3F803F80u;
  const bf16x8 ones = __builtin_bit_cast(bf16x8, onesw);

  f32x4 o[4] = {{0,0,0,0},{0,0,0,0},{0,0,0,0},{0,0,0,0}};  // O^T: row=d, col=q=l15
  f32x4 lacc = {0.f, 0.f, 0.f, 0.f};                       // l via ones-MFMA

  u32x4 kA, vA;
  auto LOADT = [&](int kt) {
    const int k1 = kt * 64;
    kA = *(const u32x4*)(Kp + (size_t)(k1 + srow) * D + scol);
    vA = *(const u32x4*)(VTp + (size_t)srow * T + k1 + scol);
  };
  auto STORET = [&](int buf) {
    *(u32x4*)&Ks[buf][srow * LDP + scol] = kA;
    u32x2 vlo; vlo[0] = vA[0]; vlo[1] = vA[1];
    u32x2 vhi; vhi[0] = vA[2]; vhi[1] = vA[3];
    *(u32x2*)&VTs[buf][srow * LDP + so0] = vlo;
    *(u32x2*)&VTs[buf][srow * LDP + so1] = vhi;
  };

  // prologue: first tile -> buf0; prefetch next
  LOADT(start);
  STORET(0);
  if (niter > 1) LOADT(start + 1);
  __syncthreads();

  for (int j = 0; j < niter; ++j) {
    const int buf = j & 1;
    const int ktg = start + j;
    if (ktg <= wdiag) {
      // S^T = K.Q^T : C-layout row = k_local = 16t+quad*4+r, col = q = l15
      f32x4 sA[4];
#pragma unroll
      for (int t = 0; t < 4; ++t) sA[t] = {-MBOUND, -MBOUND, -MBOUND, -MBOUND};
      __builtin_amdgcn_s_setprio(1);
#pragma unroll
      for (int t = 0; t < 4; ++t) {
        const bf16x8 kf0 = *(const bf16x8*)&Ks[buf][(t * 16 + l15) * LDP + quad * 8];
        const bf16x8 kf1 = *(const bf16x8*)&Ks[buf][(t * 16 + l15) * LDP + 32 + quad * 8];
        sA[t] = __builtin_amdgcn_mfma_f32_16x16x32_bf16(kf0, qfa, sA[t], 0, 0, 0);
        sA[t] = __builtin_amdgcn_mfma_f32_16x16x32_bf16(kf1, qfb, sA[t], 0, 0, 0);
      }
      __builtin_amdgcn_s_setprio(0);
      if (ktg == wdiag) {  // this wave's diagonal tile: causal mask
        const int k0 = ktg * 64;
#pragma unroll
        for (int t = 0; t < 4; ++t)
#pragma unroll
          for (int r = 0; r < 4; ++r)
            if (k0 + t * 16 + quad * 4 + r > qq) sA[t][r] = -1e30f;
      }
      // fixed-max softmax: p = 2^(s-M) (M folded into acc init), packed in-register
      unsigned W[4][2];
#pragma unroll
      for (int t = 0; t < 4; ++t) {
        float e0 = __builtin_amdgcn_exp2f(sA[t][0]);
        float e1 = __builtin_amdgcn_exp2f(sA[t][1]);
        float e2 = __builtin_amdgcn_exp2f(sA[t][2]);
        float e3 = __builtin_amdgcn_exp2f(sA[t][3]);
        W[t][0] = cvtpk(e0, e1);
        W[t][1] = cvtpk(e2, e3);
      }
      plswap(W[0][0], W[1][0]);
      plswap(W[0][1], W[1][1]);
      plswap(W[2][0], W[3][0]);
      plswap(W[2][1], W[3][1]);
      u32x4 paw; paw[0] = W[0][0]; paw[1] = W[0][1]; paw[2] = W[1][0]; paw[3] = W[1][1];
      u32x4 pbw; pbw[0] = W[2][0]; pbw[1] = W[2][1]; pbw[2] = W[3][0]; pbw[3] = W[3][1];
      const bf16x8 pa = __builtin_bit_cast(bf16x8, paw);
      const bf16x8 pb = __builtin_bit_cast(bf16x8, pbw);
      // O^T += V^T.P^T ; l += ones.P^T
      __builtin_amdgcn_s_setprio(1);
      lacc = __builtin_amdgcn_mfma_f32_16x16x32_bf16(ones, pa, lacc, 0, 0, 0);
      lacc = __builtin_amdgcn_mfma_f32_16x16x32_bf16(ones, pb, lacc, 0, 0, 0);
#pragma unroll
      for (int t = 0; t < 4; ++t) {
        const bf16x8 vf0 = *(const bf16x8*)&VTs[buf][(t * 16 + l15) * LDP + quad * 8];
        const bf16x8 vf1 = *(const bf16x8*)&VTs[buf][(t * 16 + l15) * LDP + 32 + quad * 8];
        o[t] = __builtin_amdgcn_mfma_f32_16x16x32_bf16(vf0, pa, o[t], 0, 0, 0);
        o[t] = __builtin_amdgcn_mfma_f32_16x16x32_bf16(vf1, pb, o[t], 0, 0, 0);
      }
      __builtin_amdgcn_s_setprio(0);
    }
    // stage tile j+1 into the other buffer; prefetch tile j+2
    if (j + 1 < niter) {
      STORET(buf ^ 1);
      if (j + 2 < niter) LOADT(start + j + 2);
    }
    __syncthreads();
  }

  const float lv = lacc[0];   // every lane holds the full 64-wide sum for its q
  if (mode == 1) {
    // single chunk: normalize + write Yb directly
    const float inv = 1.f / lv;
    const int bidx = bh / 12, hidx = bh % 12;
    u16* y = Yb + ((size_t)bidx * T + qq) * 768 + hidx * 64;
#pragma unroll
    for (int t = 0; t < 4; ++t) {
      u32x2 pk;
      pk[0] = cvtpk(o[t][0] * inv, o[t][1] * inv);
      pk[1] = cvtpk(o[t][2] * inv, o[t][3] * inv);
      *(u32x2*)(y + t * 16 + quad * 4) = pk;
    }
  } else {
    // write unnormalized partials: Opart[pidx][q(128)][d(64)] fp32, lpart[pidx][q(128)]
    const size_t pidx = (size_t)bh * 30 + s;
    float* Op = Opart + pidx * 8192 + (size_t)(w * 16 + l15) * 64;
#pragma unroll
    for (int t = 0; t < 4; ++t) *(f32x4*)(Op + t * 16 + quad * 4) = o[t];
    if (quad == 0) lpart[pidx * 128 + w * 16 + l15] = lv;
  }
}

// ---------------- combine partials for qt2 >= 6 (nch = 2 or 3) ----------------
__global__ __launch_bounds__(256) void attn_combine_kernel(
    const float* __restrict__ Opart, const float* __restrict__ lpart, u16* __restrict__ Yb) {
  constexpr int T = 2048;
  const int qt2 = 6 + blockIdx.x;   // 6..15
  const int bh = blockIdx.y;
  const int nch = (qt2 < 12) ? 2 : 3;
  const int off = (qt2 < 12) ? 6 + (qt2 - 6) * 2 : 18 + (qt2 - 12) * 3;
  const size_t base = (size_t)bh * 30 + off;
  const int tid = threadIdx.x;
  const int q = tid >> 1, db = (tid & 1) * 32;   // 128 q rows x 2 d-halves
  f32x4 o[8] = {{0,0,0,0},{0,0,0,0},{0,0,0,0},{0,0,0,0},{0,0,0,0},{0,0,0,0},{0,0,0,0},{0,0,0,0}};
  float l = 0.f;
  for (int cc = 0; cc < nch; ++cc) {
    const float* Op = Opart + (base + cc) * 8192 + (size_t)q * 64 + db;
#pragma unroll
    for (int v = 0; v < 8; ++v) o[v] += *(const f32x4*)(Op + v * 4);
    l += lpart[(base + cc) * 128 + q];
  }
  const float inv = 1.f / l;
  const int bidx = bh / 12, hidx = bh % 12;
  u16* y = Yb + ((size_t)bidx * T + qt2 * 128 + q) * 768 + hidx * 64 + db;
#pragma unroll
  for (int g = 0; g < 2; ++g) {
    u32x4 pk;
    pk[0] = cvtpk(o[g * 4 + 0][0] * inv, o[g * 4 + 0][1] * inv);
    pk[1] = cvtpk(o[g * 4 + 0][2] * inv, o[g * 4 + 0][3] * inv);
    pk[2] = cvtpk(o[g * 4 + 1][0] * inv, o[g * 4 + 1][1] * inv);
    pk[3] = cvtpk(o[g * 4 + 1][2] * inv, o[g * 4 + 1][3] * inv);
    *(u32x4*)(y + g * 16) = pk;
    pk[0] = cvtpk(o[g * 4 + 2][0] * inv, o[g * 4 + 2][1] * inv);
    pk[1] = cvtpk(o[g * 4 + 2][2] * inv, o[g * 4 + 2][3] * inv);
    pk[2] = cvtpk(o[g * 4 + 3][0] * inv, o[g * 4 + 3][1] * inv);
    pk[3] = cvtpk(o[g * 4 + 3][2] * inv, o[g * 4 + 3][3] * inv);
    *(u32x4*)(y + g * 16 + 8) = pk;
  }
}

// ---------------- fallback attention (used if ws too small) ----------------
__global__ __launch_bounds__(256) void attn_kernel(
    const u16* __restrict__ Qg, const u16* __restrict__ Kg, const u16* __restrict__ Vtg,
    u16* __restrict__ Yb) {
  constexpr int T = 2048, D = 64;
  constexpr int LDP = 72;
  constexpr float MBOUND = 20.0f;
  __shared__ u16 Ks[64 * LDP];
  __shared__ u16 VTs[64 * LDP];
  __shared__ u16 Ps[4 * 32 * LDP];
  const int qb = 15 - blockIdx.x;
  const int bh = blockIdx.y;
  const int Q0 = qb * 128;
  const int bidx = bh / 12, hidx = bh % 12;
  const int tid = threadIdx.x;
  const int w = tid >> 6, lane = tid & 63;
  const int l15 = lane & 15, quad = lane >> 4;
  const int srow = tid >> 2, scol = (tid & 3) * 16;
  const u16* Kp = Kg + (size_t)bh * T * D;
  const u16* VTp = Vtg + (size_t)bh * D * T;
  u16* pw0 = &Ps[(w * 32) * LDP];
  u16* pw1 = &Ps[(w * 32 + 16) * LDP];
  const u16* qrow0 = Qg + ((size_t)bh * T + Q0 + w * 16 + l15) * D;
  const bf16x8 qf0a = *(const bf16x8*)(qrow0 + quad * 8);
  const bf16x8 qf0b = *(const bf16x8*)(qrow0 + 32 + quad * 8);
  const bf16x8 qf1a = *(const bf16x8*)(qrow0 + (size_t)64 * D + quad * 8);
  const bf16x8 qf1b = *(const bf16x8*)(qrow0 + (size_t)64 * D + 32 + quad * 8);
  const int qq0 = Q0 + w * 16 + l15, qq1 = qq0 + 64;
  f32x4 o0[4] = {{0,0,0,0},{0,0,0,0},{0,0,0,0},{0,0,0,0}};
  f32x4 o1[4] = {{0,0,0,0},{0,0,0,0},{0,0,0,0},{0,0,0,0}};
  float l0v = 0.f, l1v = 0.f;
  const int nkt = 2 * qb + 2;
  u32x4 kA = *(const u32x4*)(Kp + (size_t)srow * D + scol);
  u32x4 kB = *(const u32x4*)(Kp + (size_t)srow * D + scol + 8);
  u32x4 vA = *(const u32x4*)(VTp + (size_t)srow * T + scol);
  u32x4 vB = *(const u32x4*)(VTp + (size_t)srow * T + scol + 8);
  for (int kt = 0; kt < nkt; ++kt) {
    __syncthreads();
    *(u32x4*)&Ks[srow * LDP + scol] = kA;
    *(u32x4*)&Ks[srow * LDP + scol + 8] = kB;
    *(u32x4*)&VTs[srow * LDP + scol] = vA;
    *(u32x4*)&VTs[srow * LDP + scol + 8] = vB;
    __syncthreads();
    if (kt + 1 < nkt) {
      const int k1 = (kt + 1) * 64;
      kA = *(const u32x4*)(Kp + (size_t)(k1 + srow) * D + scol);
      kB = *(const u32x4*)(Kp + (size_t)(k1 + srow) * D + scol + 8);
      vA = *(const u32x4*)(VTp + (size_t)srow * T + k1 + scol);
      vB = *(const u32x4*)(VTp + (size_t)srow * T + k1 + scol + 8);
    }
    const int k0 = kt * 64;
    const bool g0a = (kt <= 2 * qb);
    f32x4 s0[4] = {{0,0,0,0},{0,0,0,0},{0,0,0,0},{0,0,0,0}};
    f32x4 s1[4] = {{0,0,0,0},{0,0,0,0},{0,0,0,0},{0,0,0,0}};
#pragma unroll
    for (int t = 0; t < 4; ++t) {
      const bf16x8 kf0 = *(const bf16x8*)&Ks[(t * 16 + l15) * LDP + quad * 8];
      const bf16x8 kf1 = *(const bf16x8*)&Ks[(t * 16 + l15) * LDP + 32 + quad * 8];
      s0[t] = __builtin_amdgcn_mfma_f32_16x16x32_bf16(kf0, qf0a, s0[t], 0, 0, 0);
      s0[t] = __builtin_amdgcn_mfma_f32_16x16x32_bf16(kf1, qf0b, s0[t], 0, 0, 0);
      s1[t] = __builtin_amdgcn_mfma_f32_16x16x32_bf16(kf0, qf1a, s1[t], 0, 0, 0);
      s1[t] = __builtin_amdgcn_mfma_f32_16x16x32_bf16(kf1, qf1b, s1[t], 0, 0, 0);
    }
    if (g0a) {
      if (kt == 2 * qb) {
#pragma unroll
        for (int t = 0; t < 4; ++t)
#pragma unroll
          for (int r = 0; r < 4; ++r)
            if (k0 + t * 16 + quad * 4 + r > qq0) s0[t][r] = -1e30f;
      }
#pragma unroll
      for (int t = 0; t < 4; ++t) {
        float e0 = __builtin_amdgcn_exp2f(s0[t][0] - MBOUND);
        float e1 = __builtin_amdgcn_exp2f(s0[t][1] - MBOUND);
        float e2 = __builtin_amdgcn_exp2f(s0[t][2] - MBOUND);
        float e3 = __builtin_amdgcn_exp2f(s0[t][3] - MBOUND);
        l0v += (e0 + e1) + (e2 + e3);
        u32x2 pk;
        pk[0] = cvtpk(e0, e1);
        pk[1] = cvtpk(e2, e3);
        *(u32x2*)&pw0[l15 * LDP + t * 16 + quad * 4] = pk;
      }
    }
    {
      if (kt == 2 * qb + 1) {
#pragma unroll
        for (int t = 0; t < 4; ++t)
#pragma unroll
          for (int r = 0; r < 4; ++r)
            if (k0 + t * 16 + quad * 4 + r > qq1) s1[t][r] = -1e30f;
      }
#pragma unroll
      for (int t = 0; t < 4; ++t) {
        float e0 = __builtin_amdgcn_exp2f(s1[t][0] - MBOUND);
        float e1 = __builtin_amdgcn_exp2f(s1[t][1] - MBOUND);
        float e2 = __builtin_amdgcn_exp2f(s1[t][2] - MBOUND);
        float e3 = __builtin_amdgcn_exp2f(s1[t][3] - MBOUND);
        l1v += (e0 + e1) + (e2 + e3);
        u32x2 pk;
        pk[0] = cvtpk(e0, e1);
        pk[1] = cvtpk(e2, e3);
        *(u32x2*)&pw1[l15 * LDP + t * 16 + quad * 4] = pk;
      }
    }
    const bf16x8 p0a = *(const bf16x8*)&pw0[l15 * LDP + quad * 8];
    const bf16x8 p0b = *(const bf16x8*)&pw0[l15 * LDP + 32 + quad * 8];
    const bf16x8 p1a = *(const bf16x8*)&pw1[l15 * LDP + quad * 8];
    const bf16x8 p1b = *(const bf16x8*)&pw1[l15 * LDP + 32 + quad * 8];
#pragma unroll
    for (int t = 0; t < 4; ++t) {
      const bf16x8 vf0 = *(const bf16x8*)&VTs[(t * 16 + l15) * LDP + quad * 8];
      const bf16x8 vf1 = *(const bf16x8*)&VTs[(t * 16 + l15) * LDP + 32 + quad * 8];
      if (g0a) {
        o0[t] = __builtin_amdgcn_mfma_f32_16x16x32_bf16(vf0, p0a, o0[t], 0, 0, 0);
        o0[t] = __builtin_amdgcn_mfma_f32_16x16x32_bf16(vf1, p0b, o0[t], 0, 0, 0);
      }
      o1[t] = __builtin_amdgcn_mfma_f32_16x16x32_bf16(vf0, p1a, o1[t], 0, 0, 0);
      o1[t] = __builtin_amdgcn_mfma_f32_16x16x32_bf16(vf1, p1b, o1[t], 0, 0, 0);
    }
  }
  l0v += __shfl_xor(l0v, 16); l0v += __shfl_xor(l0v, 32);
  l1v += __shfl_xor(l1v, 16); l1v += __shfl_xor(l1v, 32);
  const float inv0 = 1.f / l0v, inv1 = 1.f / l1v;
  u16* y0 = Yb + ((size_t)bidx * T + qq0) * 768 + hidx * 64;
  u16* y1 = Yb + ((size_t)bidx * T + qq1) * 768 + hidx * 64;
#pragma unroll
  for (int t = 0; t < 4; ++t) {
    u32x2 pk0, pk1;
    pk0[0] = cvtpk(o0[t][0] * inv0, o0[t][1] * inv0);
    pk0[1] = cvtpk(o0[t][2] * inv0, o0[t][3] * inv0);
    pk1[0] = cvtpk(o1[t][0] * inv1, o1[t][1] * inv1);
    pk1[1] = cvtpk(o1[t][2] * inv1, o1[t][3] * inv1);
    *(u32x2*)(y0 + t * 16 + quad * 4) = pk0;
    *(u32x2*)(y1 + t * 16 + quad * 4) = pk1;
  }
}

extern "C" void kernel_launch(void* const* d_in, const int* in_sizes, int n_in,
                              void* d_out, int out_size, void* d_ws, size_t ws_size,
                              hipStream_t stream) {
  const float* x = (const float*)d_in[0];
  const float* W_qkv = (const float*)d_in[1];
  const float* b_qkv = (const float*)d_in[2];
  const float* W_proj = (const float*)d_in[3];
  const float* b_proj = (const float*)d_in[4];
  float* out = (float*)d_out;

  constexpr size_t MC = (size_t)8192 * 768;
  u16* xb = (u16*)d_ws;
  u16* Qb = xb + MC;
  u16* Kb = Qb + MC;
  u16* Vt = Kb + MC;   // transposed V: [bh][d][t]
  u16* Yb = Vt + MC;
  u16* WqkvT = Yb + MC;
  u16* WprojT = WqkvT + (size_t)2304 * 768;
  // split-K partials (after the bf16 region). Region sized for the old 1920-slot
  // layout (NEED unchanged); the 30-slot scheme uses 1440 slots = a subset.
  constexpr size_t BASE_U16 = 5 * MC + (size_t)2304 * 768 + (size_t)768 * 768;  // 33,816,576
  float* Opart = (float*)((u16*)d_ws + BASE_U16);
  float* lpart = Opart + (size_t)1920 * 8192;
  constexpr size_t NEED = BASE_U16 * 2 + ((size_t)1920 * 8192 + (size_t)1920 * 128) * 4;
  const bool use_split = (ws_size >= NEED);

  cast_x_kernel<<<6291456 / (4 * 256), 256, 0, stream>>>(x, xb, 6291456 / 4);
  transpose_cast2_kernel<<<dim3(96, 24), 256, 0, stream>>>(W_qkv, WqkvT, W_proj, WprojT);
  gemm_qkv_kernel<<<dim3(18, 64), 256, 0, stream>>>(xb, WqkvT, b_qkv, Qb, Kb, Vt);
  if (use_split) {
    attn_split_kernel<<<dim3(30, 48), 512, 0, stream>>>(Qb, Kb, Vt, Yb, Opart, lpart);
    attn_combine_kernel<<<dim3(10, 48), 256, 0, stream>>>(Opart, lpart, Yb);
  } else {
    attn_kernel<<<dim3(16, 48), 256, 0, stream>>>(Qb, Kb, Vt, Yb);
  }
  gemm_proj_kernel<<<dim3(6, 128), 256, 0, stream>>>(Yb, WprojT, b_proj, out);
}